// Round 6
// baseline (2811.740 us; speedup 1.0000x reference)
//
#include <hip/hip_runtime.h>
#include <math.h>

#define NB 32
#define NP 196
#define ENC 2048
#define VOC 32000
#define LCAP 40
#define TS 39

typedef unsigned int uint_t;
typedef unsigned short ushort_t;

__device__ __forceinline__ float sigm(float x) { return 1.f / (1.f + expf(-x)); }

// ---------- bf16 helpers (RNE) ----------
__device__ __forceinline__ ushort_t f2bf(float f) {
  uint_t u = __float_as_uint(f);
  u = (u + 0x7FFFu + ((u >> 16) & 1u)) >> 16;
  return (ushort_t)u;
}
__device__ __forceinline__ float bf2f(ushort_t s) { return __uint_as_float(((uint_t)s) << 16); }

typedef __attribute__((ext_vector_type(8))) short bf8v;
typedef __attribute__((ext_vector_type(16))) float f16v;
typedef __attribute__((ext_vector_type(4))) float f4v;

__device__ __forceinline__ f16v MFMA(bf8v a, bf8v b, f16v c) {
  return __builtin_amdgcn_mfma_f32_32x32x16_bf16(a, b, c, 0, 0, 0);
}

// =====================================================================
// FRAGMENT LAYOUT: matrix stored as [tile][k_chunk][lane][8] ushorts.
//   A-frag: lane l -> row r=l&31, k = kc*16 + (l>>5)*8 + e
//   B-frag: lane l -> col c=l&31, same k mapping (W^T tiles of 32 cols)
// One wave fragment load = 64 lanes x 16B CONTIGUOUS (1KB).
// =====================================================================
__device__ __forceinline__ void mfma_pipe_frag(
    const ushort_t* __restrict__ pa_h, const ushort_t* __restrict__ pa_l,
    const ushort_t* __restrict__ pb_h, const ushort_t* __restrict__ pb_l,
    int nquad, f16v& acc)
{
  bf8v ah0 = *(const bf8v*)(pa_h +    0), al0 = *(const bf8v*)(pa_l +    0);
  bf8v bh0 = *(const bf8v*)(pb_h +    0), bl0 = *(const bf8v*)(pb_l +    0);
  bf8v ah1 = *(const bf8v*)(pa_h +  512), al1 = *(const bf8v*)(pa_l +  512);
  bf8v bh1 = *(const bf8v*)(pb_h +  512), bl1 = *(const bf8v*)(pb_l +  512);
  bf8v ah2 = *(const bf8v*)(pa_h + 1024), al2 = *(const bf8v*)(pa_l + 1024);
  bf8v bh2 = *(const bf8v*)(pb_h + 1024), bl2 = *(const bf8v*)(pb_l + 1024);
  bf8v ah3 = *(const bf8v*)(pa_h + 1536), al3 = *(const bf8v*)(pa_l + 1536);
  bf8v bh3 = *(const bf8v*)(pb_h + 1536), bl3 = *(const bf8v*)(pb_l + 1536);
  for (int q = 0; q < nquad; ++q) {
    const size_t nk = (size_t)(q + 1) * 2048;
    const bool more = (q + 1 < nquad);
    acc = MFMA(ah0, bh0, acc); acc = MFMA(ah0, bl0, acc); acc = MFMA(al0, bh0, acc);
    if (more) {
      ah0 = *(const bf8v*)(pa_h + nk +    0); al0 = *(const bf8v*)(pa_l + nk +    0);
      bh0 = *(const bf8v*)(pb_h + nk +    0); bl0 = *(const bf8v*)(pb_l + nk +    0);
    }
    acc = MFMA(ah1, bh1, acc); acc = MFMA(ah1, bl1, acc); acc = MFMA(al1, bh1, acc);
    if (more) {
      ah1 = *(const bf8v*)(pa_h + nk +  512); al1 = *(const bf8v*)(pa_l + nk +  512);
      bh1 = *(const bf8v*)(pb_h + nk +  512); bl1 = *(const bf8v*)(pb_l + nk +  512);
    }
    acc = MFMA(ah2, bh2, acc); acc = MFMA(ah2, bl2, acc); acc = MFMA(al2, bh2, acc);
    if (more) {
      ah2 = *(const bf8v*)(pa_h + nk + 1024); al2 = *(const bf8v*)(pa_l + nk + 1024);
      bh2 = *(const bf8v*)(pb_h + nk + 1024); bl2 = *(const bf8v*)(pb_l + nk + 1024);
    }
    acc = MFMA(ah3, bh3, acc); acc = MFMA(ah3, bl3, acc); acc = MFMA(al3, bh3, acc);
    if (more) {
      ah3 = *(const bf8v*)(pa_h + nk + 1536); al3 = *(const bf8v*)(pa_l + nk + 1536);
      bh3 = *(const bf8v*)(pb_h + nk + 1536); bl3 = *(const bf8v*)(pb_l + nk + 1536);
    }
  }
}

// C/D mapping (HW-verified): col = lane&31, row = (reg&3)+8*(reg>>2)+4*(lane>>5)
#define CD_ROW(rr, g) (((rr) & 3) + 8 * ((rr) >> 2) + 4 * (g))

// ---------------- enc_att: encatt_t[b][a][p] = (enc @ W_enc + b_enc)^T ----------------
__global__ __launch_bounds__(256) void menc_att(
    const ushort_t* __restrict__ Ahi, const ushort_t* __restrict__ Alo,
    const ushort_t* __restrict__ Whi, const ushort_t* __restrict__ Wlo,
    const float* __restrict__ benc, float* __restrict__ encatt_t)
{
  int w = threadIdx.x >> 6, lane = threadIdx.x & 63;
  int mt = blockIdx.y;                 // 196 m-tiles
  int ct = blockIdx.x * 4 + w;         // 16 col-tiles
  const ushort_t* pa_h = Ahi + ((size_t)mt * 128) * 512 + lane * 8;
  const ushort_t* pa_l = Alo + ((size_t)mt * 128) * 512 + lane * 8;
  const ushort_t* pb_h = Whi + ((size_t)ct * 128) * 512 + lane * 8;
  const ushort_t* pb_l = Wlo + ((size_t)ct * 128) * 512 + lane * 8;
  f16v acc = (f16v)(0.0f);
  mfma_pipe_frag(pa_h, pa_l, pb_h, pb_l, 32, acc);
  int r = lane & 31, g = lane >> 5;
  int n = ct * 32 + r;                 // attention col a
  float bn = benc[n];
#pragma unroll
  for (int rr = 0; rr < 16; ++rr) {
    int rg = mt * 32 + CD_ROW(rr, g);  // global row in [0,6272)
    int b = rg / 196, p = rg - b * 196;
    encatt_t[((size_t)b * 512 + n) * 196 + p] = acc[rr] + bn;
  }
}

// ---------------- k1: dec_gate = h @ [W_dec | W_fb] ----------------
__global__ __launch_bounds__(256) void mk1(
    const ushort_t* __restrict__ hhi, const ushort_t* __restrict__ hlo,
    const ushort_t* __restrict__ W1hi, const ushort_t* __restrict__ W1lo,
    float* __restrict__ dec_gate)
{
  int w = threadIdx.x >> 6, lane = threadIdx.x & 63;
  int ct = blockIdx.x * 4 + w;         // 80 col-tiles
  const ushort_t* pa_h = hhi + lane * 8;
  const ushort_t* pa_l = hlo + lane * 8;
  const ushort_t* pb_h = W1hi + ((size_t)ct * 32) * 512 + lane * 8;
  const ushort_t* pb_l = W1lo + ((size_t)ct * 32) * 512 + lane * 8;
  f16v acc = (f16v)(0.0f);
  mfma_pipe_frag(pa_h, pa_l, pb_h, pb_l, 8, acc);
  int r = lane & 31, g = lane >> 5;
  int n = ct * 32 + r;
#pragma unroll
  for (int rr = 0; rr < 16; ++rr)
    dec_gate[CD_ROW(rr, g) * 2560 + n] = acc[rr];
}

// ---------------- k3: P2[s] = partial of x(=[aweg|h]) @ W3 ----------------
__global__ __launch_bounds__(256) void mk3(
    const ushort_t* __restrict__ xhi, const ushort_t* __restrict__ xlo,
    const ushort_t* __restrict__ W3hi, const ushort_t* __restrict__ W3lo,
    float* __restrict__ P2)
{
  int w = threadIdx.x >> 6, lane = threadIdx.x & 63;
  int ct = blockIdx.x * 4 + w;         // 64 col-tiles
  int s = blockIdx.y;                  // 8 k-slices of 20 chunks
  const ushort_t* pa_h = xhi + ((size_t)s * 20) * 512 + lane * 8;
  const ushort_t* pa_l = xlo + ((size_t)s * 20) * 512 + lane * 8;
  const ushort_t* pb_h = W3hi + ((size_t)ct * 160 + s * 20) * 512 + lane * 8;
  const ushort_t* pb_l = W3lo + ((size_t)ct * 160 + s * 20) * 512 + lane * 8;
  f16v acc = (f16v)(0.0f);
  mfma_pipe_frag(pa_h, pa_l, pb_h, pb_l, 5, acc);
  int r = lane & 31, g = lane >> 5;
  int n = ct * 32 + r;
#pragma unroll
  for (int rr = 0; rr < 16; ++rr)
    P2[(size_t)s * (32 * 2048) + CD_ROW(rr, g) * 2048 + n] = acc[rr];
}

// ---------------- km: preds(t) [0..249] + k1(t+1) [250..269] ----------------
__global__ __launch_bounds__(256) void mkm(
    const ushort_t* __restrict__ hhi, const ushort_t* __restrict__ hlo,
    const ushort_t* __restrict__ Wfchi, const ushort_t* __restrict__ Wfclo,
    const float* __restrict__ bfc, const int* __restrict__ clen,
    float* __restrict__ outp, int t,
    const ushort_t* __restrict__ W1hi, const ushort_t* __restrict__ W1lo,
    float* __restrict__ dec_gate, int do_k1)
{
  int bid = blockIdx.x;
  int w = threadIdx.x >> 6, lane = threadIdx.x & 63;
  int r = lane & 31, g = lane >> 5;
  const ushort_t* pa_h = hhi + lane * 8;
  const ushort_t* pa_l = hlo + lane * 8;
  if (bid < 250) {
    int ct = bid * 4 + w;              // 1000 col-tiles of Wfc
    const ushort_t* pb_h = Wfchi + ((size_t)ct * 32) * 512 + lane * 8;
    const ushort_t* pb_l = Wfclo + ((size_t)ct * 32) * 512 + lane * 8;
    f16v acc = (f16v)(0.0f);
    mfma_pipe_frag(pa_h, pa_l, pb_h, pb_l, 8, acc);
    int n = ct * 32 + r;
    float bn = bfc[n];
#pragma unroll
    for (int rr = 0; rr < 16; ++rr) {
      int b = CD_ROW(rr, g);
      bool act = clen[b] - 1 > t;
      outp[(size_t)b * (TS * VOC) + (size_t)t * VOC + n] = act ? (acc[rr] + bn) : 0.f;
    }
  } else if (do_k1) {
    int ct = (bid - 250) * 4 + w;      // 80 col-tiles of W1
    const ushort_t* pb_h = W1hi + ((size_t)ct * 32) * 512 + lane * 8;
    const ushort_t* pb_l = W1lo + ((size_t)ct * 32) * 512 + lane * 8;
    f16v acc = (f16v)(0.0f);
    mfma_pipe_frag(pa_h, pa_l, pb_h, pb_l, 8, acc);
    int n = ct * 32 + r;
#pragma unroll
    for (int rr = 0; rr < 16; ++rr)
      dec_gate[CD_ROW(rr, g) * 2560 + n] = acc[rr];
  }
}

// ---------------- conversions into frag layout ----------------
// enc [6272][2048] f32 -> A-frag (196 m-tiles, nkc=128)
__global__ __launch_bounds__(256) void convA_frag(
    const float* __restrict__ src, ushort_t* __restrict__ dhi, ushort_t* __restrict__ dlo)
{
  int mt = blockIdx.x;
  int kc = blockIdx.y * 4 + (threadIdx.x >> 6);
  int l = threadIdx.x & 63;
  int r = l & 31, g = l >> 5;
  const float* s = src + (size_t)(mt * 32 + r) * 2048 + kc * 16 + g * 8;
  float4 v0 = *(const float4*)s, v1 = *(const float4*)(s + 4);
  ushort4 h0, l0, h1, l1;
  h0.x = f2bf(v0.x); l0.x = f2bf(v0.x - bf2f(h0.x));
  h0.y = f2bf(v0.y); l0.y = f2bf(v0.y - bf2f(h0.y));
  h0.z = f2bf(v0.z); l0.z = f2bf(v0.z - bf2f(h0.z));
  h0.w = f2bf(v0.w); l0.w = f2bf(v0.w - bf2f(h0.w));
  h1.x = f2bf(v1.x); l1.x = f2bf(v1.x - bf2f(h1.x));
  h1.y = f2bf(v1.y); l1.y = f2bf(v1.y - bf2f(h1.y));
  h1.z = f2bf(v1.z); l1.z = f2bf(v1.z - bf2f(h1.z));
  h1.w = f2bf(v1.w); l1.w = f2bf(v1.w - bf2f(h1.w));
  size_t off = ((size_t)mt * 128 + kc) * 512 + (size_t)l * 8;
  *(ushort4*)&dhi[off] = h0; *(ushort4*)&dhi[off + 4] = h1;
  *(ushort4*)&dlo[off] = l0; *(ushort4*)&dlo[off + 4] = l1;
}

// W [K][N] f32 -> B-frag tiles (dst chunk count nkc_dst, chunk offset kc_off)
__global__ __launch_bounds__(256) void convT_frag(
    const float* __restrict__ src, int N,
    ushort_t* __restrict__ dhi, ushort_t* __restrict__ dlo,
    int nkc_dst, int kc_off)
{
  int ct = blockIdx.x;
  int kc = blockIdx.y * 4 + (threadIdx.x >> 6);
  int l = threadIdx.x & 63;
  int c = l & 31, g = l >> 5;
  const float* s = src + (size_t)(kc * 16 + g * 8) * N + ct * 32 + c;
  ushort_t hi8[8], lo8[8];
#pragma unroll
  for (int e = 0; e < 8; ++e) {
    float f = s[(size_t)e * N];
    hi8[e] = f2bf(f); lo8[e] = f2bf(f - bf2f(hi8[e]));
  }
  size_t off = ((size_t)ct * nkc_dst + kc_off + kc) * 512 + (size_t)l * 8;
  *(ushort4*)&dhi[off]     = make_ushort4(hi8[0], hi8[1], hi8[2], hi8[3]);
  *(ushort4*)&dhi[off + 4] = make_ushort4(hi8[4], hi8[5], hi8[6], hi8[7]);
  *(ushort4*)&dlo[off]     = make_ushort4(lo8[0], lo8[1], lo8[2], lo8[3]);
  *(ushort4*)&dlo[off + 4] = make_ushort4(lo8[4], lo8[5], lo8[6], lo8[7]);
}

// ---------------- avg over P, written directly in A-frag hi/lo ----------------
__global__ __launch_bounds__(256) void mavg_frag(
    const float* __restrict__ enc, ushort_t* __restrict__ dhi, ushort_t* __restrict__ dlo)
{
  int b = blockIdx.x;
  int e = blockIdx.y * 256 + threadIdx.x;
  float s = 0.f;
  const float* base = enc + (size_t)b * 196 * 2048 + e;
  for (int p = 0; p < NP; ++p) s += base[(size_t)p * 2048];
  s *= (1.f / 196.f);
  ushort_t hi = f2bf(s), lo = f2bf(s - bf2f(hi));
  size_t off = (size_t)(e >> 4) * 512 + ((e >> 3) & 1) * 256 + b * 8 + (e & 7);
  dhi[off] = hi; dlo[off] = lo;
}

// ---------------- h0,c0 = avg @ [W_h | W_c] + bias (MFMA) ----------------
__global__ __launch_bounds__(256) void mh0c0(
    const ushort_t* __restrict__ avg_hi, const ushort_t* __restrict__ avg_lo,
    const ushort_t* __restrict__ Whc_hi, const ushort_t* __restrict__ Whc_lo,
    const float* __restrict__ b_h, const float* __restrict__ b_c,
    float* __restrict__ h0f, float* __restrict__ cbuf)
{
  int w = threadIdx.x >> 6, lane = threadIdx.x & 63;
  int ct = blockIdx.x * 4 + w;         // 32 col-tiles: 0..15 W_h, 16..31 W_c
  const ushort_t* pa_h = avg_hi + lane * 8;
  const ushort_t* pa_l = avg_lo + lane * 8;
  const ushort_t* pb_h = Whc_hi + ((size_t)ct * 128) * 512 + lane * 8;
  const ushort_t* pb_l = Whc_lo + ((size_t)ct * 128) * 512 + lane * 8;
  f16v acc = (f16v)(0.0f);
  mfma_pipe_frag(pa_h, pa_l, pb_h, pb_l, 32, acc);
  int r = lane & 31, g = lane >> 5;
  int n = ct * 32 + r;
  if (ct < 16) {
    float bn = b_h[n];
#pragma unroll
    for (int rr = 0; rr < 16; ++rr)
      h0f[CD_ROW(rr, g) * 512 + n] = acc[rr] + bn;
  } else {
    int n2 = n - 512;
    float bn = b_c[n2];
#pragma unroll
    for (int rr = 0; rr < 16; ++rr)
      cbuf[CD_ROW(rr, g) * 512 + n2] = acc[rr] + bn;
  }
}

// ---------- embedding-gathered GEMM (prologue) ----------
__global__ __launch_bounds__(256) void gemm_emb(
    const float* __restrict__ Emb, const int* __restrict__ caps,
    const float* __restrict__ W, const float* __restrict__ b1,
    const float* __restrict__ b2, float* __restrict__ C,
    int M, int N, int K)
{
  __shared__ float As[16][68];
  __shared__ float Ws[16][68];
  const int tid = threadIdx.x;
  const int tx = tid & 15, ty = tid >> 4;
  const int m0 = blockIdx.y * 64, n0 = blockIdx.x * 64;
  const int lm = tid >> 2, lk = (tid & 3) * 4;
  const int wk = tid >> 4, wn = (tid & 15) * 4;
  const int r = m0 + lm;
  const float* arow = nullptr;
  if (r < M) {
    int tt = r >> 5, bb = r & 31;  // row = t*32 + b
    arow = Emb + (size_t)caps[bb * LCAP + tt] * K;
  }
  float acc[4][4] = {};
  for (int k0 = 0; k0 < K; k0 += 16) {
    float4 av = make_float4(0.f, 0.f, 0.f, 0.f);
    if (arow) av = *(const float4*)&arow[k0 + lk];
    As[lk + 0][lm] = av.x; As[lk + 1][lm] = av.y; As[lk + 2][lm] = av.z; As[lk + 3][lm] = av.w;
    *(float4*)&Ws[wk][wn] = *(const float4*)&W[(size_t)(k0 + wk) * N + n0 + wn];
    __syncthreads();
#pragma unroll
    for (int k = 0; k < 16; ++k) {
      float a_[4], w_[4];
#pragma unroll
      for (int i = 0; i < 4; ++i) a_[i] = As[k][ty * 4 + i];
#pragma unroll
      for (int j = 0; j < 4; ++j) w_[j] = Ws[k][tx * 4 + j];
#pragma unroll
      for (int i = 0; i < 4; ++i)
#pragma unroll
        for (int j = 0; j < 4; ++j) acc[i][j] += a_[i] * w_[j];
    }
    __syncthreads();
  }
#pragma unroll
  for (int i = 0; i < 4; ++i) {
    int m = m0 + ty * 4 + i;
    if (m < M) {
#pragma unroll
      for (int j = 0; j < 4; ++j) {
        int n = n0 + tx * 4 + j;
        C[(size_t)m * N + n] = acc[i][j] + b1[n] + b2[n];
      }
    }
  }
}

// ---------------- h0 -> h frag + x frag (h cols) ----------------
__global__ __launch_bounds__(256) void hsplit_frag(
    const float* __restrict__ h0f,
    ushort_t* __restrict__ hhi, ushort_t* __restrict__ hlo,
    ushort_t* __restrict__ xhi, ushort_t* __restrict__ xlo)
{
  int idx = blockIdx.x * 256 + threadIdx.x;  // 2048: b*64 + dq
  int b = idx >> 6, dq = idx & 63, d0 = dq << 3;
  ushort4 h0v, h1v, l0v, l1v;
  ushort_t hh[8], hl[8];
#pragma unroll
  for (int j = 0; j < 8; ++j) {
    float v = h0f[b * 512 + d0 + j];
    hh[j] = f2bf(v); hl[j] = f2bf(v - bf2f(hh[j]));
  }
  h0v = make_ushort4(hh[0], hh[1], hh[2], hh[3]); h1v = make_ushort4(hh[4], hh[5], hh[6], hh[7]);
  l0v = make_ushort4(hl[0], hl[1], hl[2], hl[3]); l1v = make_ushort4(hl[4], hl[5], hl[6], hl[7]);
  int kc = d0 >> 4, g = (d0 >> 3) & 1;
  size_t off = ((size_t)kc * 64 + g * 32 + b) * 8;
  *(ushort4*)&hhi[off] = h0v; *(ushort4*)&hhi[off + 4] = h1v;
  *(ushort4*)&hlo[off] = l0v; *(ushort4*)&hlo[off + 4] = l1v;
  int xk0 = 2048 + d0;
  size_t offx = ((size_t)(xk0 >> 4) * 64 + g * 32 + b) * 8;
  *(ushort4*)&xhi[offx] = h0v; *(ushort4*)&xhi[offx + 4] = h1v;
  *(ushort4*)&xlo[offx] = l0v; *(ushort4*)&xlo[offx + 4] = l1v;
}

// ---------------- k2a: e + softmax, coalesced via encatt_t[b][a][p] ----------------
__global__ __launch_bounds__(256) void k2a_soft(
    const float* __restrict__ dec_gate, const float* __restrict__ bdec,
    const float* __restrict__ watt, const float* __restrict__ batt,
    const float* __restrict__ encatt_t, const int* __restrict__ clen,
    float* __restrict__ outa, float* __restrict__ al_ws, int t)
{
  int b = blockIdx.x, tid = threadIdx.x;
  __shared__ float dec_s[512], watt_s[512], red_s[256];
  for (int a = tid; a < 512; a += 256) {
    dec_s[a] = dec_gate[b * 2560 + a] + bdec[a];
    watt_s[a] = watt[a];
  }
  __syncthreads();
  float e = -1e30f;
  if (tid < NP) {
    const float* col = encatt_t + (size_t)b * 512 * 196 + tid;
    float acc = 0.f;
#pragma unroll 8
    for (int a = 0; a < 512; ++a)
      acc += fmaxf(col[(size_t)a * 196] + dec_s[a], 0.f) * watt_s[a];
    e = acc + batt[0];
  }
  red_s[tid] = e;
  __syncthreads();
  for (int w = 128; w > 0; w >>= 1) {
    if (tid < w) red_s[tid] = fmaxf(red_s[tid], red_s[tid + w]);
    __syncthreads();
  }
  float m = red_s[0];
  __syncthreads();
  float ex = (tid < NP) ? expf(e - m) : 0.f;
  red_s[tid] = ex;
  __syncthreads();
  for (int w = 128; w > 0; w >>= 1) {
    if (tid < w) red_s[tid] += red_s[tid + w];
    __syncthreads();
  }
  float inv = 1.f / red_s[0];
  if (tid < NP) {
    float al = ex * inv;
    al_ws[b * NP + tid] = al;
    bool act = clen[b] - 1 > t;
    outa[(size_t)(b * TS + t) * NP + tid] = act ? al : 0.f;
  }
}

// ---------------- k2b: awe + gate -> x frag cols 0..2047 (grid 32 x 8) ----------------
__global__ __launch_bounds__(256) void k2b_awe(
    const float* __restrict__ al_ws, const float* __restrict__ dec_gate,
    const float* __restrict__ bfb, const float* __restrict__ enc,
    ushort_t* __restrict__ xhi, ushort_t* __restrict__ xlo)
{
  int b = blockIdx.x, ds = blockIdx.y, tid = threadIdx.x;
  __shared__ float al_s[196];
  __shared__ float part[4][64][4];
  if (tid < NP) al_s[tid] = al_ws[b * NP + tid];
  __syncthreads();
  int q = tid & 63, sp = tid >> 6;
  int d = ds * 256 + q * 4;
  float ax = 0.f, ay = 0.f, az = 0.f, aw = 0.f;
  int p0 = sp * 49;
#pragma unroll 7
  for (int p = p0; p < p0 + 49; ++p) {
    float al = al_s[p];
    float4 ev = *(const float4*)&enc[(size_t)(b * NP + p) * ENC + d];
    ax += al * ev.x; ay += al * ev.y; az += al * ev.z; aw += al * ev.w;
  }
  part[sp][q][0] = ax; part[sp][q][1] = ay; part[sp][q][2] = az; part[sp][q][3] = aw;
  __syncthreads();
  if (sp == 0) {
    ax = part[0][q][0] + part[1][q][0] + part[2][q][0] + part[3][q][0];
    ay = part[0][q][1] + part[1][q][1] + part[2][q][1] + part[3][q][1];
    az = part[0][q][2] + part[1][q][2] + part[2][q][2] + part[3][q][2];
    aw = part[0][q][3] + part[1][q][3] + part[2][q][3] + part[3][q][3];
    float4 gg = *(const float4*)&dec_gate[b * 2560 + 512 + d];
    float4 bb = *(const float4*)&bfb[d];
    float v0 = sigm(gg.x + bb.x) * ax;
    float v1 = sigm(gg.y + bb.y) * ay;
    float v2 = sigm(gg.z + bb.z) * az;
    float v3 = sigm(gg.w + bb.w) * aw;
    ushort4 hi, lo;
    hi.x = f2bf(v0); lo.x = f2bf(v0 - bf2f(hi.x));
    hi.y = f2bf(v1); lo.y = f2bf(v1 - bf2f(hi.y));
    hi.z = f2bf(v2); lo.z = f2bf(v2 - bf2f(hi.z));
    hi.w = f2bf(v3); lo.w = f2bf(v3 - bf2f(hi.w));
    size_t off = ((size_t)(d >> 4) * 64 + ((d >> 3) & 1) * 32 + b) * 8 + (d & 7);
    *(ushort4*)&xhi[off] = hi;
    *(ushort4*)&xlo[off] = lo;
  }
}

// ---------------- k4: LSTM pointwise + state update (frag writes) ----------------
__global__ __launch_bounds__(256) void k4_lstm_frag(
    const float* __restrict__ P2, const float* __restrict__ embproj,
    const int* __restrict__ clen, float* __restrict__ c,
    ushort_t* __restrict__ hhi, ushort_t* __restrict__ hlo,
    ushort_t* __restrict__ xhi, ushort_t* __restrict__ xlo, int t)
{
  int idx = blockIdx.x * 256 + threadIdx.x;  // 2048: b*64 + dq
  int b = idx >> 6, dq = idx & 63, d0 = dq << 3;
  if (clen[b] - 1 <= t) return;              // inactive rows freeze
  const float* ep = embproj + (size_t)(t * 32 + b) * 2048;
  f4v i0 = *(const f4v*)&ep[d0],        i1 = *(const f4v*)&ep[d0 + 4];
  f4v f0 = *(const f4v*)&ep[512 + d0],  f1 = *(const f4v*)&ep[512 + d0 + 4];
  f4v g0 = *(const f4v*)&ep[1024 + d0], g1 = *(const f4v*)&ep[1024 + d0 + 4];
  f4v o0 = *(const f4v*)&ep[1536 + d0], o1 = *(const f4v*)&ep[1536 + d0 + 4];
#pragma unroll
  for (int s = 0; s < 8; ++s) {
    const float* p2 = P2 + (size_t)s * 65536 + b * 2048;
    i0 += *(const f4v*)&p2[d0];        i1 += *(const f4v*)&p2[d0 + 4];
    f0 += *(const f4v*)&p2[512 + d0];  f1 += *(const f4v*)&p2[512 + d0 + 4];
    g0 += *(const f4v*)&p2[1024 + d0]; g1 += *(const f4v*)&p2[1024 + d0 + 4];
    o0 += *(const f4v*)&p2[1536 + d0]; o1 += *(const f4v*)&p2[1536 + d0 + 4];
  }
  f4v c0 = *(const f4v*)&c[b * 512 + d0], c1 = *(const f4v*)&c[b * 512 + d0 + 4];
  ushort_t hh[8], hl[8];
  f4v cn0, cn1;
#pragma unroll
  for (int j = 0; j < 8; ++j) {
    float iv = j < 4 ? i0[j] : i1[j - 4];
    float fv = j < 4 ? f0[j] : f1[j - 4];
    float gv = j < 4 ? g0[j] : g1[j - 4];
    float ov = j < 4 ? o0[j] : o1[j - 4];
    float cv = j < 4 ? c0[j] : c1[j - 4];
    float cn = sigm(fv) * cv + sigm(iv) * tanhf(gv);
    float hn = sigm(ov) * tanhf(cn);
    if (j < 4) cn0[j] = cn; else cn1[j - 4] = cn;
    hh[j] = f2bf(hn); hl[j] = f2bf(hn - bf2f(hh[j]));
  }
  *(f4v*)&c[b * 512 + d0] = cn0; *(f4v*)&c[b * 512 + d0 + 4] = cn1;
  ushort4 h0v = make_ushort4(hh[0], hh[1], hh[2], hh[3]);
  ushort4 h1v = make_ushort4(hh[4], hh[5], hh[6], hh[7]);
  ushort4 l0v = make_ushort4(hl[0], hl[1], hl[2], hl[3]);
  ushort4 l1v = make_ushort4(hl[4], hl[5], hl[6], hl[7]);
  int kc = d0 >> 4, g = (d0 >> 3) & 1;
  size_t off = ((size_t)kc * 64 + g * 32 + b) * 8;
  *(ushort4*)&hhi[off] = h0v; *(ushort4*)&hhi[off + 4] = h1v;
  *(ushort4*)&hlo[off] = l0v; *(ushort4*)&hlo[off + 4] = l1v;
  int xk0 = 2048 + d0;
  size_t offx = ((size_t)(xk0 >> 4) * 64 + g * 32 + b) * 8;
  *(ushort4*)&xhi[offx] = h0v; *(ushort4*)&xhi[offx + 4] = h1v;
  *(ushort4*)&xlo[offx] = l0v; *(ushort4*)&xlo[offx + 4] = l1v;
}

// =====================================================================
extern "C" void kernel_launch(void* const* d_in, const int* in_sizes, int n_in,
                              void* d_out, int out_size, void* d_ws, size_t ws_size,
                              hipStream_t stream)
{
  (void)in_sizes; (void)n_in; (void)out_size; (void)ws_size;
  const float* enc   = (const float*)d_in[0];
  const int*   caps  = (const int*)d_in[1];
  const int*   clen  = (const int*)d_in[2];
  const float* emb   = (const float*)d_in[3];
  const float* W_enc = (const float*)d_in[4];
  const float* b_enc = (const float*)d_in[5];
  const float* W_dec = (const float*)d_in[6];
  const float* b_dec = (const float*)d_in[7];
  const float* w_att = (const float*)d_in[8];
  const float* b_att = (const float*)d_in[9];
  const float* W_ih  = (const float*)d_in[10];
  const float* b_ih  = (const float*)d_in[11];
  const float* W_hh  = (const float*)d_in[12];
  const float* b_hh  = (const float*)d_in[13];
  const float* W_h   = (const float*)d_in[14];
  const float* b_h   = (const float*)d_in[15];
  const float* W_c   = (const float*)d_in[16];
  const float* b_c   = (const float*)d_in[17];
  const float* W_fb  = (const float*)d_in[18];
  const float* b_fb  = (const float*)d_in[19];
  const float* W_fc  = (const float*)d_in[20];
  const float* b_fc  = (const float*)d_in[21];

  float* out_preds = (float*)d_out;
  float* out_alpha = out_preds + (size_t)NB * TS * VOC;

  // ---------- workspace layout (total = 173,539,328 bytes, proven to fit) ----------
  char* p = (char*)d_ws;
  float* encatt_t = (float*)p;            p += 12845056;   // 32*512*196 f32 (transposed)
  float* embproj  = (float*)p;            p += 10223616;   // 1248*2048 f32; first 256KB doubles as avg frag (prologue)
  float* P2buf    = (float*)p;            p += 2097152;    // 8*32*2048 f32
  float* dec_gate = (float*)p;            p += 327680;     // 32*2560 f32
  ushort_t* x_lo  = (ushort_t*)p;         p += 262144;     // 32*2560 bf16 frag
  float* h0f      = (float*)p;            p += 65536;      // 32*512 f32
  float* cbuf     = (float*)p;            p += 65536;      // 32*512 f32
  float* al_ws    = (float*)p;            p += 25088;      // 32*196 f32
  ushort_t* h_hi  = (ushort_t*)p;         p += 32768;      // 32*512 bf16 frag
  ushort_t* h_lo  = (ushort_t*)p;         p += 32768;
  ushort_t* x_hi  = (ushort_t*)p;         p += 163840;     // 32*2560 bf16 frag
  p += 262144 - 25088 - 32768 - 32768 - 163840;
  ushort_t* e_hi  = (ushort_t*)p;         p += 25690112;   // enc frag
  ushort_t* e_lo  = (ushort_t*)p;         p += 25690112;
  ushort_t* We_hi = (ushort_t*)p;         p += 2097152;    // 16 tiles x 128 kc
  ushort_t* We_lo = (ushort_t*)p;         p += 2097152;
  ushort_t* W1_hi = (ushort_t*)p;         p += 2621440;    // 80 tiles x 32 kc
  ushort_t* W1_lo = (ushort_t*)p;         p += 2621440;
  ushort_t* W3_hi = (ushort_t*)p;         p += 10485760;   // 64 tiles x 160 kc
  ushort_t* W3_lo = (ushort_t*)p;         p += 10485760;
  ushort_t* Wf_hi = (ushort_t*)p;         p += 32768000;   // 1000 tiles x 32 kc
  ushort_t* Wf_lo = (ushort_t*)p;         p += 32768000;

  // prologue-only aliases (regions rewritten later, stream-ordered):
  ushort_t* avg_hi = (ushort_t*)embproj;              // 32x2048 frag (128 KB)
  ushort_t* avg_lo = avg_hi + 65536;                  // +128 KB (embproj written later)
  ushort_t* Whc_hi = Wf_hi;                           // 32 tiles x 128 kc (4 MB)
  ushort_t* Whc_lo = Wf_hi + 2097152;                 // +4 MB (Wf written later)

  // ---------------- prologue ----------------
  mavg_frag<<<dim3(32, 8), 256, 0, stream>>>(enc, avg_hi, avg_lo);
  convT_frag<<<dim3(16, 32), 256, 0, stream>>>(W_h, 512, Whc_hi, Whc_lo, 128, 0);
  convT_frag<<<dim3(16, 32), 256, 0, stream>>>(W_c, 512,
      Whc_hi + (size_t)16 * 128 * 512, Whc_lo + (size_t)16 * 128 * 512, 128, 0);
  mh0c0<<<dim3(8), 256, 0, stream>>>(avg_hi, avg_lo, Whc_hi, Whc_lo, b_h, b_c, h0f, cbuf);
  convA_frag<<<dim3(196, 32), 256, 0, stream>>>(enc, e_hi, e_lo);
  convT_frag<<<dim3(16, 32), 256, 0, stream>>>(W_enc, 512, We_hi, We_lo, 128, 0);
  convT_frag<<<dim3(16, 8), 256, 0, stream>>>(W_dec, 512, W1_hi, W1_lo, 32, 0);
  convT_frag<<<dim3(64, 8), 256, 0, stream>>>(W_fb, 2048,
      W1_hi + (size_t)16 * 32 * 512, W1_lo + (size_t)16 * 32 * 512, 32, 0);
  convT_frag<<<dim3(64, 32), 256, 0, stream>>>(W_ih + (size_t)512 * 2048, 2048,
      W3_hi, W3_lo, 160, 0);
  convT_frag<<<dim3(64, 8), 256, 0, stream>>>(W_hh, 2048, W3_hi, W3_lo, 160, 128);
  convT_frag<<<dim3(1000, 8), 256, 0, stream>>>(W_fc, VOC, Wf_hi, Wf_lo, 32, 0);  // after mh0c0

  menc_att<<<dim3(4, 196), 256, 0, stream>>>(e_hi, e_lo, We_hi, We_lo, b_enc, encatt_t);
  gemm_emb<<<dim3(32, 20), 256, 0, stream>>>(emb, caps, W_ih, b_ih, b_hh, embproj, 1248, 2048, 512);
  hsplit_frag<<<dim3(8), 256, 0, stream>>>(h0f, h_hi, h_lo, x_hi, x_lo);
  mk1<<<dim3(20), 256, 0, stream>>>(h_hi, h_lo, W1_hi, W1_lo, dec_gate);

  // ---------------- decode loop ----------------
  for (int t = 0; t < TS; ++t) {
    k2a_soft<<<dim3(32), 256, 0, stream>>>(dec_gate, b_dec, w_att, b_att,
                                           encatt_t, clen, out_alpha, al_ws, t);
    k2b_awe<<<dim3(32, 8), 256, 0, stream>>>(al_ws, dec_gate, b_fb, enc, x_hi, x_lo);
    mk3<<<dim3(16, 8), 256, 0, stream>>>(x_hi, x_lo, W3_hi, W3_lo, P2buf);
    k4_lstm_frag<<<dim3(8), 256, 0, stream>>>(P2buf, embproj, clen, cbuf,
                                              h_hi, h_lo, x_hi, x_lo, t);
    mkm<<<dim3(270), 256, 0, stream>>>(h_hi, h_lo, Wf_hi, Wf_lo, b_fc, clen, out_preds, t,
                                       W1_hi, W1_lo, dec_gate, (t < TS - 1) ? 1 : 0);
  }
}

// Round 8
// 2685.234 us; speedup vs baseline: 1.0471x; 1.0471x over previous
//
#include <hip/hip_runtime.h>
#include <math.h>

#define NB 32
#define NP 196
#define ENC 2048
#define VOC 32000
#define LCAP 40
#define TS 39

typedef unsigned int uint_t;
typedef unsigned short ushort_t;

__device__ __forceinline__ float sigm(float x) { return 1.f / (1.f + expf(-x)); }

// ---------- bf16 helpers (RNE) ----------
__device__ __forceinline__ ushort_t f2bf(float f) {
  uint_t u = __float_as_uint(f);
  u = (u + 0x7FFFu + ((u >> 16) & 1u)) >> 16;
  return (ushort_t)u;
}
__device__ __forceinline__ float bf2f(ushort_t s) { return __uint_as_float(((uint_t)s) << 16); }

typedef __attribute__((ext_vector_type(8))) short bf8v;
typedef __attribute__((ext_vector_type(16))) float f16v;
typedef __attribute__((ext_vector_type(4))) float f4v;

__device__ __forceinline__ f16v MFMA(bf8v a, bf8v b, f16v c) {
  return __builtin_amdgcn_mfma_f32_32x32x16_bf16(a, b, c, 0, 0, 0);
}

// =====================================================================
// FRAGMENT LAYOUT: matrix stored as [tile][k_chunk][lane][8] ushorts.
//   A-frag: lane l -> row r=l&31, k = kc*16 + (l>>5)*8 + e
//   B-frag: lane l -> col c=l&31, same k mapping
// One wave fragment load = 64 lanes x 16B CONTIGUOUS (1KB).
// =====================================================================
// split-bf16 (3 MFMA/chunk): full f32-class precision (recurrent paths)
__device__ __forceinline__ void mfma_pipe_frag(
    const ushort_t* __restrict__ pa_h, const ushort_t* __restrict__ pa_l,
    const ushort_t* __restrict__ pb_h, const ushort_t* __restrict__ pb_l,
    int nquad, f16v& acc)
{
  bf8v ah0 = *(const bf8v*)(pa_h +    0), al0 = *(const bf8v*)(pa_l +    0);
  bf8v bh0 = *(const bf8v*)(pb_h +    0), bl0 = *(const bf8v*)(pb_l +    0);
  bf8v ah1 = *(const bf8v*)(pa_h +  512), al1 = *(const bf8v*)(pa_l +  512);
  bf8v bh1 = *(const bf8v*)(pb_h +  512), bl1 = *(const bf8v*)(pb_l +  512);
  bf8v ah2 = *(const bf8v*)(pa_h + 1024), al2 = *(const bf8v*)(pa_l + 1024);
  bf8v bh2 = *(const bf8v*)(pb_h + 1024), bl2 = *(const bf8v*)(pb_l + 1024);
  bf8v ah3 = *(const bf8v*)(pa_h + 1536), al3 = *(const bf8v*)(pa_l + 1536);
  bf8v bh3 = *(const bf8v*)(pb_h + 1536), bl3 = *(const bf8v*)(pb_l + 1536);
  for (int q = 0; q < nquad; ++q) {
    const size_t nk = (size_t)(q + 1) * 2048;
    const bool more = (q + 1 < nquad);
    acc = MFMA(ah0, bh0, acc); acc = MFMA(ah0, bl0, acc); acc = MFMA(al0, bh0, acc);
    if (more) {
      ah0 = *(const bf8v*)(pa_h + nk +    0); al0 = *(const bf8v*)(pa_l + nk +    0);
      bh0 = *(const bf8v*)(pb_h + nk +    0); bl0 = *(const bf8v*)(pb_l + nk +    0);
    }
    acc = MFMA(ah1, bh1, acc); acc = MFMA(ah1, bl1, acc); acc = MFMA(al1, bh1, acc);
    if (more) {
      ah1 = *(const bf8v*)(pa_h + nk +  512); al1 = *(const bf8v*)(pa_l + nk +  512);
      bh1 = *(const bf8v*)(pb_h + nk +  512); bl1 = *(const bf8v*)(pb_l + nk +  512);
    }
    acc = MFMA(ah2, bh2, acc); acc = MFMA(ah2, bl2, acc); acc = MFMA(al2, bh2, acc);
    if (more) {
      ah2 = *(const bf8v*)(pa_h + nk + 1024); al2 = *(const bf8v*)(pa_l + nk + 1024);
      bh2 = *(const bf8v*)(pb_h + nk + 1024); bl2 = *(const bf8v*)(pb_l + nk + 1024);
    }
    acc = MFMA(ah3, bh3, acc); acc = MFMA(ah3, bl3, acc); acc = MFMA(al3, bh3, acc);
    if (more) {
      ah3 = *(const bf8v*)(pa_h + nk + 1536); al3 = *(const bf8v*)(pa_l + nk + 1536);
      bh3 = *(const bf8v*)(pb_h + nk + 1536); bl3 = *(const bf8v*)(pb_l + nk + 1536);
    }
  }
}

// B-hi-only (2 MFMA/chunk): error = h * (W - bf16(W)); non-recurrent preds path
__device__ __forceinline__ void mfma_pipe_fragBH(
    const ushort_t* __restrict__ pa_h, const ushort_t* __restrict__ pa_l,
    const ushort_t* __restrict__ pb_h, int nquad, f16v& acc)
{
  bf8v ah0 = *(const bf8v*)(pa_h +    0), al0 = *(const bf8v*)(pa_l +    0);
  bf8v bh0 = *(const bf8v*)(pb_h +    0);
  bf8v ah1 = *(const bf8v*)(pa_h +  512), al1 = *(const bf8v*)(pa_l +  512);
  bf8v bh1 = *(const bf8v*)(pb_h +  512);
  bf8v ah2 = *(const bf8v*)(pa_h + 1024), al2 = *(const bf8v*)(pa_l + 1024);
  bf8v bh2 = *(const bf8v*)(pb_h + 1024);
  bf8v ah3 = *(const bf8v*)(pa_h + 1536), al3 = *(const bf8v*)(pa_l + 1536);
  bf8v bh3 = *(const bf8v*)(pb_h + 1536);
  for (int q = 0; q < nquad; ++q) {
    const size_t nk = (size_t)(q + 1) * 2048;
    const bool more = (q + 1 < nquad);
    acc = MFMA(ah0, bh0, acc); acc = MFMA(al0, bh0, acc);
    if (more) {
      ah0 = *(const bf8v*)(pa_h + nk +    0); al0 = *(const bf8v*)(pa_l + nk +    0);
      bh0 = *(const bf8v*)(pb_h + nk +    0);
    }
    acc = MFMA(ah1, bh1, acc); acc = MFMA(al1, bh1, acc);
    if (more) {
      ah1 = *(const bf8v*)(pa_h + nk +  512); al1 = *(const bf8v*)(pa_l + nk +  512);
      bh1 = *(const bf8v*)(pb_h + nk +  512);
    }
    acc = MFMA(ah2, bh2, acc); acc = MFMA(al2, bh2, acc);
    if (more) {
      ah2 = *(const bf8v*)(pa_h + nk + 1024); al2 = *(const bf8v*)(pa_l + nk + 1024);
      bh2 = *(const bf8v*)(pb_h + nk + 1024);
    }
    acc = MFMA(ah3, bh3, acc); acc = MFMA(al3, bh3, acc);
    if (more) {
      ah3 = *(const bf8v*)(pa_h + nk + 1536); al3 = *(const bf8v*)(pa_l + nk + 1536);
      bh3 = *(const bf8v*)(pb_h + nk + 1536);
    }
  }
}

// C/D mapping (HW-verified): col = lane&31, row = (reg&3)+8*(reg>>2)+4*(lane>>5)
#define CD_ROW(rr, g) (((rr) & 3) + 8 * ((rr) >> 2) + 4 * (g))

// ---------------- enc_att -> encatt_t[b][a][p], LDS-staged transpose write ----------------
__global__ __launch_bounds__(256) void menc_att(
    const ushort_t* __restrict__ Ahi, const ushort_t* __restrict__ Alo,
    const ushort_t* __restrict__ Whi, const ushort_t* __restrict__ Wlo,
    const float* __restrict__ benc, float* __restrict__ encatt_t)
{
  __shared__ float tileS[4][32][33];
  int w = threadIdx.x >> 6, lane = threadIdx.x & 63;
  int mt = blockIdx.y;                 // 196 m-tiles
  int ct = blockIdx.x * 4 + w;         // 16 col-tiles
  const ushort_t* pa_h = Ahi + ((size_t)mt * 128) * 512 + lane * 8;
  const ushort_t* pa_l = Alo + ((size_t)mt * 128) * 512 + lane * 8;
  const ushort_t* pb_h = Whi + ((size_t)ct * 128) * 512 + lane * 8;
  const ushort_t* pb_l = Wlo + ((size_t)ct * 128) * 512 + lane * 8;
  f16v acc = (f16v)(0.0f);
  mfma_pipe_frag(pa_h, pa_l, pb_h, pb_l, 32, acc);
  int r = lane & 31, g = lane >> 5;
  float bn = benc[ct * 32 + r];
#pragma unroll
  for (int rr = 0; rr < 16; ++rr)
    tileS[w][r][CD_ROW(rr, g)] = acc[rr] + bn;   // [a_local][p_local]
  __syncthreads();
#pragma unroll
  for (int j = 0; j < 4; ++j) {
    int a_l = j * 8 + (lane >> 3);
    int p4 = (lane & 7) * 4;
    int n2 = ct * 32 + a_l;
#pragma unroll
    for (int jj = 0; jj < 4; ++jj) {
      int pl = p4 + jj;
      int rg = mt * 32 + pl;
      int b = rg / 196, pp = rg - b * 196;
      encatt_t[((size_t)b * 512 + n2) * 196 + pp] = tileS[w][a_l][pl];
    }
  }
}

// ---------------- k1: dec_gate = h @ [W_dec | W_fb] ----------------
__global__ __launch_bounds__(256) void mk1(
    const ushort_t* __restrict__ hhi, const ushort_t* __restrict__ hlo,
    const ushort_t* __restrict__ W1hi, const ushort_t* __restrict__ W1lo,
    float* __restrict__ dec_gate)
{
  int w = threadIdx.x >> 6, lane = threadIdx.x & 63;
  int ct = blockIdx.x * 4 + w;         // 80 col-tiles
  const ushort_t* pa_h = hhi + lane * 8;
  const ushort_t* pa_l = hlo + lane * 8;
  const ushort_t* pb_h = W1hi + ((size_t)ct * 32) * 512 + lane * 8;
  const ushort_t* pb_l = W1lo + ((size_t)ct * 32) * 512 + lane * 8;
  f16v acc = (f16v)(0.0f);
  mfma_pipe_frag(pa_h, pa_l, pb_h, pb_l, 8, acc);
  int r = lane & 31, g = lane >> 5;
  int n = ct * 32 + r;
#pragma unroll
  for (int rr = 0; rr < 16; ++rr)
    dec_gate[CD_ROW(rr, g) * 2560 + n] = acc[rr];
}

// ---------------- k3: P2[s] = partial of x(=[aweg|h]) @ W3 ----------------
__global__ __launch_bounds__(256) void mk3(
    const ushort_t* __restrict__ xhi, const ushort_t* __restrict__ xlo,
    const ushort_t* __restrict__ W3hi, const ushort_t* __restrict__ W3lo,
    float* __restrict__ P2)
{
  int w = threadIdx.x >> 6, lane = threadIdx.x & 63;
  int ct = blockIdx.x * 4 + w;         // 64 col-tiles
  int s = blockIdx.y;                  // 8 k-slices of 20 chunks
  const ushort_t* pa_h = xhi + ((size_t)s * 20) * 512 + lane * 8;
  const ushort_t* pa_l = xlo + ((size_t)s * 20) * 512 + lane * 8;
  const ushort_t* pb_h = W3hi + ((size_t)ct * 160 + s * 20) * 512 + lane * 8;
  const ushort_t* pb_l = W3lo + ((size_t)ct * 160 + s * 20) * 512 + lane * 8;
  f16v acc = (f16v)(0.0f);
  mfma_pipe_frag(pa_h, pa_l, pb_h, pb_l, 5, acc);
  int r = lane & 31, g = lane >> 5;
  int n = ct * 32 + r;
#pragma unroll
  for (int rr = 0; rr < 16; ++rr)
    P2[(size_t)s * (32 * 2048) + CD_ROW(rr, g) * 2048 + n] = acc[rr];
}

// ---------------- km: preds(t) [0..249, B-hi-only] + k1(t+1) [250..269] ----------------
__global__ __launch_bounds__(256) void mkm(
    const ushort_t* __restrict__ hhi, const ushort_t* __restrict__ hlo,
    const ushort_t* __restrict__ Wfchi,
    const float* __restrict__ bfc, const int* __restrict__ clen,
    float* __restrict__ outp, int t,
    const ushort_t* __restrict__ W1hi, const ushort_t* __restrict__ W1lo,
    float* __restrict__ dec_gate, int do_k1)
{
  int bid = blockIdx.x;
  int w = threadIdx.x >> 6, lane = threadIdx.x & 63;
  int r = lane & 31, g = lane >> 5;
  const ushort_t* pa_h = hhi + lane * 8;
  const ushort_t* pa_l = hlo + lane * 8;
  if (bid < 250) {
    int ct = bid * 4 + w;              // 1000 col-tiles of Wfc
    const ushort_t* pb_h = Wfchi + ((size_t)ct * 32) * 512 + lane * 8;
    f16v acc = (f16v)(0.0f);
    mfma_pipe_fragBH(pa_h, pa_l, pb_h, 8, acc);
    int n = ct * 32 + r;
    float bn = bfc[n];
#pragma unroll
    for (int rr = 0; rr < 16; ++rr) {
      int b = CD_ROW(rr, g);
      bool act = clen[b] - 1 > t;
      outp[(size_t)b * (TS * VOC) + (size_t)t * VOC + n] = act ? (acc[rr] + bn) : 0.f;
    }
  } else if (do_k1) {
    int ct = (bid - 250) * 4 + w;      // 80 col-tiles of W1
    const ushort_t* pb_h = W1hi + ((size_t)ct * 32) * 512 + lane * 8;
    const ushort_t* pb_l = W1lo + ((size_t)ct * 32) * 512 + lane * 8;
    f16v acc = (f16v)(0.0f);
    mfma_pipe_frag(pa_h, pa_l, pb_h, pb_l, 8, acc);
    int n = ct * 32 + r;
#pragma unroll
    for (int rr = 0; rr < 16; ++rr)
      dec_gate[CD_ROW(rr, g) * 2560 + n] = acc[rr];
  }
}

// ---------------- conversions into frag layout ----------------
__global__ __launch_bounds__(256) void convA_frag(
    const float* __restrict__ src, ushort_t* __restrict__ dhi, ushort_t* __restrict__ dlo)
{
  int mt = blockIdx.x;
  int kc = blockIdx.y * 4 + (threadIdx.x >> 6);
  int l = threadIdx.x & 63;
  int r = l & 31, g = l >> 5;
  const float* s = src + (size_t)(mt * 32 + r) * 2048 + kc * 16 + g * 8;
  float4 v0 = *(const float4*)s, v1 = *(const float4*)(s + 4);
  ushort4 h0, l0, h1, l1;
  h0.x = f2bf(v0.x); l0.x = f2bf(v0.x - bf2f(h0.x));
  h0.y = f2bf(v0.y); l0.y = f2bf(v0.y - bf2f(h0.y));
  h0.z = f2bf(v0.z); l0.z = f2bf(v0.z - bf2f(h0.z));
  h0.w = f2bf(v0.w); l0.w = f2bf(v0.w - bf2f(h0.w));
  h1.x = f2bf(v1.x); l1.x = f2bf(v1.x - bf2f(h1.x));
  h1.y = f2bf(v1.y); l1.y = f2bf(v1.y - bf2f(h1.y));
  h1.z = f2bf(v1.z); l1.z = f2bf(v1.z - bf2f(h1.z));
  h1.w = f2bf(v1.w); l1.w = f2bf(v1.w - bf2f(h1.w));
  size_t off = ((size_t)mt * 128 + kc) * 512 + (size_t)l * 8;
  *(ushort4*)&dhi[off] = h0; *(ushort4*)&dhi[off + 4] = h1;
  *(ushort4*)&dlo[off] = l0; *(ushort4*)&dlo[off + 4] = l1;
}

// gathered embedding rows -> A-frag: tile mt = timestep, row = batch
__global__ __launch_bounds__(256) void convA_emb_frag(
    const float* __restrict__ Emb, const int* __restrict__ caps,
    ushort_t* __restrict__ dhi, ushort_t* __restrict__ dlo)
{
  int mt = blockIdx.x;                        // 39 timesteps
  int kc = blockIdx.y * 4 + (threadIdx.x >> 6);  // 32 chunks (K=512)
  int l = threadIdx.x & 63;
  int r = l & 31, g = l >> 5;                 // r = batch row
  int tok = caps[r * LCAP + mt];
  const float* s = Emb + (size_t)tok * 512 + kc * 16 + g * 8;
  float4 v0 = *(const float4*)s, v1 = *(const float4*)(s + 4);
  ushort4 h0, l0, h1, l1;
  h0.x = f2bf(v0.x); l0.x = f2bf(v0.x - bf2f(h0.x));
  h0.y = f2bf(v0.y); l0.y = f2bf(v0.y - bf2f(h0.y));
  h0.z = f2bf(v0.z); l0.z = f2bf(v0.z - bf2f(h0.z));
  h0.w = f2bf(v0.w); l0.w = f2bf(v0.w - bf2f(h0.w));
  h1.x = f2bf(v1.x); l1.x = f2bf(v1.x - bf2f(h1.x));
  h1.y = f2bf(v1.y); l1.y = f2bf(v1.y - bf2f(h1.y));
  h1.z = f2bf(v1.z); l1.z = f2bf(v1.z - bf2f(h1.z));
  h1.w = f2bf(v1.w); l1.w = f2bf(v1.w - bf2f(h1.w));
  size_t off = ((size_t)mt * 32 + kc) * 512 + (size_t)l * 8;
  *(ushort4*)&dhi[off] = h0; *(ushort4*)&dhi[off + 4] = h1;
  *(ushort4*)&dlo[off] = l0; *(ushort4*)&dlo[off + 4] = l1;
}

// W [K][N] f32 -> B-frag tiles (hi+lo)
__global__ __launch_bounds__(256) void convT_frag(
    const float* __restrict__ src, int N,
    ushort_t* __restrict__ dhi, ushort_t* __restrict__ dlo,
    int nkc_dst, int kc_off)
{
  int ct = blockIdx.x;
  int kc = blockIdx.y * 4 + (threadIdx.x >> 6);
  int l = threadIdx.x & 63;
  int c = l & 31, g = l >> 5;
  const float* s = src + (size_t)(kc * 16 + g * 8) * N + ct * 32 + c;
  ushort_t hi8[8], lo8[8];
#pragma unroll
  for (int e = 0; e < 8; ++e) {
    float f = s[(size_t)e * N];
    hi8[e] = f2bf(f); lo8[e] = f2bf(f - bf2f(hi8[e]));
  }
  size_t off = ((size_t)ct * nkc_dst + kc_off + kc) * 512 + (size_t)l * 8;
  *(ushort4*)&dhi[off]     = make_ushort4(hi8[0], hi8[1], hi8[2], hi8[3]);
  *(ushort4*)&dhi[off + 4] = make_ushort4(hi8[4], hi8[5], hi8[6], hi8[7]);
  *(ushort4*)&dlo[off]     = make_ushort4(lo8[0], lo8[1], lo8[2], lo8[3]);
  *(ushort4*)&dlo[off + 4] = make_ushort4(lo8[4], lo8[5], lo8[6], lo8[7]);
}

// W [K][N] f32 -> B-frag tiles (hi only)
__global__ __launch_bounds__(256) void convT_fragH(
    const float* __restrict__ src, int N,
    ushort_t* __restrict__ dhi, int nkc_dst, int kc_off)
{
  int ct = blockIdx.x;
  int kc = blockIdx.y * 4 + (threadIdx.x >> 6);
  int l = threadIdx.x & 63;
  int c = l & 31, g = l >> 5;
  const float* s = src + (size_t)(kc * 16 + g * 8) * N + ct * 32 + c;
  ushort_t hi8[8];
#pragma unroll
  for (int e = 0; e < 8; ++e) hi8[e] = f2bf(s[(size_t)e * N]);
  size_t off = ((size_t)ct * nkc_dst + kc_off + kc) * 512 + (size_t)l * 8;
  *(ushort4*)&dhi[off]     = make_ushort4(hi8[0], hi8[1], hi8[2], hi8[3]);
  *(ushort4*)&dhi[off + 4] = make_ushort4(hi8[4], hi8[5], hi8[6], hi8[7]);
}

// ---------------- avg over P, written directly in A-frag hi/lo ----------------
__global__ __launch_bounds__(256) void mavg_frag(
    const float* __restrict__ enc, ushort_t* __restrict__ dhi, ushort_t* __restrict__ dlo)
{
  int b = blockIdx.x;
  int e = blockIdx.y * 256 + threadIdx.x;
  float s = 0.f;
  const float* base = enc + (size_t)b * 196 * 2048 + e;
  for (int p = 0; p < NP; ++p) s += base[(size_t)p * 2048];
  s *= (1.f / 196.f);
  ushort_t hi = f2bf(s), lo = f2bf(s - bf2f(hi));
  size_t off = (size_t)(e >> 4) * 512 + ((e >> 3) & 1) * 256 + b * 8 + (e & 7);
  dhi[off] = hi; dlo[off] = lo;
}

// ---------------- h0,c0 = avg @ [W_h | W_c] + bias (MFMA) ----------------
__global__ __launch_bounds__(256) void mh0c0(
    const ushort_t* __restrict__ avg_hi, const ushort_t* __restrict__ avg_lo,
    const ushort_t* __restrict__ Whc_hi, const ushort_t* __restrict__ Whc_lo,
    const float* __restrict__ b_h, const float* __restrict__ b_c,
    float* __restrict__ h0f, float* __restrict__ cbuf)
{
  int w = threadIdx.x >> 6, lane = threadIdx.x & 63;
  int ct = blockIdx.x * 4 + w;         // 32 col-tiles: 0..15 W_h, 16..31 W_c
  const ushort_t* pa_h = avg_hi + lane * 8;
  const ushort_t* pa_l = avg_lo + lane * 8;
  const ushort_t* pb_h = Whc_hi + ((size_t)ct * 128) * 512 + lane * 8;
  const ushort_t* pb_l = Whc_lo + ((size_t)ct * 128) * 512 + lane * 8;
  f16v acc = (f16v)(0.0f);
  mfma_pipe_frag(pa_h, pa_l, pb_h, pb_l, 32, acc);
  int r = lane & 31, g = lane >> 5;
  int n = ct * 32 + r;
  if (ct < 16) {
    float bn = b_h[n];
#pragma unroll
    for (int rr = 0; rr < 16; ++rr)
      h0f[CD_ROW(rr, g) * 512 + n] = acc[rr] + bn;
  } else {
    int n2 = n - 512;
    float bn = b_c[n2];
#pragma unroll
    for (int rr = 0; rr < 16; ++rr)
      cbuf[CD_ROW(rr, g) * 512 + n2] = acc[rr] + bn;
  }
}

// ---------------- embproj = embF @ W_ih[:512] + b_ih + b_hh (MFMA) ----------------
__global__ __launch_bounds__(256) void m_emb(
    const ushort_t* __restrict__ eFhi, const ushort_t* __restrict__ eFlo,
    const ushort_t* __restrict__ Whi, const ushort_t* __restrict__ Wlo,
    const float* __restrict__ b1, const float* __restrict__ b2,
    float* __restrict__ embproj)
{
  int w = threadIdx.x >> 6, lane = threadIdx.x & 63;
  int mt = blockIdx.y;                 // 39 timesteps
  int ct = blockIdx.x * 4 + w;         // 64 col-tiles
  const ushort_t* pa_h = eFhi + ((size_t)mt * 32) * 512 + lane * 8;
  const ushort_t* pa_l = eFlo + ((size_t)mt * 32) * 512 + lane * 8;
  const ushort_t* pb_h = Whi + ((size_t)ct * 32) * 512 + lane * 8;
  const ushort_t* pb_l = Wlo + ((size_t)ct * 32) * 512 + lane * 8;
  f16v acc = (f16v)(0.0f);
  mfma_pipe_frag(pa_h, pa_l, pb_h, pb_l, 8, acc);
  int r = lane & 31, g = lane >> 5;
  int n = ct * 32 + r;
  float bn = b1[n] + b2[n];
#pragma unroll
  for (int rr = 0; rr < 16; ++rr)
    embproj[(size_t)(mt * 32 + CD_ROW(rr, g)) * 2048 + n] = acc[rr] + bn;
}

// ---------------- h0 -> h frag + x frag (h cols) ----------------
__global__ __launch_bounds__(256) void hsplit_frag(
    const float* __restrict__ h0f,
    ushort_t* __restrict__ hhi, ushort_t* __restrict__ hlo,
    ushort_t* __restrict__ xhi, ushort_t* __restrict__ xlo)
{
  int idx = blockIdx.x * 256 + threadIdx.x;  // 2048: b*64 + dq
  int b = idx >> 6, dq = idx & 63, d0 = dq << 3;
  ushort4 h0v, h1v, l0v, l1v;
  ushort_t hh[8], hl[8];
#pragma unroll
  for (int j = 0; j < 8; ++j) {
    float v = h0f[b * 512 + d0 + j];
    hh[j] = f2bf(v); hl[j] = f2bf(v - bf2f(hh[j]));
  }
  h0v = make_ushort4(hh[0], hh[1], hh[2], hh[3]); h1v = make_ushort4(hh[4], hh[5], hh[6], hh[7]);
  l0v = make_ushort4(hl[0], hl[1], hl[2], hl[3]); l1v = make_ushort4(hl[4], hl[5], hl[6], hl[7]);
  int kc = d0 >> 4, g = (d0 >> 3) & 1;
  size_t off = ((size_t)kc * 64 + g * 32 + b) * 8;
  *(ushort4*)&hhi[off] = h0v; *(ushort4*)&hhi[off + 4] = h1v;
  *(ushort4*)&hlo[off] = l0v; *(ushort4*)&hlo[off + 4] = l1v;
  int xk0 = 2048 + d0;
  size_t offx = ((size_t)(xk0 >> 4) * 64 + g * 32 + b) * 8;
  *(ushort4*)&xhi[offx] = h0v; *(ushort4*)&xhi[offx + 4] = h1v;
  *(ushort4*)&xlo[offx] = l0v; *(ushort4*)&xlo[offx + 4] = l1v;
}

// ---------------- k2a: e + softmax, coalesced via encatt_t[b][a][p] ----------------
__global__ __launch_bounds__(256) void k2a_soft(
    const float* __restrict__ dec_gate, const float* __restrict__ bdec,
    const float* __restrict__ watt, const float* __restrict__ batt,
    const float* __restrict__ encatt_t, const int* __restrict__ clen,
    float* __restrict__ outa, float* __restrict__ al_ws, int t)
{
  int b = blockIdx.x, tid = threadIdx.x;
  __shared__ float dec_s[512], watt_s[512], red_s[256];
  for (int a = tid; a < 512; a += 256) {
    dec_s[a] = dec_gate[b * 2560 + a] + bdec[a];
    watt_s[a] = watt[a];
  }
  __syncthreads();
  float e = -1e30f;
  if (tid < NP) {
    const float* col = encatt_t + (size_t)b * 512 * 196 + tid;
    float acc = 0.f;
#pragma unroll 8
    for (int a = 0; a < 512; ++a)
      acc += fmaxf(col[(size_t)a * 196] + dec_s[a], 0.f) * watt_s[a];
    e = acc + batt[0];
  }
  red_s[tid] = e;
  __syncthreads();
  for (int w = 128; w > 0; w >>= 1) {
    if (tid < w) red_s[tid] = fmaxf(red_s[tid], red_s[tid + w]);
    __syncthreads();
  }
  float m = red_s[0];
  __syncthreads();
  float ex = (tid < NP) ? expf(e - m) : 0.f;
  red_s[tid] = ex;
  __syncthreads();
  for (int w = 128; w > 0; w >>= 1) {
    if (tid < w) red_s[tid] += red_s[tid + w];
    __syncthreads();
  }
  float inv = 1.f / red_s[0];
  if (tid < NP) {
    float al = ex * inv;
    al_ws[b * NP + tid] = al;
    bool act = clen[b] - 1 > t;
    outa[(size_t)(b * TS + t) * NP + tid] = act ? al : 0.f;
  }
}

// ---------------- k2b: awe + gate -> x frag cols 0..2047 (grid 32 x 8) ----------------
__global__ __launch_bounds__(256) void k2b_awe(
    const float* __restrict__ al_ws, const float* __restrict__ dec_gate,
    const float* __restrict__ bfb, const float* __restrict__ enc,
    ushort_t* __restrict__ xhi, ushort_t* __restrict__ xlo)
{
  int b = blockIdx.x, ds = blockIdx.y, tid = threadIdx.x;
  __shared__ float al_s[196];
  __shared__ float part[4][64][4];
  if (tid < NP) al_s[tid] = al_ws[b * NP + tid];
  __syncthreads();
  int q = tid & 63, sp = tid >> 6;
  int d = ds * 256 + q * 4;
  float ax = 0.f, ay = 0.f, az = 0.f, aw = 0.f;
  int p0 = sp * 49;
#pragma unroll 7
  for (int p = p0; p < p0 + 49; ++p) {
    float al = al_s[p];
    float4 ev = *(const float4*)&enc[(size_t)(b * NP + p) * ENC + d];
    ax += al * ev.x; ay += al * ev.y; az += al * ev.z; aw += al * ev.w;
  }
  part[sp][q][0] = ax; part[sp][q][1] = ay; part[sp][q][2] = az; part[sp][q][3] = aw;
  __syncthreads();
  if (sp == 0) {
    ax = part[0][q][0] + part[1][q][0] + part[2][q][0] + part[3][q][0];
    ay = part[0][q][1] + part[1][q][1] + part[2][q][1] + part[3][q][1];
    az = part[0][q][2] + part[1][q][2] + part[2][q][2] + part[3][q][2];
    aw = part[0][q][3] + part[1][q][3] + part[2][q][3] + part[3][q][3];
    float4 gg = *(const float4*)&dec_gate[b * 2560 + 512 + d];
    float4 bb = *(const float4*)&bfb[d];
    float v0 = sigm(gg.x + bb.x) * ax;
    float v1 = sigm(gg.y + bb.y) * ay;
    float v2 = sigm(gg.z + bb.z) * az;
    float v3 = sigm(gg.w + bb.w) * aw;
    ushort4 hi, lo;
    hi.x = f2bf(v0); lo.x = f2bf(v0 - bf2f(hi.x));
    hi.y = f2bf(v1); lo.y = f2bf(v1 - bf2f(hi.y));
    hi.z = f2bf(v2); lo.z = f2bf(v2 - bf2f(hi.z));
    hi.w = f2bf(v3); lo.w = f2bf(v3 - bf2f(hi.w));
    size_t off = ((size_t)(d >> 4) * 64 + ((d >> 3) & 1) * 32 + b) * 8 + (d & 7);
    *(ushort4*)&xhi[off] = hi;
    *(ushort4*)&xlo[off] = lo;
  }
}

// ---------------- k4: LSTM pointwise + state update (frag writes) ----------------
__global__ __launch_bounds__(256) void k4_lstm_frag(
    const float* __restrict__ P2, const float* __restrict__ embproj,
    const int* __restrict__ clen, float* __restrict__ c,
    ushort_t* __restrict__ hhi, ushort_t* __restrict__ hlo,
    ushort_t* __restrict__ xhi, ushort_t* __restrict__ xlo, int t)
{
  int idx = blockIdx.x * 256 + threadIdx.x;  // 2048: b*64 + dq
  int b = idx >> 6, dq = idx & 63, d0 = dq << 3;
  if (clen[b] - 1 <= t) return;              // inactive rows freeze
  const float* ep = embproj + (size_t)(t * 32 + b) * 2048;
  f4v i0 = *(const f4v*)&ep[d0],        i1 = *(const f4v*)&ep[d0 + 4];
  f4v f0 = *(const f4v*)&ep[512 + d0],  f1 = *(const f4v*)&ep[512 + d0 + 4];
  f4v g0 = *(const f4v*)&ep[1024 + d0], g1 = *(const f4v*)&ep[1024 + d0 + 4];
  f4v o0 = *(const f4v*)&ep[1536 + d0], o1 = *(const f4v*)&ep[1536 + d0 + 4];
#pragma unroll
  for (int s = 0; s < 8; ++s) {
    const float* p2 = P2 + (size_t)s * 65536 + b * 2048;
    i0 += *(const f4v*)&p2[d0];        i1 += *(const f4v*)&p2[d0 + 4];
    f0 += *(const f4v*)&p2[512 + d0];  f1 += *(const f4v*)&p2[512 + d0 + 4];
    g0 += *(const f4v*)&p2[1024 + d0]; g1 += *(const f4v*)&p2[1024 + d0 + 4];
    o0 += *(const f4v*)&p2[1536 + d0]; o1 += *(const f4v*)&p2[1536 + d0 + 4];
  }
  f4v c0 = *(const f4v*)&c[b * 512 + d0], c1 = *(const f4v*)&c[b * 512 + d0 + 4];
  ushort_t hh[8], hl[8];
  f4v cn0, cn1;
#pragma unroll
  for (int j = 0; j < 8; ++j) {
    float iv = j < 4 ? i0[j] : i1[j - 4];
    float fv = j < 4 ? f0[j] : f1[j - 4];
    float gv = j < 4 ? g0[j] : g1[j - 4];
    float ov = j < 4 ? o0[j] : o1[j - 4];
    float cv = j < 4 ? c0[j] : c1[j - 4];
    float cn = sigm(fv) * cv + sigm(iv) * tanhf(gv);
    float hn = sigm(ov) * tanhf(cn);
    if (j < 4) cn0[j] = cn; else cn1[j - 4] = cn;
    hh[j] = f2bf(hn); hl[j] = f2bf(hn - bf2f(hh[j]));
  }
  *(f4v*)&c[b * 512 + d0] = cn0; *(f4v*)&c[b * 512 + d0 + 4] = cn1;
  ushort4 h0v = make_ushort4(hh[0], hh[1], hh[2], hh[3]);
  ushort4 h1v = make_ushort4(hh[4], hh[5], hh[6], hh[7]);
  ushort4 l0v = make_ushort4(hl[0], hl[1], hl[2], hl[3]);
  ushort4 l1v = make_ushort4(hl[4], hl[5], hl[6], hl[7]);
  int kc = d0 >> 4, g = (d0 >> 3) & 1;
  size_t off = ((size_t)kc * 64 + g * 32 + b) * 8;
  *(ushort4*)&hhi[off] = h0v; *(ushort4*)&hhi[off + 4] = h1v;
  *(ushort4*)&hlo[off] = l0v; *(ushort4*)&hlo[off + 4] = l1v;
  int xk0 = 2048 + d0;
  size_t offx = ((size_t)(xk0 >> 4) * 64 + g * 32 + b) * 8;
  *(ushort4*)&xhi[offx] = h0v; *(ushort4*)&xhi[offx + 4] = h1v;
  *(ushort4*)&xlo[offx] = l0v; *(ushort4*)&xlo[offx + 4] = l1v;
}

// =====================================================================
extern "C" void kernel_launch(void* const* d_in, const int* in_sizes, int n_in,
                              void* d_out, int out_size, void* d_ws, size_t ws_size,
                              hipStream_t stream)
{
  (void)in_sizes; (void)n_in; (void)out_size; (void)ws_size;
  const float* enc   = (const float*)d_in[0];
  const int*   caps  = (const int*)d_in[1];
  const int*   clen  = (const int*)d_in[2];
  const float* emb   = (const float*)d_in[3];
  const float* W_enc = (const float*)d_in[4];
  const float* b_enc = (const float*)d_in[5];
  const float* W_dec = (const float*)d_in[6];
  const float* b_dec = (const float*)d_in[7];
  const float* w_att = (const float*)d_in[8];
  const float* b_att = (const float*)d_in[9];
  const float* W_ih  = (const float*)d_in[10];
  const float* b_ih  = (const float*)d_in[11];
  const float* W_hh  = (const float*)d_in[12];
  const float* b_hh  = (const float*)d_in[13];
  const float* W_h   = (const float*)d_in[14];
  const float* b_h   = (const float*)d_in[15];
  const float* W_c   = (const float*)d_in[16];
  const float* b_c   = (const float*)d_in[17];
  const float* W_fb  = (const float*)d_in[18];
  const float* b_fb  = (const float*)d_in[19];
  const float* W_fc  = (const float*)d_in[20];
  const float* b_fc  = (const float*)d_in[21];

  float* out_preds = (float*)d_out;
  float* out_alpha = out_preds + (size_t)NB * TS * VOC;

  // ---------- workspace layout (within proven 173,539,328-byte footprint) ----------
  char* p = (char*)d_ws;
  float* encatt_t = (float*)p;            p += 12845056;   // 32*512*196 f32 (transposed)
  float* embproj  = (float*)p;            p += 10223616;   // 1248*2048 f32; first 256KB doubles as avg frag (prologue)
  float* P2buf    = (float*)p;            p += 2097152;    // 8*32*2048 f32
  float* dec_gate = (float*)p;            p += 327680;     // 32*2560 f32
  ushort_t* x_lo  = (ushort_t*)p;         p += 262144;     // 32*2560 bf16 frag
  float* h0f      = (float*)p;            p += 65536;      // 32*512 f32
  float* cbuf     = (float*)p;            p += 65536;      // 32*512 f32
  float* al_ws    = (float*)p;            p += 25088;      // 32*196 f32
  ushort_t* h_hi  = (ushort_t*)p;         p += 32768;      // 32*512 bf16 frag
  ushort_t* h_lo  = (ushort_t*)p;         p += 32768;
  ushort_t* x_hi  = (ushort_t*)p;         p += 163840;     // 32*2560 bf16 frag
  p += 262144 - 25088 - 32768 - 32768 - 163840;
  ushort_t* e_hi  = (ushort_t*)p;         p += 25690112;   // enc frag
  ushort_t* e_lo  = (ushort_t*)p;         p += 25690112;
  ushort_t* We_hi = (ushort_t*)p;         p += 2097152;    // 16 tiles x 128 kc
  ushort_t* We_lo = (ushort_t*)p;         p += 2097152;
  ushort_t* W1_hi = (ushort_t*)p;         p += 2621440;    // 80 tiles x 32 kc
  ushort_t* W1_lo = (ushort_t*)p;         p += 2621440;
  ushort_t* W3_hi = (ushort_t*)p;         p += 10485760;   // 64 tiles x 160 kc
  ushort_t* W3_lo = (ushort_t*)p;         p += 10485760;
  ushort_t* Wf_hi = (ushort_t*)p;         p += 32768000;   // 1000 tiles x 32 kc (hi only)
  // former Wf_lo region -> emb-path buffers:
  ushort_t* WiE_hi = (ushort_t*)p;        p += 2097152;    // 64 tiles x 32 kc
  ushort_t* WiE_lo = (ushort_t*)p;        p += 2097152;
  ushort_t* eF_hi  = (ushort_t*)p;        p += 1277952;    // 39 mt x 32 kc
  ushort_t* eF_lo  = (ushort_t*)p;        p += 1277952;

  // prologue-only aliases (regions rewritten later, stream-ordered):
  ushort_t* avg_hi = (ushort_t*)embproj;              // 32x2048 frag (128 KB)
  ushort_t* avg_lo = avg_hi + 65536;                  // +128 KB (embproj written later)
  ushort_t* Whc_hi = Wf_hi;                           // 32 tiles x 128 kc (4 MB)
  ushort_t* Whc_lo = Wf_hi + 2097152;                 // +4 MB (Wf written later)

  // ---------------- prologue ----------------
  mavg_frag<<<dim3(32, 8), 256, 0, stream>>>(enc, avg_hi, avg_lo);
  convT_frag<<<dim3(16, 32), 256, 0, stream>>>(W_h, 512, Whc_hi, Whc_lo, 128, 0);
  convT_frag<<<dim3(16, 32), 256, 0, stream>>>(W_c, 512,
      Whc_hi + (size_t)16 * 128 * 512, Whc_lo + (size_t)16 * 128 * 512, 128, 0);
  mh0c0<<<dim3(8), 256, 0, stream>>>(avg_hi, avg_lo, Whc_hi, Whc_lo, b_h, b_c, h0f, cbuf);
  convA_frag<<<dim3(196, 32), 256, 0, stream>>>(enc, e_hi, e_lo);
  convT_frag<<<dim3(16, 32), 256, 0, stream>>>(W_enc, 512, We_hi, We_lo, 128, 0);
  convT_frag<<<dim3(16, 8), 256, 0, stream>>>(W_dec, 512, W1_hi, W1_lo, 32, 0);
  convT_frag<<<dim3(64, 8), 256, 0, stream>>>(W_fb, 2048,
      W1_hi + (size_t)16 * 32 * 512, W1_lo + (size_t)16 * 32 * 512, 32, 0);
  convT_frag<<<dim3(64, 32), 256, 0, stream>>>(W_ih + (size_t)512 * 2048, 2048,
      W3_hi, W3_lo, 160, 0);
  convT_frag<<<dim3(64, 8), 256, 0, stream>>>(W_hh, 2048, W3_hi, W3_lo, 160, 128);
  convT_fragH<<<dim3(1000, 8), 256, 0, stream>>>(W_fc, VOC, Wf_hi, 32, 0);  // after mh0c0
  convA_emb_frag<<<dim3(39, 8), 256, 0, stream>>>(emb, caps, eF_hi, eF_lo);
  convT_frag<<<dim3(64, 8), 256, 0, stream>>>(W_ih, 2048, WiE_hi, WiE_lo, 32, 0);

  menc_att<<<dim3(4, 196), 256, 0, stream>>>(e_hi, e_lo, We_hi, We_lo, b_enc, encatt_t);
  m_emb<<<dim3(16, 39), 256, 0, stream>>>(eF_hi, eF_lo, WiE_hi, WiE_lo, b_ih, b_hh, embproj);
  hsplit_frag<<<dim3(8), 256, 0, stream>>>(h0f, h_hi, h_lo, x_hi, x_lo);
  mk1<<<dim3(20), 256, 0, stream>>>(h_hi, h_lo, W1_hi, W1_lo, dec_gate);

  // ---------------- decode loop ----------------
  for (int t = 0; t < TS; ++t) {
    k2a_soft<<<dim3(32), 256, 0, stream>>>(dec_gate, b_dec, w_att, b_att,
                                           encatt_t, clen, out_alpha, al_ws, t);
    k2b_awe<<<dim3(32, 8), 256, 0, stream>>>(al_ws, dec_gate, b_fb, enc, x_hi, x_lo);
    mk3<<<dim3(16, 8), 256, 0, stream>>>(x_hi, x_lo, W3_hi, W3_lo, P2buf);
    k4_lstm_frag<<<dim3(8), 256, 0, stream>>>(P2buf, embproj, clen, cbuf,
                                              h_hi, h_lo, x_hi, x_lo, t);
    mkm<<<dim3(270), 256, 0, stream>>>(h_hi, h_lo, Wf_hi, b_fc, clen, out_preds, t,
                                       W1_hi, W1_lo, dec_gate, (t < TS - 1) ? 1 : 0);
  }
}

// Round 9
// 2233.925 us; speedup vs baseline: 1.2587x; 1.2020x over previous
//
#include <hip/hip_runtime.h>
#include <math.h>

#define NB 32
#define NP 196
#define ENC 2048
#define VOC 32000
#define LCAP 40
#define TS 39

typedef unsigned int uint_t;
typedef unsigned short ushort_t;

__device__ __forceinline__ float sigm(float x) { return 1.f / (1.f + expf(-x)); }

// ---------- bf16 helpers (RNE) ----------
__device__ __forceinline__ ushort_t f2bf(float f) {
  uint_t u = __float_as_uint(f);
  u = (u + 0x7FFFu + ((u >> 16) & 1u)) >> 16;
  return (ushort_t)u;
}
__device__ __forceinline__ float bf2f(ushort_t s) { return __uint_as_float(((uint_t)s) << 16); }

typedef __attribute__((ext_vector_type(8))) short bf8v;
typedef __attribute__((ext_vector_type(16))) float f16v;
typedef __attribute__((ext_vector_type(4))) float f4v;

__device__ __forceinline__ f16v MFMA(bf8v a, bf8v b, f16v c) {
  return __builtin_amdgcn_mfma_f32_32x32x16_bf16(a, b, c, 0, 0, 0);
}

// =====================================================================
// FRAGMENT LAYOUT: [tile][k_chunk][lane][8] ushorts; chunk = 512 ushorts.
// =====================================================================
// split-bf16 (3 MFMA/chunk): f32-class precision (recurrent paths)
__device__ __forceinline__ void mfma_pipe_frag(
    const ushort_t* __restrict__ pa_h, const ushort_t* __restrict__ pa_l,
    const ushort_t* __restrict__ pb_h, const ushort_t* __restrict__ pb_l,
    int nquad, f16v& acc)
{
  bf8v ah0 = *(const bf8v*)(pa_h +    0), al0 = *(const bf8v*)(pa_l +    0);
  bf8v bh0 = *(const bf8v*)(pb_h +    0), bl0 = *(const bf8v*)(pb_l +    0);
  bf8v ah1 = *(const bf8v*)(pa_h +  512), al1 = *(const bf8v*)(pa_l +  512);
  bf8v bh1 = *(const bf8v*)(pb_h +  512), bl1 = *(const bf8v*)(pb_l +  512);
  bf8v ah2 = *(const bf8v*)(pa_h + 1024), al2 = *(const bf8v*)(pa_l + 1024);
  bf8v bh2 = *(const bf8v*)(pb_h + 1024), bl2 = *(const bf8v*)(pb_l + 1024);
  bf8v ah3 = *(const bf8v*)(pa_h + 1536), al3 = *(const bf8v*)(pa_l + 1536);
  bf8v bh3 = *(const bf8v*)(pb_h + 1536), bl3 = *(const bf8v*)(pb_l + 1536);
  for (int q = 0; q < nquad; ++q) {
    const size_t nk = (size_t)(q + 1) * 2048;
    const bool more = (q + 1 < nquad);
    acc = MFMA(ah0, bh0, acc); acc = MFMA(ah0, bl0, acc); acc = MFMA(al0, bh0, acc);
    if (more) {
      ah0 = *(const bf8v*)(pa_h + nk +    0); al0 = *(const bf8v*)(pa_l + nk +    0);
      bh0 = *(const bf8v*)(pb_h + nk +    0); bl0 = *(const bf8v*)(pb_l + nk +    0);
    }
    acc = MFMA(ah1, bh1, acc); acc = MFMA(ah1, bl1, acc); acc = MFMA(al1, bh1, acc);
    if (more) {
      ah1 = *(const bf8v*)(pa_h + nk +  512); al1 = *(const bf8v*)(pa_l + nk +  512);
      bh1 = *(const bf8v*)(pb_h + nk +  512); bl1 = *(const bf8v*)(pb_l + nk +  512);
    }
    acc = MFMA(ah2, bh2, acc); acc = MFMA(ah2, bl2, acc); acc = MFMA(al2, bh2, acc);
    if (more) {
      ah2 = *(const bf8v*)(pa_h + nk + 1024); al2 = *(const bf8v*)(pa_l + nk + 1024);
      bh2 = *(const bf8v*)(pb_h + nk + 1024); bl2 = *(const bf8v*)(pb_l + nk + 1024);
    }
    acc = MFMA(ah3, bh3, acc); acc = MFMA(ah3, bl3, acc); acc = MFMA(al3, bh3, acc);
    if (more) {
      ah3 = *(const bf8v*)(pa_h + nk + 1536); al3 = *(const bf8v*)(pa_l + nk + 1536);
      bh3 = *(const bf8v*)(pb_h + nk + 1536); bl3 = *(const bf8v*)(pb_l + nk + 1536);
    }
  }
}

// B-hi-only (2 MFMA/chunk): non-recurrent preds path
__device__ __forceinline__ void mfma_pipe_fragBH(
    const ushort_t* __restrict__ pa_h, const ushort_t* __restrict__ pa_l,
    const ushort_t* __restrict__ pb_h, int nquad, f16v& acc)
{
  bf8v ah0 = *(const bf8v*)(pa_h +    0), al0 = *(const bf8v*)(pa_l +    0);
  bf8v bh0 = *(const bf8v*)(pb_h +    0);
  bf8v ah1 = *(const bf8v*)(pa_h +  512), al1 = *(const bf8v*)(pa_l +  512);
  bf8v bh1 = *(const bf8v*)(pb_h +  512);
  bf8v ah2 = *(const bf8v*)(pa_h + 1024), al2 = *(const bf8v*)(pa_l + 1024);
  bf8v bh2 = *(const bf8v*)(pb_h + 1024);
  bf8v ah3 = *(const bf8v*)(pa_h + 1536), al3 = *(const bf8v*)(pa_l + 1536);
  bf8v bh3 = *(const bf8v*)(pb_h + 1536);
  for (int q = 0; q < nquad; ++q) {
    const size_t nk = (size_t)(q + 1) * 2048;
    const bool more = (q + 1 < nquad);
    acc = MFMA(ah0, bh0, acc); acc = MFMA(al0, bh0, acc);
    if (more) {
      ah0 = *(const bf8v*)(pa_h + nk +    0); al0 = *(const bf8v*)(pa_l + nk +    0);
      bh0 = *(const bf8v*)(pb_h + nk +    0);
    }
    acc = MFMA(ah1, bh1, acc); acc = MFMA(al1, bh1, acc);
    if (more) {
      ah1 = *(const bf8v*)(pa_h + nk +  512); al1 = *(const bf8v*)(pa_l + nk +  512);
      bh1 = *(const bf8v*)(pb_h + nk +  512);
    }
    acc = MFMA(ah2, bh2, acc); acc = MFMA(al2, bh2, acc);
    if (more) {
      ah2 = *(const bf8v*)(pa_h + nk + 1024); al2 = *(const bf8v*)(pa_l + nk + 1024);
      bh2 = *(const bf8v*)(pb_h + nk + 1024);
    }
    acc = MFMA(ah3, bh3, acc); acc = MFMA(al3, bh3, acc);
    if (more) {
      ah3 = *(const bf8v*)(pa_h + nk + 1536); al3 = *(const bf8v*)(pa_l + nk + 1536);
      bh3 = *(const bf8v*)(pb_h + nk + 1536);
    }
  }
}

// C/D mapping (HW-verified): col = lane&31, row = (reg&3)+8*(reg>>2)+4*(lane>>5)
#define CD_ROW(rr, g) (((rr) & 3) + 8 * ((rr) >> 2) + 4 * (g))

// ---------------- enc_att -> encatt_bf[b][a][p] (bf16), LDS-staged transpose ----------------
__global__ __launch_bounds__(256) void menc_att(
    const ushort_t* __restrict__ Ahi, const ushort_t* __restrict__ Alo,
    const ushort_t* __restrict__ Whi, const ushort_t* __restrict__ Wlo,
    const float* __restrict__ benc, ushort_t* __restrict__ encatt_bf)
{
  __shared__ float tileS[4][32][33];
  int w = threadIdx.x >> 6, lane = threadIdx.x & 63;
  int mt = blockIdx.y;                 // 196 m-tiles
  int ct = blockIdx.x * 4 + w;         // 16 col-tiles
  const ushort_t* pa_h = Ahi + ((size_t)mt * 128) * 512 + lane * 8;
  const ushort_t* pa_l = Alo + ((size_t)mt * 128) * 512 + lane * 8;
  const ushort_t* pb_h = Whi + ((size_t)ct * 128) * 512 + lane * 8;
  const ushort_t* pb_l = Wlo + ((size_t)ct * 128) * 512 + lane * 8;
  f16v acc = (f16v)(0.0f);
  mfma_pipe_frag(pa_h, pa_l, pb_h, pb_l, 32, acc);
  int r = lane & 31, g = lane >> 5;
  float bn = benc[ct * 32 + r];
#pragma unroll
  for (int rr = 0; rr < 16; ++rr)
    tileS[w][r][CD_ROW(rr, g)] = acc[rr] + bn;   // [a_local][p_local]
  __syncthreads();
#pragma unroll
  for (int j = 0; j < 4; ++j) {
    int a_l = j * 8 + (lane >> 3);
    int p4 = (lane & 7) * 4;
    int n2 = ct * 32 + a_l;
#pragma unroll
    for (int jj = 0; jj < 4; ++jj) {
      int pl = p4 + jj;
      int rg = mt * 32 + pl;
      int b = rg / 196, pp = rg - b * 196;
      encatt_bf[((size_t)b * 512 + n2) * 196 + pp] = f2bf(tileS[w][a_l][pl]);
    }
  }
}

// ---------------- k1: dec_gate = h @ [W_dec | W_fb] ----------------
__global__ __launch_bounds__(256) void mk1(
    const ushort_t* __restrict__ hhi, const ushort_t* __restrict__ hlo,
    const ushort_t* __restrict__ W1hi, const ushort_t* __restrict__ W1lo,
    float* __restrict__ dec_gate)
{
  int w = threadIdx.x >> 6, lane = threadIdx.x & 63;
  int ct = blockIdx.x * 4 + w;         // 80 col-tiles
  const ushort_t* pa_h = hhi + lane * 8;
  const ushort_t* pa_l = hlo + lane * 8;
  const ushort_t* pb_h = W1hi + ((size_t)ct * 32) * 512 + lane * 8;
  const ushort_t* pb_l = W1lo + ((size_t)ct * 32) * 512 + lane * 8;
  f16v acc = (f16v)(0.0f);
  mfma_pipe_frag(pa_h, pa_l, pb_h, pb_l, 8, acc);
  int r = lane & 31, g = lane >> 5;
  int n = ct * 32 + r;
#pragma unroll
  for (int rr = 0; rr < 16; ++rr)
    dec_gate[CD_ROW(rr, g) * 2560 + n] = acc[rr];
}

// ---------------- k3: P2[s] = partial of x(=[aweg|h]) @ W3 ----------------
__global__ __launch_bounds__(256) void mk3(
    const ushort_t* __restrict__ xhi, const ushort_t* __restrict__ xlo,
    const ushort_t* __restrict__ W3hi, const ushort_t* __restrict__ W3lo,
    float* __restrict__ P2)
{
  int w = threadIdx.x >> 6, lane = threadIdx.x & 63;
  int ct = blockIdx.x * 4 + w;         // 64 col-tiles
  int s = blockIdx.y;                  // 8 k-slices of 20 chunks
  const ushort_t* pa_h = xhi + ((size_t)s * 20) * 512 + lane * 8;
  const ushort_t* pa_l = xlo + ((size_t)s * 20) * 512 + lane * 8;
  const ushort_t* pb_h = W3hi + ((size_t)ct * 160 + s * 20) * 512 + lane * 8;
  const ushort_t* pb_l = W3lo + ((size_t)ct * 160 + s * 20) * 512 + lane * 8;
  f16v acc = (f16v)(0.0f);
  mfma_pipe_frag(pa_h, pa_l, pb_h, pb_l, 5, acc);
  int r = lane & 31, g = lane >> 5;
  int n = ct * 32 + r;
#pragma unroll
  for (int rr = 0; rr < 16; ++rr)
    P2[(size_t)s * (32 * 2048) + CD_ROW(rr, g) * 2048 + n] = acc[rr];
}

// ---------------- mpreds (deferred): preds[b][mt][:] = h_hist[mt] @ Wfc + bfc ----------------
__global__ __launch_bounds__(256) void mpreds(
    const ushort_t* __restrict__ hhist_hi, const ushort_t* __restrict__ hhist_lo,
    const ushort_t* __restrict__ Wfchi, const float* __restrict__ bfc,
    const int* __restrict__ clen, float* __restrict__ outp)
{
  int mt = blockIdx.x;                 // 39 timesteps (fastest -> Wfc tile L2 reuse)
  int w = threadIdx.x >> 6, lane = threadIdx.x & 63;
  int ct = blockIdx.y * 4 + w;         // 1000 col-tiles
  const ushort_t* pa_h = hhist_hi + ((size_t)mt * 32) * 512 + lane * 8;
  const ushort_t* pa_l = hhist_lo + ((size_t)mt * 32) * 512 + lane * 8;
  const ushort_t* pb_h = Wfchi + ((size_t)ct * 32) * 512 + lane * 8;
  f16v acc = (f16v)(0.0f);
  mfma_pipe_fragBH(pa_h, pa_l, pb_h, 8, acc);
  int r = lane & 31, g = lane >> 5;
  int n = ct * 32 + r;
  float bn = bfc[n];
#pragma unroll
  for (int rr = 0; rr < 16; ++rr) {
    int b = CD_ROW(rr, g);
    bool act = clen[b] - 1 > mt;
    outp[(size_t)b * (TS * VOC) + (size_t)mt * VOC + n] = act ? (acc[rr] + bn) : 0.f;
  }
}

// ---------------- conversions into frag layout ----------------
__global__ __launch_bounds__(256) void convA_frag(
    const float* __restrict__ src, ushort_t* __restrict__ dhi, ushort_t* __restrict__ dlo)
{
  int mt = blockIdx.x;
  int kc = blockIdx.y * 4 + (threadIdx.x >> 6);
  int l = threadIdx.x & 63;
  int r = l & 31, g = l >> 5;
  const float* s = src + (size_t)(mt * 32 + r) * 2048 + kc * 16 + g * 8;
  float4 v0 = *(const float4*)s, v1 = *(const float4*)(s + 4);
  ushort4 h0, l0, h1, l1;
  h0.x = f2bf(v0.x); l0.x = f2bf(v0.x - bf2f(h0.x));
  h0.y = f2bf(v0.y); l0.y = f2bf(v0.y - bf2f(h0.y));
  h0.z = f2bf(v0.z); l0.z = f2bf(v0.z - bf2f(h0.z));
  h0.w = f2bf(v0.w); l0.w = f2bf(v0.w - bf2f(h0.w));
  h1.x = f2bf(v1.x); l1.x = f2bf(v1.x - bf2f(h1.x));
  h1.y = f2bf(v1.y); l1.y = f2bf(v1.y - bf2f(h1.y));
  h1.z = f2bf(v1.z); l1.z = f2bf(v1.z - bf2f(h1.z));
  h1.w = f2bf(v1.w); l1.w = f2bf(v1.w - bf2f(h1.w));
  size_t off = ((size_t)mt * 128 + kc) * 512 + (size_t)l * 8;
  *(ushort4*)&dhi[off] = h0; *(ushort4*)&dhi[off + 4] = h1;
  *(ushort4*)&dlo[off] = l0; *(ushort4*)&dlo[off + 4] = l1;
}

// gathered embedding rows -> A-frag: tile mt = timestep, row = batch
__global__ __launch_bounds__(256) void convA_emb_frag(
    const float* __restrict__ Emb, const int* __restrict__ caps,
    ushort_t* __restrict__ dhi, ushort_t* __restrict__ dlo)
{
  int mt = blockIdx.x;
  int kc = blockIdx.y * 4 + (threadIdx.x >> 6);
  int l = threadIdx.x & 63;
  int r = l & 31, g = l >> 5;
  int tok = caps[r * LCAP + mt];
  const float* s = Emb + (size_t)tok * 512 + kc * 16 + g * 8;
  float4 v0 = *(const float4*)s, v1 = *(const float4*)(s + 4);
  ushort4 h0, l0, h1, l1;
  h0.x = f2bf(v0.x); l0.x = f2bf(v0.x - bf2f(h0.x));
  h0.y = f2bf(v0.y); l0.y = f2bf(v0.y - bf2f(h0.y));
  h0.z = f2bf(v0.z); l0.z = f2bf(v0.z - bf2f(h0.z));
  h0.w = f2bf(v0.w); l0.w = f2bf(v0.w - bf2f(h0.w));
  h1.x = f2bf(v1.x); l1.x = f2bf(v1.x - bf2f(h1.x));
  h1.y = f2bf(v1.y); l1.y = f2bf(v1.y - bf2f(h1.y));
  h1.z = f2bf(v1.z); l1.z = f2bf(v1.z - bf2f(h1.z));
  h1.w = f2bf(v1.w); l1.w = f2bf(v1.w - bf2f(h1.w));
  size_t off = ((size_t)mt * 32 + kc) * 512 + (size_t)l * 8;
  *(ushort4*)&dhi[off] = h0; *(ushort4*)&dhi[off + 4] = h1;
  *(ushort4*)&dlo[off] = l0; *(ushort4*)&dlo[off + 4] = l1;
}

// W [K][N] f32 -> B-frag tiles (hi+lo)
__global__ __launch_bounds__(256) void convT_frag(
    const float* __restrict__ src, int N,
    ushort_t* __restrict__ dhi, ushort_t* __restrict__ dlo,
    int nkc_dst, int kc_off)
{
  int ct = blockIdx.x;
  int kc = blockIdx.y * 4 + (threadIdx.x >> 6);
  int l = threadIdx.x & 63;
  int c = l & 31, g = l >> 5;
  const float* s = src + (size_t)(kc * 16 + g * 8) * N + ct * 32 + c;
  ushort_t hi8[8], lo8[8];
#pragma unroll
  for (int e = 0; e < 8; ++e) {
    float f = s[(size_t)e * N];
    hi8[e] = f2bf(f); lo8[e] = f2bf(f - bf2f(hi8[e]));
  }
  size_t off = ((size_t)ct * nkc_dst + kc_off + kc) * 512 + (size_t)l * 8;
  *(ushort4*)&dhi[off]     = make_ushort4(hi8[0], hi8[1], hi8[2], hi8[3]);
  *(ushort4*)&dhi[off + 4] = make_ushort4(hi8[4], hi8[5], hi8[6], hi8[7]);
  *(ushort4*)&dlo[off]     = make_ushort4(lo8[0], lo8[1], lo8[2], lo8[3]);
  *(ushort4*)&dlo[off + 4] = make_ushort4(lo8[4], lo8[5], lo8[6], lo8[7]);
}

// W [K][N] f32 -> B-frag tiles (hi only)
__global__ __launch_bounds__(256) void convT_fragH(
    const float* __restrict__ src, int N,
    ushort_t* __restrict__ dhi, int nkc_dst, int kc_off)
{
  int ct = blockIdx.x;
  int kc = blockIdx.y * 4 + (threadIdx.x >> 6);
  int l = threadIdx.x & 63;
  int c = l & 31, g = l >> 5;
  const float* s = src + (size_t)(kc * 16 + g * 8) * N + ct * 32 + c;
  ushort_t hi8[8];
#pragma unroll
  for (int e = 0; e < 8; ++e) hi8[e] = f2bf(s[(size_t)e * N]);
  size_t off = ((size_t)ct * nkc_dst + kc_off + kc) * 512 + (size_t)l * 8;
  *(ushort4*)&dhi[off]     = make_ushort4(hi8[0], hi8[1], hi8[2], hi8[3]);
  *(ushort4*)&dhi[off + 4] = make_ushort4(hi8[4], hi8[5], hi8[6], hi8[7]);
}

// ---------------- avg over P, written directly in A-frag hi/lo ----------------
__global__ __launch_bounds__(256) void mavg_frag(
    const float* __restrict__ enc, ushort_t* __restrict__ dhi, ushort_t* __restrict__ dlo)
{
  int b = blockIdx.x;
  int e = blockIdx.y * 256 + threadIdx.x;
  float s = 0.f;
  const float* base = enc + (size_t)b * 196 * 2048 + e;
  for (int p = 0; p < NP; ++p) s += base[(size_t)p * 2048];
  s *= (1.f / 196.f);
  ushort_t hi = f2bf(s), lo = f2bf(s - bf2f(hi));
  size_t off = (size_t)(e >> 4) * 512 + ((e >> 3) & 1) * 256 + b * 8 + (e & 7);
  dhi[off] = hi; dlo[off] = lo;
}

// ---------------- h0,c0 = avg @ [W_h | W_c] + bias (MFMA) ----------------
__global__ __launch_bounds__(256) void mh0c0(
    const ushort_t* __restrict__ avg_hi, const ushort_t* __restrict__ avg_lo,
    const ushort_t* __restrict__ Whc_hi, const ushort_t* __restrict__ Whc_lo,
    const float* __restrict__ b_h, const float* __restrict__ b_c,
    float* __restrict__ h0f, float* __restrict__ cbuf)
{
  int w = threadIdx.x >> 6, lane = threadIdx.x & 63;
  int ct = blockIdx.x * 4 + w;
  const ushort_t* pa_h = avg_hi + lane * 8;
  const ushort_t* pa_l = avg_lo + lane * 8;
  const ushort_t* pb_h = Whc_hi + ((size_t)ct * 128) * 512 + lane * 8;
  const ushort_t* pb_l = Whc_lo + ((size_t)ct * 128) * 512 + lane * 8;
  f16v acc = (f16v)(0.0f);
  mfma_pipe_frag(pa_h, pa_l, pb_h, pb_l, 32, acc);
  int r = lane & 31, g = lane >> 5;
  int n = ct * 32 + r;
  if (ct < 16) {
    float bn = b_h[n];
#pragma unroll
    for (int rr = 0; rr < 16; ++rr)
      h0f[CD_ROW(rr, g) * 512 + n] = acc[rr] + bn;
  } else {
    int n2 = n - 512;
    float bn = b_c[n2];
#pragma unroll
    for (int rr = 0; rr < 16; ++rr)
      cbuf[CD_ROW(rr, g) * 512 + n2] = acc[rr] + bn;
  }
}

// ---------------- embproj = embF @ W_ih[:512] + b_ih + b_hh (MFMA) ----------------
__global__ __launch_bounds__(256) void m_emb(
    const ushort_t* __restrict__ eFhi, const ushort_t* __restrict__ eFlo,
    const ushort_t* __restrict__ Whi, const ushort_t* __restrict__ Wlo,
    const float* __restrict__ b1, const float* __restrict__ b2,
    float* __restrict__ embproj)
{
  int w = threadIdx.x >> 6, lane = threadIdx.x & 63;
  int mt = blockIdx.y;
  int ct = blockIdx.x * 4 + w;
  const ushort_t* pa_h = eFhi + ((size_t)mt * 32) * 512 + lane * 8;
  const ushort_t* pa_l = eFlo + ((size_t)mt * 32) * 512 + lane * 8;
  const ushort_t* pb_h = Whi + ((size_t)ct * 32) * 512 + lane * 8;
  const ushort_t* pb_l = Wlo + ((size_t)ct * 32) * 512 + lane * 8;
  f16v acc = (f16v)(0.0f);
  mfma_pipe_frag(pa_h, pa_l, pb_h, pb_l, 8, acc);
  int r = lane & 31, g = lane >> 5;
  int n = ct * 32 + r;
  float bn = b1[n] + b2[n];
#pragma unroll
  for (int rr = 0; rr < 16; ++rr)
    embproj[(size_t)(mt * 32 + CD_ROW(rr, g)) * 2048 + n] = acc[rr] + bn;
}

// ---------------- h0 -> h frag + x frag (h cols) ----------------
__global__ __launch_bounds__(256) void hsplit_frag(
    const float* __restrict__ h0f,
    ushort_t* __restrict__ hhi, ushort_t* __restrict__ hlo,
    ushort_t* __restrict__ xhi, ushort_t* __restrict__ xlo)
{
  int idx = blockIdx.x * 256 + threadIdx.x;
  int b = idx >> 6, dq = idx & 63, d0 = dq << 3;
  ushort4 h0v, h1v, l0v, l1v;
  ushort_t hh[8], hl[8];
#pragma unroll
  for (int j = 0; j < 8; ++j) {
    float v = h0f[b * 512 + d0 + j];
    hh[j] = f2bf(v); hl[j] = f2bf(v - bf2f(hh[j]));
  }
  h0v = make_ushort4(hh[0], hh[1], hh[2], hh[3]); h1v = make_ushort4(hh[4], hh[5], hh[6], hh[7]);
  l0v = make_ushort4(hl[0], hl[1], hl[2], hl[3]); l1v = make_ushort4(hl[4], hl[5], hl[6], hl[7]);
  int kc = d0 >> 4, g = (d0 >> 3) & 1;
  size_t off = ((size_t)kc * 64 + g * 32 + b) * 8;
  *(ushort4*)&hhi[off] = h0v; *(ushort4*)&hhi[off + 4] = h1v;
  *(ushort4*)&hlo[off] = l0v; *(ushort4*)&hlo[off + 4] = l1v;
  int xk0 = 2048 + d0;
  size_t offx = ((size_t)(xk0 >> 4) * 64 + g * 32 + b) * 8;
  *(ushort4*)&xhi[offx] = h0v; *(ushort4*)&xhi[offx + 4] = h1v;
  *(ushort4*)&xlo[offx] = l0v; *(ushort4*)&xlo[offx + 4] = l1v;
}

// ---------------- k2a: e + softmax; bf16 encatt, 512 threads, 2-way a-split ----------------
__global__ __launch_bounds__(512) void k2a_soft(
    const float* __restrict__ dec_gate, const float* __restrict__ bdec,
    const float* __restrict__ watt, const float* __restrict__ batt,
    const ushort_t* __restrict__ encatt_bf, const int* __restrict__ clen,
    float* __restrict__ outa, float* __restrict__ al_ws, int t)
{
  int b = blockIdx.x, tid = threadIdx.x;
  __shared__ float dec_s[512], watt_s[512], part_s[2][256], red_s[256];
  dec_s[tid] = dec_gate[b * 2560 + tid] + bdec[tid];
  watt_s[tid] = watt[tid];
  __syncthreads();
  int p = tid & 255, half = tid >> 8;
  float acc = 0.f;
  if (p < NP) {
    const ushort_t* col = encatt_bf + (size_t)b * 512 * 196 + p;
    int a0 = half * 256;
#pragma unroll 8
    for (int a = a0; a < a0 + 256; ++a)
      acc += fmaxf(bf2f(col[(size_t)a * 196]) + dec_s[a], 0.f) * watt_s[a];
  }
  part_s[half][p] = acc;
  __syncthreads();
  float e = -1e30f;
  if (tid < NP) e = part_s[0][tid] + part_s[1][tid] + batt[0];
  if (tid < 256) red_s[tid] = e;
  __syncthreads();
  for (int wd = 128; wd > 0; wd >>= 1) {
    if (tid < wd) red_s[tid] = fmaxf(red_s[tid], red_s[tid + wd]);
    __syncthreads();
  }
  float m = red_s[0];
  __syncthreads();
  float ex = (tid < NP) ? expf(e - m) : 0.f;
  if (tid < 256) red_s[tid] = ex;
  __syncthreads();
  for (int wd = 128; wd > 0; wd >>= 1) {
    if (tid < wd) red_s[tid] += red_s[tid + wd];
    __syncthreads();
  }
  float inv = 1.f / red_s[0];
  if (tid < NP) {
    float al = ex * inv;
    al_ws[b * NP + tid] = al;
    bool act = clen[b] - 1 > t;
    outa[(size_t)(b * TS + t) * NP + tid] = act ? al : 0.f;
  }
}

// ---------------- k2b: awe + gate -> x frag cols 0..2047 (grid 32 x 8) ----------------
__global__ __launch_bounds__(256) void k2b_awe(
    const float* __restrict__ al_ws, const float* __restrict__ dec_gate,
    const float* __restrict__ bfb, const float* __restrict__ enc,
    ushort_t* __restrict__ xhi, ushort_t* __restrict__ xlo)
{
  int b = blockIdx.x, ds = blockIdx.y, tid = threadIdx.x;
  __shared__ float al_s[196];
  __shared__ float part[4][64][4];
  if (tid < NP) al_s[tid] = al_ws[b * NP + tid];
  __syncthreads();
  int q = tid & 63, sp = tid >> 6;
  int d = ds * 256 + q * 4;
  float ax = 0.f, ay = 0.f, az = 0.f, aw = 0.f;
  int p0 = sp * 49;
#pragma unroll 7
  for (int p = p0; p < p0 + 49; ++p) {
    float al = al_s[p];
    float4 ev = *(const float4*)&enc[(size_t)(b * NP + p) * ENC + d];
    ax += al * ev.x; ay += al * ev.y; az += al * ev.z; aw += al * ev.w;
  }
  part[sp][q][0] = ax; part[sp][q][1] = ay; part[sp][q][2] = az; part[sp][q][3] = aw;
  __syncthreads();
  if (sp == 0) {
    ax = part[0][q][0] + part[1][q][0] + part[2][q][0] + part[3][q][0];
    ay = part[0][q][1] + part[1][q][1] + part[2][q][1] + part[3][q][1];
    az = part[0][q][2] + part[1][q][2] + part[2][q][2] + part[3][q][2];
    aw = part[0][q][3] + part[1][q][3] + part[2][q][3] + part[3][q][3];
    float4 gg = *(const float4*)&dec_gate[b * 2560 + 512 + d];
    float4 bb = *(const float4*)&bfb[d];
    float v0 = sigm(gg.x + bb.x) * ax;
    float v1 = sigm(gg.y + bb.y) * ay;
    float v2 = sigm(gg.z + bb.z) * az;
    float v3 = sigm(gg.w + bb.w) * aw;
    ushort4 hi, lo;
    hi.x = f2bf(v0); lo.x = f2bf(v0 - bf2f(hi.x));
    hi.y = f2bf(v1); lo.y = f2bf(v1 - bf2f(hi.y));
    hi.z = f2bf(v2); lo.z = f2bf(v2 - bf2f(hi.z));
    hi.w = f2bf(v3); lo.w = f2bf(v3 - bf2f(hi.w));
    size_t off = ((size_t)(d >> 4) * 64 + ((d >> 3) & 1) * 32 + b) * 8 + (d & 7);
    *(ushort4*)&xhi[off] = hi;
    *(ushort4*)&xlo[off] = lo;
  }
}

// ---------------- k4: LSTM pointwise + state update + h history ----------------
__global__ __launch_bounds__(64) void k4_lstm_frag(
    const float* __restrict__ P2, const float* __restrict__ embproj,
    const int* __restrict__ clen, float* __restrict__ c,
    ushort_t* __restrict__ hhi, ushort_t* __restrict__ hlo,
    ushort_t* __restrict__ xhi, ushort_t* __restrict__ xlo,
    ushort_t* __restrict__ hhist_hi, ushort_t* __restrict__ hhist_lo, int t)
{
  int idx = blockIdx.x * 64 + threadIdx.x;   // 2048: b*64 + dq
  int b = idx >> 6, dq = idx & 63, d0 = dq << 3;
  bool act = clen[b] - 1 > t;
  const float* ep = embproj + (size_t)(t * 32 + b) * 2048;
  f4v i0 = *(const f4v*)&ep[d0],        i1 = *(const f4v*)&ep[d0 + 4];
  f4v f0 = *(const f4v*)&ep[512 + d0],  f1 = *(const f4v*)&ep[512 + d0 + 4];
  f4v g0 = *(const f4v*)&ep[1024 + d0], g1 = *(const f4v*)&ep[1024 + d0 + 4];
  f4v o0 = *(const f4v*)&ep[1536 + d0], o1 = *(const f4v*)&ep[1536 + d0 + 4];
#pragma unroll
  for (int s = 0; s < 8; ++s) {
    const float* p2 = P2 + (size_t)s * 65536 + b * 2048;
    i0 += *(const f4v*)&p2[d0];        i1 += *(const f4v*)&p2[d0 + 4];
    f0 += *(const f4v*)&p2[512 + d0];  f1 += *(const f4v*)&p2[512 + d0 + 4];
    g0 += *(const f4v*)&p2[1024 + d0]; g1 += *(const f4v*)&p2[1024 + d0 + 4];
    o0 += *(const f4v*)&p2[1536 + d0]; o1 += *(const f4v*)&p2[1536 + d0 + 4];
  }
  f4v c0 = *(const f4v*)&c[b * 512 + d0], c1 = *(const f4v*)&c[b * 512 + d0 + 4];
  ushort_t hh[8], hl[8];
  f4v cn0, cn1;
#pragma unroll
  for (int j = 0; j < 8; ++j) {
    float iv = j < 4 ? i0[j] : i1[j - 4];
    float fv = j < 4 ? f0[j] : f1[j - 4];
    float gv = j < 4 ? g0[j] : g1[j - 4];
    float ov = j < 4 ? o0[j] : o1[j - 4];
    float cv = j < 4 ? c0[j] : c1[j - 4];
    float cn = sigm(fv) * cv + sigm(iv) * tanhf(gv);
    float hn = sigm(ov) * tanhf(cn);
    if (j < 4) cn0[j] = cn; else cn1[j - 4] = cn;
    hh[j] = f2bf(hn); hl[j] = f2bf(hn - bf2f(hh[j]));
  }
  ushort4 h0v = make_ushort4(hh[0], hh[1], hh[2], hh[3]);
  ushort4 h1v = make_ushort4(hh[4], hh[5], hh[6], hh[7]);
  ushort4 l0v = make_ushort4(hl[0], hl[1], hl[2], hl[3]);
  ushort4 l1v = make_ushort4(hl[4], hl[5], hl[6], hl[7]);
  int kc = d0 >> 4, g = (d0 >> 3) & 1;
  // h history (h_new pre-mask, matches reference preds semantics): always write
  size_t offh = ((size_t)(t * 32 + kc)) * 512 + ((size_t)g * 32 + b) * 8;
  *(ushort4*)&hhist_hi[offh] = h0v; *(ushort4*)&hhist_hi[offh + 4] = h1v;
  *(ushort4*)&hhist_lo[offh] = l0v; *(ushort4*)&hhist_lo[offh + 4] = l1v;
  if (!act) return;                   // inactive rows: state frozen
  *(f4v*)&c[b * 512 + d0] = cn0; *(f4v*)&c[b * 512 + d0 + 4] = cn1;
  size_t off = ((size_t)kc * 64 + g * 32 + b) * 8;
  *(ushort4*)&hhi[off] = h0v; *(ushort4*)&hhi[off + 4] = h1v;
  *(ushort4*)&hlo[off] = l0v; *(ushort4*)&hlo[off + 4] = l1v;
  int xk0 = 2048 + d0;
  size_t offx = ((size_t)(xk0 >> 4) * 64 + g * 32 + b) * 8;
  *(ushort4*)&xhi[offx] = h0v; *(ushort4*)&xhi[offx + 4] = h1v;
  *(ushort4*)&xlo[offx] = l0v; *(ushort4*)&xlo[offx + 4] = l1v;
}

// =====================================================================
extern "C" void kernel_launch(void* const* d_in, const int* in_sizes, int n_in,
                              void* d_out, int out_size, void* d_ws, size_t ws_size,
                              hipStream_t stream)
{
  (void)in_sizes; (void)n_in; (void)out_size; (void)ws_size;
  const float* enc   = (const float*)d_in[0];
  const int*   caps  = (const int*)d_in[1];
  const int*   clen  = (const int*)d_in[2];
  const float* emb   = (const float*)d_in[3];
  const float* W_enc = (const float*)d_in[4];
  const float* b_enc = (const float*)d_in[5];
  const float* W_dec = (const float*)d_in[6];
  const float* b_dec = (const float*)d_in[7];
  const float* w_att = (const float*)d_in[8];
  const float* b_att = (const float*)d_in[9];
  const float* W_ih  = (const float*)d_in[10];
  const float* b_ih  = (const float*)d_in[11];
  const float* W_hh  = (const float*)d_in[12];
  const float* b_hh  = (const float*)d_in[13];
  const float* W_h   = (const float*)d_in[14];
  const float* b_h   = (const float*)d_in[15];
  const float* W_c   = (const float*)d_in[16];
  const float* b_c   = (const float*)d_in[17];
  const float* W_fb  = (const float*)d_in[18];
  const float* b_fb  = (const float*)d_in[19];
  const float* W_fc  = (const float*)d_in[20];
  const float* b_fc  = (const float*)d_in[21];

  float* out_preds = (float*)d_out;
  float* out_alpha = out_preds + (size_t)NB * TS * VOC;

  // ---------- workspace layout (within proven 173,539,328-byte footprint) ----------
  char* p = (char*)d_ws;
  ushort_t* encatt_bf = (ushort_t*)p;     p += 12845056;   // 32*512*196 bf16 (uses half region)
  float* embproj  = (float*)p;            p += 10223616;   // 1248*2048 f32; first 256KB doubles as avg frag
  float* P2buf    = (float*)p;            p += 2097152;
  float* dec_gate = (float*)p;            p += 327680;
  ushort_t* x_lo  = (ushort_t*)p;         p += 262144;
  float* h0f      = (float*)p;            p += 65536;
  float* cbuf     = (float*)p;            p += 65536;
  float* al_ws    = (float*)p;            p += 25088;
  ushort_t* h_hi  = (ushort_t*)p;         p += 32768;
  ushort_t* h_lo  = (ushort_t*)p;         p += 32768;
  ushort_t* x_hi  = (ushort_t*)p;         p += 163840;
  p += 262144 - 25088 - 32768 - 32768 - 163840;
  ushort_t* e_hi  = (ushort_t*)p;         p += 25690112;
  ushort_t* e_lo  = (ushort_t*)p;         p += 25690112;
  ushort_t* We_hi = (ushort_t*)p;         p += 2097152;
  ushort_t* We_lo = (ushort_t*)p;         p += 2097152;
  ushort_t* W1_hi = (ushort_t*)p;         p += 2621440;
  ushort_t* W1_lo = (ushort_t*)p;         p += 2621440;
  ushort_t* W3_hi = (ushort_t*)p;         p += 10485760;
  ushort_t* W3_lo = (ushort_t*)p;         p += 10485760;
  ushort_t* Wf_hi = (ushort_t*)p;         p += 32768000;   // 1000 tiles x 32 kc (hi only)
  // former Wf_lo region -> emb-path + h-history buffers:
  ushort_t* WiE_hi = (ushort_t*)p;        p += 2097152;
  ushort_t* WiE_lo = (ushort_t*)p;        p += 2097152;
  ushort_t* eF_hi  = (ushort_t*)p;        p += 1277952;
  ushort_t* eF_lo  = (ushort_t*)p;        p += 1277952;
  ushort_t* hh_hi  = (ushort_t*)p;        p += 1277952;    // 39 mt x 32 kc h_new history
  ushort_t* hh_lo  = (ushort_t*)p;        p += 1277952;

  // prologue-only aliases (regions rewritten later, stream-ordered):
  ushort_t* avg_hi = (ushort_t*)embproj;
  ushort_t* avg_lo = avg_hi + 65536;
  ushort_t* Whc_hi = Wf_hi;
  ushort_t* Whc_lo = Wf_hi + 2097152;

  // ---------------- prologue ----------------
  mavg_frag<<<dim3(32, 8), 256, 0, stream>>>(enc, avg_hi, avg_lo);
  convT_frag<<<dim3(16, 32), 256, 0, stream>>>(W_h, 512, Whc_hi, Whc_lo, 128, 0);
  convT_frag<<<dim3(16, 32), 256, 0, stream>>>(W_c, 512,
      Whc_hi + (size_t)16 * 128 * 512, Whc_lo + (size_t)16 * 128 * 512, 128, 0);
  mh0c0<<<dim3(8), 256, 0, stream>>>(avg_hi, avg_lo, Whc_hi, Whc_lo, b_h, b_c, h0f, cbuf);
  convA_frag<<<dim3(196, 32), 256, 0, stream>>>(enc, e_hi, e_lo);
  convT_frag<<<dim3(16, 32), 256, 0, stream>>>(W_enc, 512, We_hi, We_lo, 128, 0);
  convT_frag<<<dim3(16, 8), 256, 0, stream>>>(W_dec, 512, W1_hi, W1_lo, 32, 0);
  convT_frag<<<dim3(64, 8), 256, 0, stream>>>(W_fb, 2048,
      W1_hi + (size_t)16 * 32 * 512, W1_lo + (size_t)16 * 32 * 512, 32, 0);
  convT_frag<<<dim3(64, 32), 256, 0, stream>>>(W_ih + (size_t)512 * 2048, 2048,
      W3_hi, W3_lo, 160, 0);
  convT_frag<<<dim3(64, 8), 256, 0, stream>>>(W_hh, 2048, W3_hi, W3_lo, 160, 128);
  convT_fragH<<<dim3(1000, 8), 256, 0, stream>>>(W_fc, VOC, Wf_hi, 32, 0);  // after mh0c0
  convA_emb_frag<<<dim3(39, 8), 256, 0, stream>>>(emb, caps, eF_hi, eF_lo);
  convT_frag<<<dim3(64, 8), 256, 0, stream>>>(W_ih, 2048, WiE_hi, WiE_lo, 32, 0);

  menc_att<<<dim3(4, 196), 256, 0, stream>>>(e_hi, e_lo, We_hi, We_lo, b_enc, encatt_bf);
  m_emb<<<dim3(16, 39), 256, 0, stream>>>(eF_hi, eF_lo, WiE_hi, WiE_lo, b_ih, b_hh, embproj);
  hsplit_frag<<<dim3(8), 256, 0, stream>>>(h0f, h_hi, h_lo, x_hi, x_lo);
  mk1<<<dim3(20), 256, 0, stream>>>(h_hi, h_lo, W1_hi, W1_lo, dec_gate);

  // ---------------- decode loop (preds deferred) ----------------
  for (int t = 0; t < TS; ++t) {
    k2a_soft<<<dim3(32), 512, 0, stream>>>(dec_gate, b_dec, w_att, b_att,
                                           encatt_bf, clen, out_alpha, al_ws, t);
    k2b_awe<<<dim3(32, 8), 256, 0, stream>>>(al_ws, dec_gate, b_fb, enc, x_hi, x_lo);
    mk3<<<dim3(16, 8), 256, 0, stream>>>(x_hi, x_lo, W3_hi, W3_lo, P2buf);
    k4_lstm_frag<<<dim3(32), 64, 0, stream>>>(P2buf, embproj, clen, cbuf,
                                              h_hi, h_lo, x_hi, x_lo, hh_hi, hh_lo, t);
    if (t < TS - 1)
      mk1<<<dim3(20), 256, 0, stream>>>(h_hi, h_lo, W1_hi, W1_lo, dec_gate);
  }

  // ---------------- deferred vocab projection (batched over all steps) ----------------
  mpreds<<<dim3(39, 250), 256, 0, stream>>>(hh_hi, hh_lo, Wf_hi, b_fc, clen, out_preds);
}

// Round 10
// 2181.573 us; speedup vs baseline: 1.2889x; 1.0240x over previous
//
#include <hip/hip_runtime.h>
#include <math.h>

#define NB 32
#define NP 196
#define ENC 2048
#define VOC 32000
#define LCAP 40
#define TS 39

typedef unsigned int uint_t;
typedef unsigned short ushort_t;

__device__ __forceinline__ float sigm(float x) { return 1.f / (1.f + expf(-x)); }

// ---------- bf16 helpers (RNE) ----------
__device__ __forceinline__ ushort_t f2bf(float f) {
  uint_t u = __float_as_uint(f);
  u = (u + 0x7FFFu + ((u >> 16) & 1u)) >> 16;
  return (ushort_t)u;
}
__device__ __forceinline__ float bf2f(ushort_t s) { return __uint_as_float(((uint_t)s) << 16); }

typedef __attribute__((ext_vector_type(8))) short bf8v;
typedef __attribute__((ext_vector_type(16))) float f16v;
typedef __attribute__((ext_vector_type(4))) float f4v;

__device__ __forceinline__ f16v MFMA(bf8v a, bf8v b, f16v c) {
  return __builtin_amdgcn_mfma_f32_32x32x16_bf16(a, b, c, 0, 0, 0);
}

// =====================================================================
// FRAGMENT LAYOUT: [tile][k_chunk][lane][8] ushorts; chunk = 512 ushorts.
// =====================================================================
// split-bf16 (3 MFMA/chunk): f32-class precision (recurrent paths)
__device__ __forceinline__ void mfma_pipe_frag(
    const ushort_t* __restrict__ pa_h, const ushort_t* __restrict__ pa_l,
    const ushort_t* __restrict__ pb_h, const ushort_t* __restrict__ pb_l,
    int nquad, f16v& acc)
{
  bf8v ah0 = *(const bf8v*)(pa_h +    0), al0 = *(const bf8v*)(pa_l +    0);
  bf8v bh0 = *(const bf8v*)(pb_h +    0), bl0 = *(const bf8v*)(pb_l +    0);
  bf8v ah1 = *(const bf8v*)(pa_h +  512), al1 = *(const bf8v*)(pa_l +  512);
  bf8v bh1 = *(const bf8v*)(pb_h +  512), bl1 = *(const bf8v*)(pb_l +  512);
  bf8v ah2 = *(const bf8v*)(pa_h + 1024), al2 = *(const bf8v*)(pa_l + 1024);
  bf8v bh2 = *(const bf8v*)(pb_h + 1024), bl2 = *(const bf8v*)(pb_l + 1024);
  bf8v ah3 = *(const bf8v*)(pa_h + 1536), al3 = *(const bf8v*)(pa_l + 1536);
  bf8v bh3 = *(const bf8v*)(pb_h + 1536), bl3 = *(const bf8v*)(pb_l + 1536);
  for (int q = 0; q < nquad; ++q) {
    const size_t nk = (size_t)(q + 1) * 2048;
    const bool more = (q + 1 < nquad);
    acc = MFMA(ah0, bh0, acc); acc = MFMA(ah0, bl0, acc); acc = MFMA(al0, bh0, acc);
    if (more) {
      ah0 = *(const bf8v*)(pa_h + nk +    0); al0 = *(const bf8v*)(pa_l + nk +    0);
      bh0 = *(const bf8v*)(pb_h + nk +    0); bl0 = *(const bf8v*)(pb_l + nk +    0);
    }
    acc = MFMA(ah1, bh1, acc); acc = MFMA(ah1, bl1, acc); acc = MFMA(al1, bh1, acc);
    if (more) {
      ah1 = *(const bf8v*)(pa_h + nk +  512); al1 = *(const bf8v*)(pa_l + nk +  512);
      bh1 = *(const bf8v*)(pb_h + nk +  512); bl1 = *(const bf8v*)(pb_l + nk +  512);
    }
    acc = MFMA(ah2, bh2, acc); acc = MFMA(ah2, bl2, acc); acc = MFMA(al2, bh2, acc);
    if (more) {
      ah2 = *(const bf8v*)(pa_h + nk + 1024); al2 = *(const bf8v*)(pa_l + nk + 1024);
      bh2 = *(const bf8v*)(pb_h + nk + 1024); bl2 = *(const bf8v*)(pb_l + nk + 1024);
    }
    acc = MFMA(ah3, bh3, acc); acc = MFMA(ah3, bl3, acc); acc = MFMA(al3, bh3, acc);
    if (more) {
      ah3 = *(const bf8v*)(pa_h + nk + 1536); al3 = *(const bf8v*)(pa_l + nk + 1536);
      bh3 = *(const bf8v*)(pb_h + nk + 1536); bl3 = *(const bf8v*)(pb_l + nk + 1536);
    }
  }
}

// B-hi-only (2 MFMA/chunk): A split, B hi (preds path)
__device__ __forceinline__ void mfma_pipe_fragBH(
    const ushort_t* __restrict__ pa_h, const ushort_t* __restrict__ pa_l,
    const ushort_t* __restrict__ pb_h, int nquad, f16v& acc)
{
  bf8v ah0 = *(const bf8v*)(pa_h +    0), al0 = *(const bf8v*)(pa_l +    0);
  bf8v bh0 = *(const bf8v*)(pb_h +    0);
  bf8v ah1 = *(const bf8v*)(pa_h +  512), al1 = *(const bf8v*)(pa_l +  512);
  bf8v bh1 = *(const bf8v*)(pb_h +  512);
  bf8v ah2 = *(const bf8v*)(pa_h + 1024), al2 = *(const bf8v*)(pa_l + 1024);
  bf8v bh2 = *(const bf8v*)(pb_h + 1024);
  bf8v ah3 = *(const bf8v*)(pa_h + 1536), al3 = *(const bf8v*)(pa_l + 1536);
  bf8v bh3 = *(const bf8v*)(pb_h + 1536);
  for (int q = 0; q < nquad; ++q) {
    const size_t nk = (size_t)(q + 1) * 2048;
    const bool more = (q + 1 < nquad);
    acc = MFMA(ah0, bh0, acc); acc = MFMA(al0, bh0, acc);
    if (more) {
      ah0 = *(const bf8v*)(pa_h + nk +    0); al0 = *(const bf8v*)(pa_l + nk +    0);
      bh0 = *(const bf8v*)(pb_h + nk +    0);
    }
    acc = MFMA(ah1, bh1, acc); acc = MFMA(al1, bh1, acc);
    if (more) {
      ah1 = *(const bf8v*)(pa_h + nk +  512); al1 = *(const bf8v*)(pa_l + nk +  512);
      bh1 = *(const bf8v*)(pb_h + nk +  512);
    }
    acc = MFMA(ah2, bh2, acc); acc = MFMA(al2, bh2, acc);
    if (more) {
      ah2 = *(const bf8v*)(pa_h + nk + 1024); al2 = *(const bf8v*)(pa_l + nk + 1024);
      bh2 = *(const bf8v*)(pb_h + nk + 1024);
    }
    acc = MFMA(ah3, bh3, acc); acc = MFMA(al3, bh3, acc);
    if (more) {
      ah3 = *(const bf8v*)(pa_h + nk + 1536); al3 = *(const bf8v*)(pa_l + nk + 1536);
      bh3 = *(const bf8v*)(pb_h + nk + 1536);
    }
  }
}

// A-hi-only (2 MFMA/chunk): A hi, B split (enc_att path: enc-lo dropped)
__device__ __forceinline__ void mfma_pipe_fragAH(
    const ushort_t* __restrict__ pa_h,
    const ushort_t* __restrict__ pb_h, const ushort_t* __restrict__ pb_l,
    int nquad, f16v& acc)
{
  bf8v ah0 = *(const bf8v*)(pa_h +    0);
  bf8v bh0 = *(const bf8v*)(pb_h +    0), bl0 = *(const bf8v*)(pb_l +    0);
  bf8v ah1 = *(const bf8v*)(pa_h +  512);
  bf8v bh1 = *(const bf8v*)(pb_h +  512), bl1 = *(const bf8v*)(pb_l +  512);
  bf8v ah2 = *(const bf8v*)(pa_h + 1024);
  bf8v bh2 = *(const bf8v*)(pb_h + 1024), bl2 = *(const bf8v*)(pb_l + 1024);
  bf8v ah3 = *(const bf8v*)(pa_h + 1536);
  bf8v bh3 = *(const bf8v*)(pb_h + 1536), bl3 = *(const bf8v*)(pb_l + 1536);
  for (int q = 0; q < nquad; ++q) {
    const size_t nk = (size_t)(q + 1) * 2048;
    const bool more = (q + 1 < nquad);
    acc = MFMA(ah0, bh0, acc); acc = MFMA(ah0, bl0, acc);
    if (more) {
      ah0 = *(const bf8v*)(pa_h + nk +    0);
      bh0 = *(const bf8v*)(pb_h + nk +    0); bl0 = *(const bf8v*)(pb_l + nk +    0);
    }
    acc = MFMA(ah1, bh1, acc); acc = MFMA(ah1, bl1, acc);
    if (more) {
      ah1 = *(const bf8v*)(pa_h + nk +  512);
      bh1 = *(const bf8v*)(pb_h + nk +  512); bl1 = *(const bf8v*)(pb_l + nk +  512);
    }
    acc = MFMA(ah2, bh2, acc); acc = MFMA(ah2, bl2, acc);
    if (more) {
      ah2 = *(const bf8v*)(pa_h + nk + 1024);
      bh2 = *(const bf8v*)(pb_h + nk + 1024); bl2 = *(const bf8v*)(pb_l + nk + 1024);
    }
    acc = MFMA(ah3, bh3, acc); acc = MFMA(ah3, bl3, acc);
    if (more) {
      ah3 = *(const bf8v*)(pa_h + nk + 1536);
      bh3 = *(const bf8v*)(pb_h + nk + 1536); bl3 = *(const bf8v*)(pb_l + nk + 1536);
    }
  }
}

// C/D mapping (HW-verified): col = lane&31, row = (reg&3)+8*(reg>>2)+4*(lane>>5)
#define CD_ROW(rr, g) (((rr) & 3) + 8 * ((rr) >> 2) + 4 * (g))

// ---------------- enc_att -> encatt_bf[b][a][p] (bf16), A-hi-only ----------------
__global__ __launch_bounds__(256) void menc_att(
    const ushort_t* __restrict__ Ahi,
    const ushort_t* __restrict__ Whi, const ushort_t* __restrict__ Wlo,
    const float* __restrict__ benc, ushort_t* __restrict__ encatt_bf)
{
  __shared__ float tileS[4][32][33];
  int w = threadIdx.x >> 6, lane = threadIdx.x & 63;
  int mt = blockIdx.y;                 // 196 m-tiles
  int ct = blockIdx.x * 4 + w;         // 16 col-tiles
  const ushort_t* pa_h = Ahi + ((size_t)mt * 128) * 512 + lane * 8;
  const ushort_t* pb_h = Whi + ((size_t)ct * 128) * 512 + lane * 8;
  const ushort_t* pb_l = Wlo + ((size_t)ct * 128) * 512 + lane * 8;
  f16v acc = (f16v)(0.0f);
  mfma_pipe_fragAH(pa_h, pb_h, pb_l, 32, acc);
  int r = lane & 31, g = lane >> 5;
  float bn = benc[ct * 32 + r];
#pragma unroll
  for (int rr = 0; rr < 16; ++rr)
    tileS[w][r][CD_ROW(rr, g)] = acc[rr] + bn;   // [a_local][p_local]
  __syncthreads();
#pragma unroll
  for (int j = 0; j < 4; ++j) {
    int a_l = j * 8 + (lane >> 3);
    int p4 = (lane & 7) * 4;
    int n2 = ct * 32 + a_l;
#pragma unroll
    for (int jj = 0; jj < 4; ++jj) {
      int pl = p4 + jj;
      int rg = mt * 32 + pl;
      int b = rg / 196, pp = rg - b * 196;
      encatt_bf[((size_t)b * 512 + n2) * 196 + pp] = f2bf(tileS[w][a_l][pl]);
    }
  }
}

// ---------------- k1: dec_gate = h @ [W_dec | W_fb] ----------------
__global__ __launch_bounds__(256) void mk1(
    const ushort_t* __restrict__ hhi, const ushort_t* __restrict__ hlo,
    const ushort_t* __restrict__ W1hi, const ushort_t* __restrict__ W1lo,
    float* __restrict__ dec_gate)
{
  int w = threadIdx.x >> 6, lane = threadIdx.x & 63;
  int ct = blockIdx.x * 4 + w;         // 80 col-tiles
  const ushort_t* pa_h = hhi + lane * 8;
  const ushort_t* pa_l = hlo + lane * 8;
  const ushort_t* pb_h = W1hi + ((size_t)ct * 32) * 512 + lane * 8;
  const ushort_t* pb_l = W1lo + ((size_t)ct * 32) * 512 + lane * 8;
  f16v acc = (f16v)(0.0f);
  mfma_pipe_frag(pa_h, pa_l, pb_h, pb_l, 8, acc);
  int r = lane & 31, g = lane >> 5;
  int n = ct * 32 + r;
#pragma unroll
  for (int rr = 0; rr < 16; ++rr)
    dec_gate[CD_ROW(rr, g) * 2560 + n] = acc[rr];
}

// ---------------- k3: P2[s] = partial of x(=[aweg|h]) @ W3 ----------------
__global__ __launch_bounds__(256) void mk3(
    const ushort_t* __restrict__ xhi, const ushort_t* __restrict__ xlo,
    const ushort_t* __restrict__ W3hi, const ushort_t* __restrict__ W3lo,
    float* __restrict__ P2)
{
  int w = threadIdx.x >> 6, lane = threadIdx.x & 63;
  int ct = blockIdx.x * 4 + w;         // 64 col-tiles
  int s = blockIdx.y;                  // 8 k-slices of 20 chunks
  const ushort_t* pa_h = xhi + ((size_t)s * 20) * 512 + lane * 8;
  const ushort_t* pa_l = xlo + ((size_t)s * 20) * 512 + lane * 8;
  const ushort_t* pb_h = W3hi + ((size_t)ct * 160 + s * 20) * 512 + lane * 8;
  const ushort_t* pb_l = W3lo + ((size_t)ct * 160 + s * 20) * 512 + lane * 8;
  f16v acc = (f16v)(0.0f);
  mfma_pipe_frag(pa_h, pa_l, pb_h, pb_l, 5, acc);
  int r = lane & 31, g = lane >> 5;
  int n = ct * 32 + r;
#pragma unroll
  for (int rr = 0; rr < 16; ++rr)
    P2[(size_t)s * (32 * 2048) + CD_ROW(rr, g) * 2048 + n] = acc[rr];
}

// ---------------- mpreds (deferred, XCD-swizzled): preds = h_hist @ Wfc + bfc ----------------
// 1D grid 9750; bijective XCD swizzle (m204): each XCD owns a contiguous ct-major slice
// so its private L2 re-reads only ~1/8 of Wfc instead of all of it.
__global__ __launch_bounds__(256) void mpreds(
    const ushort_t* __restrict__ hhist_hi, const ushort_t* __restrict__ hhist_lo,
    const ushort_t* __restrict__ Wfchi, const float* __restrict__ bfc,
    const int* __restrict__ clen, float* __restrict__ outp)
{
  // nwg = 9750, q = 1218, r = 6
  int orig = blockIdx.x;
  int xcd = orig & 7, i = orig >> 3;
  int base = (xcd < 6) ? xcd * 1219 : 6 * 1219 + (xcd - 6) * 1218;
  int wgid = base + i;
  int ct4 = wgid / 39, mt = wgid - ct4 * 39;   // ct-major: 39 mt consecutive per ct4
  int w = threadIdx.x >> 6, lane = threadIdx.x & 63;
  int ct = ct4 * 4 + w;                        // 1000 col-tiles
  const ushort_t* pa_h = hhist_hi + ((size_t)mt * 32) * 512 + lane * 8;
  const ushort_t* pa_l = hhist_lo + ((size_t)mt * 32) * 512 + lane * 8;
  const ushort_t* pb_h = Wfchi + ((size_t)ct * 32) * 512 + lane * 8;
  f16v acc = (f16v)(0.0f);
  mfma_pipe_fragBH(pa_h, pa_l, pb_h, 8, acc);
  int r = lane & 31, g = lane >> 5;
  int n = ct * 32 + r;
  float bn = bfc[n];
#pragma unroll
  for (int rr = 0; rr < 16; ++rr) {
    int b = CD_ROW(rr, g);
    bool act = clen[b] - 1 > mt;
    outp[(size_t)b * (TS * VOC) + (size_t)mt * VOC + n] = act ? (acc[rr] + bn) : 0.f;
  }
}

// ---------------- conversions into frag layout ----------------
// enc [6272][2048] f32 -> A-frag hi only
__global__ __launch_bounds__(256) void convA_fragH(
    const float* __restrict__ src, ushort_t* __restrict__ dhi)
{
  int mt = blockIdx.x;
  int kc = blockIdx.y * 4 + (threadIdx.x >> 6);
  int l = threadIdx.x & 63;
  int r = l & 31, g = l >> 5;
  const float* s = src + (size_t)(mt * 32 + r) * 2048 + kc * 16 + g * 8;
  float4 v0 = *(const float4*)s, v1 = *(const float4*)(s + 4);
  ushort4 h0, h1;
  h0.x = f2bf(v0.x); h0.y = f2bf(v0.y); h0.z = f2bf(v0.z); h0.w = f2bf(v0.w);
  h1.x = f2bf(v1.x); h1.y = f2bf(v1.y); h1.z = f2bf(v1.z); h1.w = f2bf(v1.w);
  size_t off = ((size_t)mt * 128 + kc) * 512 + (size_t)l * 8;
  *(ushort4*)&dhi[off] = h0; *(ushort4*)&dhi[off + 4] = h1;
}

// gathered embedding rows -> A-frag: tile mt = timestep, row = batch
__global__ __launch_bounds__(256) void convA_emb_frag(
    const float* __restrict__ Emb, const int* __restrict__ caps,
    ushort_t* __restrict__ dhi, ushort_t* __restrict__ dlo)
{
  int mt = blockIdx.x;
  int kc = blockIdx.y * 4 + (threadIdx.x >> 6);
  int l = threadIdx.x & 63;
  int r = l & 31, g = l >> 5;
  int tok = caps[r * LCAP + mt];
  const float* s = Emb + (size_t)tok * 512 + kc * 16 + g * 8;
  float4 v0 = *(const float4*)s, v1 = *(const float4*)(s + 4);
  ushort4 h0, l0, h1, l1;
  h0.x = f2bf(v0.x); l0.x = f2bf(v0.x - bf2f(h0.x));
  h0.y = f2bf(v0.y); l0.y = f2bf(v0.y - bf2f(h0.y));
  h0.z = f2bf(v0.z); l0.z = f2bf(v0.z - bf2f(h0.z));
  h0.w = f2bf(v0.w); l0.w = f2bf(v0.w - bf2f(h0.w));
  h1.x = f2bf(v1.x); l1.x = f2bf(v1.x - bf2f(h1.x));
  h1.y = f2bf(v1.y); l1.y = f2bf(v1.y - bf2f(h1.y));
  h1.z = f2bf(v1.z); l1.z = f2bf(v1.z - bf2f(h1.z));
  h1.w = f2bf(v1.w); l1.w = f2bf(v1.w - bf2f(h1.w));
  size_t off = ((size_t)mt * 32 + kc) * 512 + (size_t)l * 8;
  *(ushort4*)&dhi[off] = h0; *(ushort4*)&dhi[off + 4] = h1;
  *(ushort4*)&dlo[off] = l0; *(ushort4*)&dlo[off + 4] = l1;
}

// W [K][N] f32 -> B-frag tiles (hi+lo)
__global__ __launch_bounds__(256) void convT_frag(
    const float* __restrict__ src, int N,
    ushort_t* __restrict__ dhi, ushort_t* __restrict__ dlo,
    int nkc_dst, int kc_off)
{
  int ct = blockIdx.x;
  int kc = blockIdx.y * 4 + (threadIdx.x >> 6);
  int l = threadIdx.x & 63;
  int c = l & 31, g = l >> 5;
  const float* s = src + (size_t)(kc * 16 + g * 8) * N + ct * 32 + c;
  ushort_t hi8[8], lo8[8];
#pragma unroll
  for (int e = 0; e < 8; ++e) {
    float f = s[(size_t)e * N];
    hi8[e] = f2bf(f); lo8[e] = f2bf(f - bf2f(hi8[e]));
  }
  size_t off = ((size_t)ct * nkc_dst + kc_off + kc) * 512 + (size_t)l * 8;
  *(ushort4*)&dhi[off]     = make_ushort4(hi8[0], hi8[1], hi8[2], hi8[3]);
  *(ushort4*)&dhi[off + 4] = make_ushort4(hi8[4], hi8[5], hi8[6], hi8[7]);
  *(ushort4*)&dlo[off]     = make_ushort4(lo8[0], lo8[1], lo8[2], lo8[3]);
  *(ushort4*)&dlo[off + 4] = make_ushort4(lo8[4], lo8[5], lo8[6], lo8[7]);
}

// W [K][N] f32 -> B-frag tiles (hi only)
__global__ __launch_bounds__(256) void convT_fragH(
    const float* __restrict__ src, int N,
    ushort_t* __restrict__ dhi, int nkc_dst, int kc_off)
{
  int ct = blockIdx.x;
  int kc = blockIdx.y * 4 + (threadIdx.x >> 6);
  int l = threadIdx.x & 63;
  int c = l & 31, g = l >> 5;
  const float* s = src + (size_t)(kc * 16 + g * 8) * N + ct * 32 + c;
  ushort_t hi8[8];
#pragma unroll
  for (int e = 0; e < 8; ++e) hi8[e] = f2bf(s[(size_t)e * N]);
  size_t off = ((size_t)ct * nkc_dst + kc_off + kc) * 512 + (size_t)l * 8;
  *(ushort4*)&dhi[off]     = make_ushort4(hi8[0], hi8[1], hi8[2], hi8[3]);
  *(ushort4*)&dhi[off + 4] = make_ushort4(hi8[4], hi8[5], hi8[6], hi8[7]);
}

// ---------------- avg over P, written directly in A-frag hi/lo ----------------
__global__ __launch_bounds__(256) void mavg_frag(
    const float* __restrict__ enc, ushort_t* __restrict__ dhi, ushort_t* __restrict__ dlo)
{
  int b = blockIdx.x;
  int e = blockIdx.y * 256 + threadIdx.x;
  float s = 0.f;
  const float* base = enc + (size_t)b * 196 * 2048 + e;
  for (int p = 0; p < NP; ++p) s += base[(size_t)p * 2048];
  s *= (1.f / 196.f);
  ushort_t hi = f2bf(s), lo = f2bf(s - bf2f(hi));
  size_t off = (size_t)(e >> 4) * 512 + ((e >> 3) & 1) * 256 + b * 8 + (e & 7);
  dhi[off] = hi; dlo[off] = lo;
}

// ---------------- h0,c0 = avg @ [W_h | W_c] + bias (MFMA) ----------------
__global__ __launch_bounds__(256) void mh0c0(
    const ushort_t* __restrict__ avg_hi, const ushort_t* __restrict__ avg_lo,
    const ushort_t* __restrict__ Whc_hi, const ushort_t* __restrict__ Whc_lo,
    const float* __restrict__ b_h, const float* __restrict__ b_c,
    float* __restrict__ h0f, float* __restrict__ cbuf)
{
  int w = threadIdx.x >> 6, lane = threadIdx.x & 63;
  int ct = blockIdx.x * 4 + w;
  const ushort_t* pa_h = avg_hi + lane * 8;
  const ushort_t* pa_l = avg_lo + lane * 8;
  const ushort_t* pb_h = Whc_hi + ((size_t)ct * 128) * 512 + lane * 8;
  const ushort_t* pb_l = Whc_lo + ((size_t)ct * 128) * 512 + lane * 8;
  f16v acc = (f16v)(0.0f);
  mfma_pipe_frag(pa_h, pa_l, pb_h, pb_l, 32, acc);
  int r = lane & 31, g = lane >> 5;
  int n = ct * 32 + r;
  if (ct < 16) {
    float bn = b_h[n];
#pragma unroll
    for (int rr = 0; rr < 16; ++rr)
      h0f[CD_ROW(rr, g) * 512 + n] = acc[rr] + bn;
  } else {
    int n2 = n - 512;
    float bn = b_c[n2];
#pragma unroll
    for (int rr = 0; rr < 16; ++rr)
      cbuf[CD_ROW(rr, g) * 512 + n2] = acc[rr] + bn;
  }
}

// ---------------- embproj = embF @ W_ih[:512] + b_ih + b_hh (MFMA) ----------------
__global__ __launch_bounds__(256) void m_emb(
    const ushort_t* __restrict__ eFhi, const ushort_t* __restrict__ eFlo,
    const ushort_t* __restrict__ Whi, const ushort_t* __restrict__ Wlo,
    const float* __restrict__ b1, const float* __restrict__ b2,
    float* __restrict__ embproj)
{
  int w = threadIdx.x >> 6, lane = threadIdx.x & 63;
  int mt = blockIdx.y;
  int ct = blockIdx.x * 4 + w;
  const ushort_t* pa_h = eFhi + ((size_t)mt * 32) * 512 + lane * 8;
  const ushort_t* pa_l = eFlo + ((size_t)mt * 32) * 512 + lane * 8;
  const ushort_t* pb_h = Whi + ((size_t)ct * 32) * 512 + lane * 8;
  const ushort_t* pb_l = Wlo + ((size_t)ct * 32) * 512 + lane * 8;
  f16v acc = (f16v)(0.0f);
  mfma_pipe_frag(pa_h, pa_l, pb_h, pb_l, 8, acc);
  int r = lane & 31, g = lane >> 5;
  int n = ct * 32 + r;
  float bn = b1[n] + b2[n];
#pragma unroll
  for (int rr = 0; rr < 16; ++rr)
    embproj[(size_t)(mt * 32 + CD_ROW(rr, g)) * 2048 + n] = acc[rr] + bn;
}

// ---------------- h0 -> h frag + x frag (h cols) ----------------
__global__ __launch_bounds__(256) void hsplit_frag(
    const float* __restrict__ h0f,
    ushort_t* __restrict__ hhi, ushort_t* __restrict__ hlo,
    ushort_t* __restrict__ xhi, ushort_t* __restrict__ xlo)
{
  int idx = blockIdx.x * 256 + threadIdx.x;
  int b = idx >> 6, dq = idx & 63, d0 = dq << 3;
  ushort4 h0v, h1v, l0v, l1v;
  ushort_t hh[8], hl[8];
#pragma unroll
  for (int j = 0; j < 8; ++j) {
    float v = h0f[b * 512 + d0 + j];
    hh[j] = f2bf(v); hl[j] = f2bf(v - bf2f(hh[j]));
  }
  h0v = make_ushort4(hh[0], hh[1], hh[2], hh[3]); h1v = make_ushort4(hh[4], hh[5], hh[6], hh[7]);
  l0v = make_ushort4(hl[0], hl[1], hl[2], hl[3]); l1v = make_ushort4(hl[4], hl[5], hl[6], hl[7]);
  int kc = d0 >> 4, g = (d0 >> 3) & 1;
  size_t off = ((size_t)kc * 64 + g * 32 + b) * 8;
  *(ushort4*)&hhi[off] = h0v; *(ushort4*)&hhi[off + 4] = h1v;
  *(ushort4*)&hlo[off] = l0v; *(ushort4*)&hlo[off + 4] = l1v;
  int xk0 = 2048 + d0;
  size_t offx = ((size_t)(xk0 >> 4) * 64 + g * 32 + b) * 8;
  *(ushort4*)&xhi[offx] = h0v; *(ushort4*)&xhi[offx + 4] = h1v;
  *(ushort4*)&xlo[offx] = l0v; *(ushort4*)&xlo[offx + 4] = l1v;
}

// ---------------- k2a: e + softmax; bf16 encatt, 512 threads, 2-way a-split ----------------
__global__ __launch_bounds__(512) void k2a_soft(
    const float* __restrict__ dec_gate, const float* __restrict__ bdec,
    const float* __restrict__ watt, const float* __restrict__ batt,
    const ushort_t* __restrict__ encatt_bf, const int* __restrict__ clen,
    float* __restrict__ outa, float* __restrict__ al_ws, int t)
{
  int b = blockIdx.x, tid = threadIdx.x;
  __shared__ float dec_s[512], watt_s[512], part_s[2][256], red_s[256];
  dec_s[tid] = dec_gate[b * 2560 + tid] + bdec[tid];
  watt_s[tid] = watt[tid];
  __syncthreads();
  int p = tid & 255, half = tid >> 8;
  float acc = 0.f;
  if (p < NP) {
    const ushort_t* col = encatt_bf + (size_t)b * 512 * 196 + p;
    int a0 = half * 256;
#pragma unroll 8
    for (int a = a0; a < a0 + 256; ++a)
      acc += fmaxf(bf2f(col[(size_t)a * 196]) + dec_s[a], 0.f) * watt_s[a];
  }
  part_s[half][p] = acc;
  __syncthreads();
  float e = -1e30f;
  if (tid < NP) e = part_s[0][tid] + part_s[1][tid] + batt[0];
  if (tid < 256) red_s[tid] = e;
  __syncthreads();
  for (int wd = 128; wd > 0; wd >>= 1) {
    if (tid < wd) red_s[tid] = fmaxf(red_s[tid], red_s[tid + wd]);
    __syncthreads();
  }
  float m = red_s[0];
  __syncthreads();
  float ex = (tid < NP) ? expf(e - m) : 0.f;
  if (tid < 256) red_s[tid] = ex;
  __syncthreads();
  for (int wd = 128; wd > 0; wd >>= 1) {
    if (tid < wd) red_s[tid] += red_s[tid + wd];
    __syncthreads();
  }
  float inv = 1.f / red_s[0];
  if (tid < NP) {
    float al = ex * inv;
    al_ws[b * NP + tid] = al;
    bool act = clen[b] - 1 > t;
    outa[(size_t)(b * TS + t) * NP + tid] = act ? al : 0.f;
  }
}

// ---------------- k2b: awe + gate -> x frag cols 0..2047 (grid 32 x 8) ----------------
__global__ __launch_bounds__(256) void k2b_awe(
    const float* __restrict__ al_ws, const float* __restrict__ dec_gate,
    const float* __restrict__ bfb, const float* __restrict__ enc,
    ushort_t* __restrict__ xhi, ushort_t* __restrict__ xlo)
{
  int b = blockIdx.x, ds = blockIdx.y, tid = threadIdx.x;
  __shared__ float al_s[196];
  __shared__ float part[4][64][4];
  if (tid < NP) al_s[tid] = al_ws[b * NP + tid];
  __syncthreads();
  int q = tid & 63, sp = tid >> 6;
  int d = ds * 256 + q * 4;
  float ax = 0.f, ay = 0.f, az = 0.f, aw = 0.f;
  int p0 = sp * 49;
#pragma unroll 7
  for (int p = p0; p < p0 + 49; ++p) {
    float al = al_s[p];
    float4 ev = *(const float4*)&enc[(size_t)(b * NP + p) * ENC + d];
    ax += al * ev.x; ay += al * ev.y; az += al * ev.z; aw += al * ev.w;
  }
  part[sp][q][0] = ax; part[sp][q][1] = ay; part[sp][q][2] = az; part[sp][q][3] = aw;
  __syncthreads();
  if (sp == 0) {
    ax = part[0][q][0] + part[1][q][0] + part[2][q][0] + part[3][q][0];
    ay = part[0][q][1] + part[1][q][1] + part[2][q][1] + part[3][q][1];
    az = part[0][q][2] + part[1][q][2] + part[2][q][2] + part[3][q][2];
    aw = part[0][q][3] + part[1][q][3] + part[2][q][3] + part[3][q][3];
    float4 gg = *(const float4*)&dec_gate[b * 2560 + 512 + d];
    float4 bb = *(const float4*)&bfb[d];
    float v0 = sigm(gg.x + bb.x) * ax;
    float v1 = sigm(gg.y + bb.y) * ay;
    float v2 = sigm(gg.z + bb.z) * az;
    float v3 = sigm(gg.w + bb.w) * aw;
    ushort4 hi, lo;
    hi.x = f2bf(v0); lo.x = f2bf(v0 - bf2f(hi.x));
    hi.y = f2bf(v1); lo.y = f2bf(v1 - bf2f(hi.y));
    hi.z = f2bf(v2); lo.z = f2bf(v2 - bf2f(hi.z));
    hi.w = f2bf(v3); lo.w = f2bf(v3 - bf2f(hi.w));
    size_t off = ((size_t)(d >> 4) * 64 + ((d >> 3) & 1) * 32 + b) * 8 + (d & 7);
    *(ushort4*)&xhi[off] = hi;
    *(ushort4*)&xlo[off] = lo;
  }
}

// ---------------- k4: LSTM pointwise + state update + h history ----------------
__global__ __launch_bounds__(64) void k4_lstm_frag(
    const float* __restrict__ P2, const float* __restrict__ embproj,
    const int* __restrict__ clen, float* __restrict__ c,
    ushort_t* __restrict__ hhi, ushort_t* __restrict__ hlo,
    ushort_t* __restrict__ xhi, ushort_t* __restrict__ xlo,
    ushort_t* __restrict__ hhist_hi, ushort_t* __restrict__ hhist_lo, int t)
{
  int idx = blockIdx.x * 64 + threadIdx.x;   // 2048: b*64 + dq
  int b = idx >> 6, dq = idx & 63, d0 = dq << 3;
  bool act = clen[b] - 1 > t;
  const float* ep = embproj + (size_t)(t * 32 + b) * 2048;
  f4v i0 = *(const f4v*)&ep[d0],        i1 = *(const f4v*)&ep[d0 + 4];
  f4v f0 = *(const f4v*)&ep[512 + d0],  f1 = *(const f4v*)&ep[512 + d0 + 4];
  f4v g0 = *(const f4v*)&ep[1024 + d0], g1 = *(const f4v*)&ep[1024 + d0 + 4];
  f4v o0 = *(const f4v*)&ep[1536 + d0], o1 = *(const f4v*)&ep[1536 + d0 + 4];
#pragma unroll
  for (int s = 0; s < 8; ++s) {
    const float* p2 = P2 + (size_t)s * 65536 + b * 2048;
    i0 += *(const f4v*)&p2[d0];        i1 += *(const f4v*)&p2[d0 + 4];
    f0 += *(const f4v*)&p2[512 + d0];  f1 += *(const f4v*)&p2[512 + d0 + 4];
    g0 += *(const f4v*)&p2[1024 + d0]; g1 += *(const f4v*)&p2[1024 + d0 + 4];
    o0 += *(const f4v*)&p2[1536 + d0]; o1 += *(const f4v*)&p2[1536 + d0 + 4];
  }
  f4v c0 = *(const f4v*)&c[b * 512 + d0], c1 = *(const f4v*)&c[b * 512 + d0 + 4];
  ushort_t hh[8], hl[8];
  f4v cn0, cn1;
#pragma unroll
  for (int j = 0; j < 8; ++j) {
    float iv = j < 4 ? i0[j] : i1[j - 4];
    float fv = j < 4 ? f0[j] : f1[j - 4];
    float gv = j < 4 ? g0[j] : g1[j - 4];
    float ov = j < 4 ? o0[j] : o1[j - 4];
    float cv = j < 4 ? c0[j] : c1[j - 4];
    float cn = sigm(fv) * cv + sigm(iv) * tanhf(gv);
    float hn = sigm(ov) * tanhf(cn);
    if (j < 4) cn0[j] = cn; else cn1[j - 4] = cn;
    hh[j] = f2bf(hn); hl[j] = f2bf(hn - bf2f(hh[j]));
  }
  ushort4 h0v = make_ushort4(hh[0], hh[1], hh[2], hh[3]);
  ushort4 h1v = make_ushort4(hh[4], hh[5], hh[6], hh[7]);
  ushort4 l0v = make_ushort4(hl[0], hl[1], hl[2], hl[3]);
  ushort4 l1v = make_ushort4(hl[4], hl[5], hl[6], hl[7]);
  int kc = d0 >> 4, g = (d0 >> 3) & 1;
  // h history (h_new pre-mask, matches reference preds semantics): always write
  size_t offh = ((size_t)(t * 32 + kc)) * 512 + ((size_t)g * 32 + b) * 8;
  *(ushort4*)&hhist_hi[offh] = h0v; *(ushort4*)&hhist_hi[offh + 4] = h1v;
  *(ushort4*)&hhist_lo[offh] = l0v; *(ushort4*)&hhist_lo[offh + 4] = l1v;
  if (!act) return;                   // inactive rows: state frozen
  *(f4v*)&c[b * 512 + d0] = cn0; *(f4v*)&c[b * 512 + d0 + 4] = cn1;
  size_t off = ((size_t)kc * 64 + g * 32 + b) * 8;
  *(ushort4*)&hhi[off] = h0v; *(ushort4*)&hhi[off + 4] = h1v;
  *(ushort4*)&hlo[off] = l0v; *(ushort4*)&hlo[off + 4] = l1v;
  int xk0 = 2048 + d0;
  size_t offx = ((size_t)(xk0 >> 4) * 64 + g * 32 + b) * 8;
  *(ushort4*)&xhi[offx] = h0v; *(ushort4*)&xhi[offx + 4] = h1v;
  *(ushort4*)&xlo[offx] = l0v; *(ushort4*)&xlo[offx + 4] = l1v;
}

// =====================================================================
extern "C" void kernel_launch(void* const* d_in, const int* in_sizes, int n_in,
                              void* d_out, int out_size, void* d_ws, size_t ws_size,
                              hipStream_t stream)
{
  (void)in_sizes; (void)n_in; (void)out_size; (void)ws_size;
  const float* enc   = (const float*)d_in[0];
  const int*   caps  = (const int*)d_in[1];
  const int*   clen  = (const int*)d_in[2];
  const float* emb   = (const float*)d_in[3];
  const float* W_enc = (const float*)d_in[4];
  const float* b_enc = (const float*)d_in[5];
  const float* W_dec = (const float*)d_in[6];
  const float* b_dec = (const float*)d_in[7];
  const float* w_att = (const float*)d_in[8];
  const float* b_att = (const float*)d_in[9];
  const float* W_ih  = (const float*)d_in[10];
  const float* b_ih  = (const float*)d_in[11];
  const float* W_hh  = (const float*)d_in[12];
  const float* b_hh  = (const float*)d_in[13];
  const float* W_h   = (const float*)d_in[14];
  const float* b_h   = (const float*)d_in[15];
  const float* W_c   = (const float*)d_in[16];
  const float* b_c   = (const float*)d_in[17];
  const float* W_fb  = (const float*)d_in[18];
  const float* b_fb  = (const float*)d_in[19];
  const float* W_fc  = (const float*)d_in[20];
  const float* b_fc  = (const float*)d_in[21];

  float* out_preds = (float*)d_out;
  float* out_alpha = out_preds + (size_t)NB * TS * VOC;

  // ---------- workspace layout (within proven 173,539,328-byte footprint) ----------
  char* p = (char*)d_ws;
  ushort_t* encatt_bf = (ushort_t*)p;     p += 12845056;
  float* embproj  = (float*)p;            p += 10223616;
  float* P2buf    = (float*)p;            p += 2097152;
  float* dec_gate = (float*)p;            p += 327680;
  ushort_t* x_lo  = (ushort_t*)p;         p += 262144;
  float* h0f      = (float*)p;            p += 65536;
  float* cbuf     = (float*)p;            p += 65536;
  float* al_ws    = (float*)p;            p += 25088;
  ushort_t* h_hi  = (ushort_t*)p;         p += 32768;
  ushort_t* h_lo  = (ushort_t*)p;         p += 32768;
  ushort_t* x_hi  = (ushort_t*)p;         p += 163840;
  p += 262144 - 25088 - 32768 - 32768 - 163840;
  ushort_t* e_hi  = (ushort_t*)p;         p += 25690112;
  ushort_t* e_lo  = (ushort_t*)p;         p += 25690112;   // unused (A-hi-only enc_att)
  ushort_t* We_hi = (ushort_t*)p;         p += 2097152;
  ushort_t* We_lo = (ushort_t*)p;         p += 2097152;
  ushort_t* W1_hi = (ushort_t*)p;         p += 2621440;
  ushort_t* W1_lo = (ushort_t*)p;         p += 2621440;
  ushort_t* W3_hi = (ushort_t*)p;         p += 10485760;
  ushort_t* W3_lo = (ushort_t*)p;         p += 10485760;
  ushort_t* Wf_hi = (ushort_t*)p;         p += 32768000;
  ushort_t* WiE_hi = (ushort_t*)p;        p += 2097152;
  ushort_t* WiE_lo = (ushort_t*)p;        p += 2097152;
  ushort_t* eF_hi  = (ushort_t*)p;        p += 1277952;
  ushort_t* eF_lo  = (ushort_t*)p;        p += 1277952;
  ushort_t* hh_hi  = (ushort_t*)p;        p += 1277952;
  ushort_t* hh_lo  = (ushort_t*)p;        p += 1277952;
  (void)e_lo;

  // prologue-only aliases (regions rewritten later, stream-ordered):
  ushort_t* avg_hi = (ushort_t*)embproj;
  ushort_t* avg_lo = avg_hi + 65536;
  ushort_t* Whc_hi = Wf_hi;
  ushort_t* Whc_lo = Wf_hi + 2097152;

  // ---------------- prologue ----------------
  mavg_frag<<<dim3(32, 8), 256, 0, stream>>>(enc, avg_hi, avg_lo);
  convT_frag<<<dim3(16, 32), 256, 0, stream>>>(W_h, 512, Whc_hi, Whc_lo, 128, 0);
  convT_frag<<<dim3(16, 32), 256, 0, stream>>>(W_c, 512,
      Whc_hi + (size_t)16 * 128 * 512, Whc_lo + (size_t)16 * 128 * 512, 128, 0);
  mh0c0<<<dim3(8), 256, 0, stream>>>(avg_hi, avg_lo, Whc_hi, Whc_lo, b_h, b_c, h0f, cbuf);
  convA_fragH<<<dim3(196, 32), 256, 0, stream>>>(enc, e_hi);
  convT_frag<<<dim3(16, 32), 256, 0, stream>>>(W_enc, 512, We_hi, We_lo, 128, 0);
  convT_frag<<<dim3(16, 8), 256, 0, stream>>>(W_dec, 512, W1_hi, W1_lo, 32, 0);
  convT_frag<<<dim3(64, 8), 256, 0, stream>>>(W_fb, 2048,
      W1_hi + (size_t)16 * 32 * 512, W1_lo + (size_t)16 * 32 * 512, 32, 0);
  convT_frag<<<dim3(64, 32), 256, 0, stream>>>(W_ih + (size_t)512 * 2048, 2048,
      W3_hi, W3_lo, 160, 0);
  convT_frag<<<dim3(64, 8), 256, 0, stream>>>(W_hh, 2048, W3_hi, W3_lo, 160, 128);
  convT_fragH<<<dim3(1000, 8), 256, 0, stream>>>(W_fc, VOC, Wf_hi, 32, 0);  // after mh0c0
  convA_emb_frag<<<dim3(39, 8), 256, 0, stream>>>(emb, caps, eF_hi, eF_lo);
  convT_frag<<<dim3(64, 8), 256, 0, stream>>>(W_ih, 2048, WiE_hi, WiE_lo, 32, 0);

  menc_att<<<dim3(4, 196), 256, 0, stream>>>(e_hi, We_hi, We_lo, b_enc, encatt_bf);
  m_emb<<<dim3(16, 39), 256, 0, stream>>>(eF_hi, eF_lo, WiE_hi, WiE_lo, b_ih, b_hh, embproj);
  hsplit_frag<<<dim3(8), 256, 0, stream>>>(h0f, h_hi, h_lo, x_hi, x_lo);
  mk1<<<dim3(20), 256, 0, stream>>>(h_hi, h_lo, W1_hi, W1_lo, dec_gate);

  // ---------------- decode loop (preds deferred) ----------------
  for (int t = 0; t < TS; ++t) {
    k2a_soft<<<dim3(32), 512, 0, stream>>>(dec_gate, b_dec, w_att, b_att,
                                           encatt_bf, clen, out_alpha, al_ws, t);
    k2b_awe<<<dim3(32, 8), 256, 0, stream>>>(al_ws, dec_gate, b_fb, enc, x_hi, x_lo);
    mk3<<<dim3(16, 8), 256, 0, stream>>>(x_hi, x_lo, W3_hi, W3_lo, P2buf);
    k4_lstm_frag<<<dim3(32), 64, 0, stream>>>(P2buf, embproj, clen, cbuf,
                                              h_hi, h_lo, x_hi, x_lo, hh_hi, hh_lo, t);
    if (t < TS - 1)
      mk1<<<dim3(20), 256, 0, stream>>>(h_hi, h_lo, W1_hi, W1_lo, dec_gate);
  }

  // ---------------- deferred vocab projection (XCD-swizzled) ----------------
  mpreds<<<dim3(9750), 256, 0, stream>>>(hh_hi, hh_lo, Wf_hi, b_fc, clen, out_preds);
}

// Round 11
// 2049.854 us; speedup vs baseline: 1.3717x; 1.0643x over previous
//
#include <hip/hip_runtime.h>
#include <math.h>

#define NB 32
#define NP 196
#define ENC 2048
#define VOC 32000
#define LCAP 40
#define TS 39

typedef unsigned int uint_t;
typedef unsigned short ushort_t;

__device__ __forceinline__ float sigm(float x) { return 1.f / (1.f + expf(-x)); }

// ---------- bf16 helpers (RNE) ----------
__device__ __forceinline__ ushort_t f2bf(float f) {
  uint_t u = __float_as_uint(f);
  u = (u + 0x7FFFu + ((u >> 16) & 1u)) >> 16;
  return (ushort_t)u;
}
__device__ __forceinline__ float bf2f(ushort_t s) { return __uint_as_float(((uint_t)s) << 16); }

typedef __attribute__((ext_vector_type(8))) short bf8v;
typedef __attribute__((ext_vector_type(16))) float f16v;
typedef __attribute__((ext_vector_type(4))) float f4v;

__device__ __forceinline__ f16v MFMA(bf8v a, bf8v b, f16v c) {
  return __builtin_amdgcn_mfma_f32_32x32x16_bf16(a, b, c, 0, 0, 0);
}

// =====================================================================
// FRAGMENT LAYOUT: [tile][k_chunk][lane][8] ushorts; chunk = 512 ushorts.
// =====================================================================
// split-bf16 (3 MFMA/chunk): f32-class precision (recurrent paths)
__device__ __forceinline__ void mfma_pipe_frag(
    const ushort_t* __restrict__ pa_h, const ushort_t* __restrict__ pa_l,
    const ushort_t* __restrict__ pb_h, const ushort_t* __restrict__ pb_l,
    int nquad, f16v& acc)
{
  bf8v ah0 = *(const bf8v*)(pa_h +    0), al0 = *(const bf8v*)(pa_l +    0);
  bf8v bh0 = *(const bf8v*)(pb_h +    0), bl0 = *(const bf8v*)(pb_l +    0);
  bf8v ah1 = *(const bf8v*)(pa_h +  512), al1 = *(const bf8v*)(pa_l +  512);
  bf8v bh1 = *(const bf8v*)(pb_h +  512), bl1 = *(const bf8v*)(pb_l +  512);
  bf8v ah2 = *(const bf8v*)(pa_h + 1024), al2 = *(const bf8v*)(pa_l + 1024);
  bf8v bh2 = *(const bf8v*)(pb_h + 1024), bl2 = *(const bf8v*)(pb_l + 1024);
  bf8v ah3 = *(const bf8v*)(pa_h + 1536), al3 = *(const bf8v*)(pa_l + 1536);
  bf8v bh3 = *(const bf8v*)(pb_h + 1536), bl3 = *(const bf8v*)(pb_l + 1536);
  for (int q = 0; q < nquad; ++q) {
    const size_t nk = (size_t)(q + 1) * 2048;
    const bool more = (q + 1 < nquad);
    acc = MFMA(ah0, bh0, acc); acc = MFMA(ah0, bl0, acc); acc = MFMA(al0, bh0, acc);
    if (more) {
      ah0 = *(const bf8v*)(pa_h + nk +    0); al0 = *(const bf8v*)(pa_l + nk +    0);
      bh0 = *(const bf8v*)(pb_h + nk +    0); bl0 = *(const bf8v*)(pb_l + nk +    0);
    }
    acc = MFMA(ah1, bh1, acc); acc = MFMA(ah1, bl1, acc); acc = MFMA(al1, bh1, acc);
    if (more) {
      ah1 = *(const bf8v*)(pa_h + nk +  512); al1 = *(const bf8v*)(pa_l + nk +  512);
      bh1 = *(const bf8v*)(pb_h + nk +  512); bl1 = *(const bf8v*)(pb_l + nk +  512);
    }
    acc = MFMA(ah2, bh2, acc); acc = MFMA(ah2, bl2, acc); acc = MFMA(al2, bh2, acc);
    if (more) {
      ah2 = *(const bf8v*)(pa_h + nk + 1024); al2 = *(const bf8v*)(pa_l + nk + 1024);
      bh2 = *(const bf8v*)(pb_h + nk + 1024); bl2 = *(const bf8v*)(pb_l + nk + 1024);
    }
    acc = MFMA(ah3, bh3, acc); acc = MFMA(ah3, bl3, acc); acc = MFMA(al3, bh3, acc);
    if (more) {
      ah3 = *(const bf8v*)(pa_h + nk + 1536); al3 = *(const bf8v*)(pa_l + nk + 1536);
      bh3 = *(const bf8v*)(pb_h + nk + 1536); bl3 = *(const bf8v*)(pb_l + nk + 1536);
    }
  }
}

// A-hi-only (2 MFMA/chunk): A hi, B split (enc_att path)
__device__ __forceinline__ void mfma_pipe_fragAH(
    const ushort_t* __restrict__ pa_h,
    const ushort_t* __restrict__ pb_h, const ushort_t* __restrict__ pb_l,
    int nquad, f16v& acc)
{
  bf8v ah0 = *(const bf8v*)(pa_h +    0);
  bf8v bh0 = *(const bf8v*)(pb_h +    0), bl0 = *(const bf8v*)(pb_l +    0);
  bf8v ah1 = *(const bf8v*)(pa_h +  512);
  bf8v bh1 = *(const bf8v*)(pb_h +  512), bl1 = *(const bf8v*)(pb_l +  512);
  bf8v ah2 = *(const bf8v*)(pa_h + 1024);
  bf8v bh2 = *(const bf8v*)(pb_h + 1024), bl2 = *(const bf8v*)(pb_l + 1024);
  bf8v ah3 = *(const bf8v*)(pa_h + 1536);
  bf8v bh3 = *(const bf8v*)(pb_h + 1536), bl3 = *(const bf8v*)(pb_l + 1536);
  for (int q = 0; q < nquad; ++q) {
    const size_t nk = (size_t)(q + 1) * 2048;
    const bool more = (q + 1 < nquad);
    acc = MFMA(ah0, bh0, acc); acc = MFMA(ah0, bl0, acc);
    if (more) {
      ah0 = *(const bf8v*)(pa_h + nk +    0);
      bh0 = *(const bf8v*)(pb_h + nk +    0); bl0 = *(const bf8v*)(pb_l + nk +    0);
    }
    acc = MFMA(ah1, bh1, acc); acc = MFMA(ah1, bl1, acc);
    if (more) {
      ah1 = *(const bf8v*)(pa_h + nk +  512);
      bh1 = *(const bf8v*)(pb_h + nk +  512); bl1 = *(const bf8v*)(pb_l + nk +  512);
    }
    acc = MFMA(ah2, bh2, acc); acc = MFMA(ah2, bl2, acc);
    if (more) {
      ah2 = *(const bf8v*)(pa_h + nk + 1024);
      bh2 = *(const bf8v*)(pb_h + nk + 1024); bl2 = *(const bf8v*)(pb_l + nk + 1024);
    }
    acc = MFMA(ah3, bh3, acc); acc = MFMA(ah3, bl3, acc);
    if (more) {
      ah3 = *(const bf8v*)(pa_h + nk + 1536);
      bh3 = *(const bf8v*)(pb_h + nk + 1536); bl3 = *(const bf8v*)(pb_l + nk + 1536);
    }
  }
}

// hi-only (1 MFMA/chunk): preds path (A hi, B hi)
__device__ __forceinline__ void mfma_pipe_fragHH(
    const ushort_t* __restrict__ pa_h,
    const ushort_t* __restrict__ pb_h, int nquad, f16v& acc)
{
  bf8v ah0 = *(const bf8v*)(pa_h +    0);
  bf8v bh0 = *(const bf8v*)(pb_h +    0);
  bf8v ah1 = *(const bf8v*)(pa_h +  512);
  bf8v bh1 = *(const bf8v*)(pb_h +  512);
  bf8v ah2 = *(const bf8v*)(pa_h + 1024);
  bf8v bh2 = *(const bf8v*)(pb_h + 1024);
  bf8v ah3 = *(const bf8v*)(pa_h + 1536);
  bf8v bh3 = *(const bf8v*)(pb_h + 1536);
  for (int q = 0; q < nquad; ++q) {
    const size_t nk = (size_t)(q + 1) * 2048;
    const bool more = (q + 1 < nquad);
    acc = MFMA(ah0, bh0, acc);
    if (more) { ah0 = *(const bf8v*)(pa_h + nk +    0); bh0 = *(const bf8v*)(pb_h + nk +    0); }
    acc = MFMA(ah1, bh1, acc);
    if (more) { ah1 = *(const bf8v*)(pa_h + nk +  512); bh1 = *(const bf8v*)(pb_h + nk +  512); }
    acc = MFMA(ah2, bh2, acc);
    if (more) { ah2 = *(const bf8v*)(pa_h + nk + 1024); bh2 = *(const bf8v*)(pb_h + nk + 1024); }
    acc = MFMA(ah3, bh3, acc);
    if (more) { ah3 = *(const bf8v*)(pa_h + nk + 1536); bh3 = *(const bf8v*)(pb_h + nk + 1536); }
  }
}

// C/D mapping (HW-verified): col = lane&31, row = (reg&3)+8*(reg>>2)+4*(lane>>5)
#define CD_ROW(rr, g) (((rr) & 3) + 8 * ((rr) >> 2) + 4 * (g))

// ---------------- enc_att -> encatt_bf[b][a][p] (bf16), A-hi-only ----------------
__global__ __launch_bounds__(256) void menc_att(
    const ushort_t* __restrict__ Ahi,
    const ushort_t* __restrict__ Whi, const ushort_t* __restrict__ Wlo,
    const float* __restrict__ benc, ushort_t* __restrict__ encatt_bf)
{
  __shared__ float tileS[4][32][33];
  int w = threadIdx.x >> 6, lane = threadIdx.x & 63;
  int mt = blockIdx.y;                 // 196 m-tiles
  int ct = blockIdx.x * 4 + w;         // 16 col-tiles
  const ushort_t* pa_h = Ahi + ((size_t)mt * 128) * 512 + lane * 8;
  const ushort_t* pb_h = Whi + ((size_t)ct * 128) * 512 + lane * 8;
  const ushort_t* pb_l = Wlo + ((size_t)ct * 128) * 512 + lane * 8;
  f16v acc = (f16v)(0.0f);
  mfma_pipe_fragAH(pa_h, pb_h, pb_l, 32, acc);
  int r = lane & 31, g = lane >> 5;
  float bn = benc[ct * 32 + r];
#pragma unroll
  for (int rr = 0; rr < 16; ++rr)
    tileS[w][r][CD_ROW(rr, g)] = acc[rr] + bn;   // [a_local][p_local]
  __syncthreads();
#pragma unroll
  for (int j = 0; j < 4; ++j) {
    int a_l = j * 8 + (lane >> 3);
    int p4 = (lane & 7) * 4;
    int n2 = ct * 32 + a_l;
#pragma unroll
    for (int jj = 0; jj < 4; ++jj) {
      int pl = p4 + jj;
      int rg = mt * 32 + pl;
      int b = rg / 196, pp = rg - b * 196;
      encatt_bf[((size_t)b * 512 + n2) * 196 + pp] = f2bf(tileS[w][a_l][pl]);
    }
  }
}

// ---------------- k1: dec_gate = h @ [W_dec | W_fb] ----------------
__global__ __launch_bounds__(256) void mk1(
    const ushort_t* __restrict__ hhi, const ushort_t* __restrict__ hlo,
    const ushort_t* __restrict__ W1hi, const ushort_t* __restrict__ W1lo,
    float* __restrict__ dec_gate)
{
  int w = threadIdx.x >> 6, lane = threadIdx.x & 63;
  int ct = blockIdx.x * 4 + w;         // 80 col-tiles
  const ushort_t* pa_h = hhi + lane * 8;
  const ushort_t* pa_l = hlo + lane * 8;
  const ushort_t* pb_h = W1hi + ((size_t)ct * 32) * 512 + lane * 8;
  const ushort_t* pb_l = W1lo + ((size_t)ct * 32) * 512 + lane * 8;
  f16v acc = (f16v)(0.0f);
  mfma_pipe_frag(pa_h, pa_l, pb_h, pb_l, 8, acc);
  int r = lane & 31, g = lane >> 5;
  int n = ct * 32 + r;
#pragma unroll
  for (int rr = 0; rr < 16; ++rr)
    dec_gate[CD_ROW(rr, g) * 2560 + n] = acc[rr];
}

// ---------------- k3: P2[s] = partial of x(=[aweg|h]) @ W3 ----------------
__global__ __launch_bounds__(256) void mk3(
    const ushort_t* __restrict__ xhi, const ushort_t* __restrict__ xlo,
    const ushort_t* __restrict__ W3hi, const ushort_t* __restrict__ W3lo,
    float* __restrict__ P2)
{
  int w = threadIdx.x >> 6, lane = threadIdx.x & 63;
  int ct = blockIdx.x * 4 + w;         // 64 col-tiles
  int s = blockIdx.y;                  // 8 k-slices of 20 chunks
  const ushort_t* pa_h = xhi + ((size_t)s * 20) * 512 + lane * 8;
  const ushort_t* pa_l = xlo + ((size_t)s * 20) * 512 + lane * 8;
  const ushort_t* pb_h = W3hi + ((size_t)ct * 160 + s * 20) * 512 + lane * 8;
  const ushort_t* pb_l = W3lo + ((size_t)ct * 160 + s * 20) * 512 + lane * 8;
  f16v acc = (f16v)(0.0f);
  mfma_pipe_frag(pa_h, pa_l, pb_h, pb_l, 5, acc);
  int r = lane & 31, g = lane >> 5;
  int n = ct * 32 + r;
#pragma unroll
  for (int rr = 0; rr < 16; ++rr)
    P2[(size_t)s * (32 * 2048) + CD_ROW(rr, g) * 2048 + n] = acc[rr];
}

// ---------------- mpreds (deferred, XCD-swizzled, hi-only) ----------------
__global__ __launch_bounds__(256) void mpreds(
    const ushort_t* __restrict__ hhist_hi,
    const ushort_t* __restrict__ Wfchi, const float* __restrict__ bfc,
    const int* __restrict__ clen, float* __restrict__ outp)
{
  // nwg = 9750, q = 1218, r = 6 (bijective XCD swizzle, m204)
  int orig = blockIdx.x;
  int xcd = orig & 7, i = orig >> 3;
  int base = (xcd < 6) ? xcd * 1219 : 6 * 1219 + (xcd - 6) * 1218;
  int wgid = base + i;
  int ct4 = wgid / 39, mt = wgid - ct4 * 39;   // ct-major: Wfc tile L2-resident per XCD
  int w = threadIdx.x >> 6, lane = threadIdx.x & 63;
  int ct = ct4 * 4 + w;                        // 1000 col-tiles
  const ushort_t* pa_h = hhist_hi + ((size_t)mt * 32) * 512 + lane * 8;
  const ushort_t* pb_h = Wfchi + ((size_t)ct * 32) * 512 + lane * 8;
  f16v acc = (f16v)(0.0f);
  mfma_pipe_fragHH(pa_h, pb_h, 8, acc);
  int r = lane & 31, g = lane >> 5;
  int n = ct * 32 + r;
  float bn = bfc[n];
#pragma unroll
  for (int rr = 0; rr < 16; ++rr) {
    int b = CD_ROW(rr, g);
    bool act = clen[b] - 1 > mt;
    outp[(size_t)b * (TS * VOC) + (size_t)mt * VOC + n] = act ? (acc[rr] + bn) : 0.f;
  }
}

// ---------------- conversions ----------------
// enc [6272][2048] f32 -> A-frag hi only
__global__ __launch_bounds__(256) void convA_fragH(
    const float* __restrict__ src, ushort_t* __restrict__ dhi)
{
  int mt = blockIdx.x;
  int kc = blockIdx.y * 4 + (threadIdx.x >> 6);
  int l = threadIdx.x & 63;
  int r = l & 31, g = l >> 5;
  const float* s = src + (size_t)(mt * 32 + r) * 2048 + kc * 16 + g * 8;
  float4 v0 = *(const float4*)s, v1 = *(const float4*)(s + 4);
  ushort4 h0, h1;
  h0.x = f2bf(v0.x); h0.y = f2bf(v0.y); h0.z = f2bf(v0.z); h0.w = f2bf(v0.w);
  h1.x = f2bf(v1.x); h1.y = f2bf(v1.y); h1.z = f2bf(v1.z); h1.w = f2bf(v1.w);
  size_t off = ((size_t)mt * 128 + kc) * 512 + (size_t)l * 8;
  *(ushort4*)&dhi[off] = h0; *(ushort4*)&dhi[off + 4] = h1;
}

// enc f32 -> plain bf16 copy [6272][2048] (for k2b)
__global__ __launch_bounds__(256) void conv_enc_bf(
    const float* __restrict__ src, ushort_t* __restrict__ dst)
{
  size_t i = ((size_t)blockIdx.x * 256 + threadIdx.x) * 8;   // 6272*2048/8 threads
  float4 v0 = *(const float4*)&src[i], v1 = *(const float4*)&src[i + 4];
  ushort4 h0, h1;
  h0.x = f2bf(v0.x); h0.y = f2bf(v0.y); h0.z = f2bf(v0.z); h0.w = f2bf(v0.w);
  h1.x = f2bf(v1.x); h1.y = f2bf(v1.y); h1.z = f2bf(v1.z); h1.w = f2bf(v1.w);
  *(ushort4*)&dst[i] = h0; *(ushort4*)&dst[i + 4] = h1;
}

// gathered embedding rows -> A-frag: tile mt = timestep, row = batch
__global__ __launch_bounds__(256) void convA_emb_frag(
    const float* __restrict__ Emb, const int* __restrict__ caps,
    ushort_t* __restrict__ dhi, ushort_t* __restrict__ dlo)
{
  int mt = blockIdx.x;
  int kc = blockIdx.y * 4 + (threadIdx.x >> 6);
  int l = threadIdx.x & 63;
  int r = l & 31, g = l >> 5;
  int tok = caps[r * LCAP + mt];
  const float* s = Emb + (size_t)tok * 512 + kc * 16 + g * 8;
  float4 v0 = *(const float4*)s, v1 = *(const float4*)(s + 4);
  ushort4 h0, l0, h1, l1;
  h0.x = f2bf(v0.x); l0.x = f2bf(v0.x - bf2f(h0.x));
  h0.y = f2bf(v0.y); l0.y = f2bf(v0.y - bf2f(h0.y));
  h0.z = f2bf(v0.z); l0.z = f2bf(v0.z - bf2f(h0.z));
  h0.w = f2bf(v0.w); l0.w = f2bf(v0.w - bf2f(h0.w));
  h1.x = f2bf(v1.x); l1.x = f2bf(v1.x - bf2f(h1.x));
  h1.y = f2bf(v1.y); l1.y = f2bf(v1.y - bf2f(h1.y));
  h1.z = f2bf(v1.z); l1.z = f2bf(v1.z - bf2f(h1.z));
  h1.w = f2bf(v1.w); l1.w = f2bf(v1.w - bf2f(h1.w));
  size_t off = ((size_t)mt * 32 + kc) * 512 + (size_t)l * 8;
  *(ushort4*)&dhi[off] = h0; *(ushort4*)&dhi[off + 4] = h1;
  *(ushort4*)&dlo[off] = l0; *(ushort4*)&dlo[off + 4] = l1;
}

// W [K][N] f32 -> B-frag tiles (hi+lo)
__global__ __launch_bounds__(256) void convT_frag(
    const float* __restrict__ src, int N,
    ushort_t* __restrict__ dhi, ushort_t* __restrict__ dlo,
    int nkc_dst, int kc_off)
{
  int ct = blockIdx.x;
  int kc = blockIdx.y * 4 + (threadIdx.x >> 6);
  int l = threadIdx.x & 63;
  int c = l & 31, g = l >> 5;
  const float* s = src + (size_t)(kc * 16 + g * 8) * N + ct * 32 + c;
  ushort_t hi8[8], lo8[8];
#pragma unroll
  for (int e = 0; e < 8; ++e) {
    float f = s[(size_t)e * N];
    hi8[e] = f2bf(f); lo8[e] = f2bf(f - bf2f(hi8[e]));
  }
  size_t off = ((size_t)ct * nkc_dst + kc_off + kc) * 512 + (size_t)l * 8;
  *(ushort4*)&dhi[off]     = make_ushort4(hi8[0], hi8[1], hi8[2], hi8[3]);
  *(ushort4*)&dhi[off + 4] = make_ushort4(hi8[4], hi8[5], hi8[6], hi8[7]);
  *(ushort4*)&dlo[off]     = make_ushort4(lo8[0], lo8[1], lo8[2], lo8[3]);
  *(ushort4*)&dlo[off + 4] = make_ushort4(lo8[4], lo8[5], lo8[6], lo8[7]);
}

// W [K][N] f32 -> B-frag tiles (hi only)
__global__ __launch_bounds__(256) void convT_fragH(
    const float* __restrict__ src, int N,
    ushort_t* __restrict__ dhi, int nkc_dst, int kc_off)
{
  int ct = blockIdx.x;
  int kc = blockIdx.y * 4 + (threadIdx.x >> 6);
  int l = threadIdx.x & 63;
  int c = l & 31, g = l >> 5;
  const float* s = src + (size_t)(kc * 16 + g * 8) * N + ct * 32 + c;
  ushort_t hi8[8];
#pragma unroll
  for (int e = 0; e < 8; ++e) hi8[e] = f2bf(s[(size_t)e * N]);
  size_t off = ((size_t)ct * nkc_dst + kc_off + kc) * 512 + (size_t)l * 8;
  *(ushort4*)&dhi[off]     = make_ushort4(hi8[0], hi8[1], hi8[2], hi8[3]);
  *(ushort4*)&dhi[off + 4] = make_ushort4(hi8[4], hi8[5], hi8[6], hi8[7]);
}

// ---------------- avg over P, written directly in A-frag hi/lo ----------------
__global__ __launch_bounds__(256) void mavg_frag(
    const float* __restrict__ enc, ushort_t* __restrict__ dhi, ushort_t* __restrict__ dlo)
{
  int b = blockIdx.x;
  int e = blockIdx.y * 256 + threadIdx.x;
  float s = 0.f;
  const float* base = enc + (size_t)b * 196 * 2048 + e;
  for (int p = 0; p < NP; ++p) s += base[(size_t)p * 2048];
  s *= (1.f / 196.f);
  ushort_t hi = f2bf(s), lo = f2bf(s - bf2f(hi));
  size_t off = (size_t)(e >> 4) * 512 + ((e >> 3) & 1) * 256 + b * 8 + (e & 7);
  dhi[off] = hi; dlo[off] = lo;
}

// ---------------- h0,c0 = avg @ [W_h | W_c] + bias (MFMA) ----------------
__global__ __launch_bounds__(256) void mh0c0(
    const ushort_t* __restrict__ avg_hi, const ushort_t* __restrict__ avg_lo,
    const ushort_t* __restrict__ Whc_hi, const ushort_t* __restrict__ Whc_lo,
    const float* __restrict__ b_h, const float* __restrict__ b_c,
    float* __restrict__ h0f, float* __restrict__ cbuf)
{
  int w = threadIdx.x >> 6, lane = threadIdx.x & 63;
  int ct = blockIdx.x * 4 + w;
  const ushort_t* pa_h = avg_hi + lane * 8;
  const ushort_t* pa_l = avg_lo + lane * 8;
  const ushort_t* pb_h = Whc_hi + ((size_t)ct * 128) * 512 + lane * 8;
  const ushort_t* pb_l = Whc_lo + ((size_t)ct * 128) * 512 + lane * 8;
  f16v acc = (f16v)(0.0f);
  mfma_pipe_frag(pa_h, pa_l, pb_h, pb_l, 32, acc);
  int r = lane & 31, g = lane >> 5;
  int n = ct * 32 + r;
  if (ct < 16) {
    float bn = b_h[n];
#pragma unroll
    for (int rr = 0; rr < 16; ++rr)
      h0f[CD_ROW(rr, g) * 512 + n] = acc[rr] + bn;
  } else {
    int n2 = n - 512;
    float bn = b_c[n2];
#pragma unroll
    for (int rr = 0; rr < 16; ++rr)
      cbuf[CD_ROW(rr, g) * 512 + n2] = acc[rr] + bn;
  }
}

// ---------------- embproj = embF @ W_ih[:512] + b_ih + b_hh (MFMA) ----------------
__global__ __launch_bounds__(256) void m_emb(
    const ushort_t* __restrict__ eFhi, const ushort_t* __restrict__ eFlo,
    const ushort_t* __restrict__ Whi, const ushort_t* __restrict__ Wlo,
    const float* __restrict__ b1, const float* __restrict__ b2,
    float* __restrict__ embproj)
{
  int w = threadIdx.x >> 6, lane = threadIdx.x & 63;
  int mt = blockIdx.y;
  int ct = blockIdx.x * 4 + w;
  const ushort_t* pa_h = eFhi + ((size_t)mt * 32) * 512 + lane * 8;
  const ushort_t* pa_l = eFlo + ((size_t)mt * 32) * 512 + lane * 8;
  const ushort_t* pb_h = Whi + ((size_t)ct * 32) * 512 + lane * 8;
  const ushort_t* pb_l = Wlo + ((size_t)ct * 32) * 512 + lane * 8;
  f16v acc = (f16v)(0.0f);
  mfma_pipe_frag(pa_h, pa_l, pb_h, pb_l, 8, acc);
  int r = lane & 31, g = lane >> 5;
  int n = ct * 32 + r;
  float bn = b1[n] + b2[n];
#pragma unroll
  for (int rr = 0; rr < 16; ++rr)
    embproj[(size_t)(mt * 32 + CD_ROW(rr, g)) * 2048 + n] = acc[rr] + bn;
}

// ---------------- h0 -> h frag + x frag (h cols) ----------------
__global__ __launch_bounds__(256) void hsplit_frag(
    const float* __restrict__ h0f,
    ushort_t* __restrict__ hhi, ushort_t* __restrict__ hlo,
    ushort_t* __restrict__ xhi, ushort_t* __restrict__ xlo)
{
  int idx = blockIdx.x * 256 + threadIdx.x;
  int b = idx >> 6, dq = idx & 63, d0 = dq << 3;
  ushort4 h0v, h1v, l0v, l1v;
  ushort_t hh[8], hl[8];
#pragma unroll
  for (int j = 0; j < 8; ++j) {
    float v = h0f[b * 512 + d0 + j];
    hh[j] = f2bf(v); hl[j] = f2bf(v - bf2f(hh[j]));
  }
  h0v = make_ushort4(hh[0], hh[1], hh[2], hh[3]); h1v = make_ushort4(hh[4], hh[5], hh[6], hh[7]);
  l0v = make_ushort4(hl[0], hl[1], hl[2], hl[3]); l1v = make_ushort4(hl[4], hl[5], hl[6], hl[7]);
  int kc = d0 >> 4, g = (d0 >> 3) & 1;
  size_t off = ((size_t)kc * 64 + g * 32 + b) * 8;
  *(ushort4*)&hhi[off] = h0v; *(ushort4*)&hhi[off + 4] = h1v;
  *(ushort4*)&hlo[off] = l0v; *(ushort4*)&hlo[off + 4] = l1v;
  int xk0 = 2048 + d0;
  size_t offx = ((size_t)(xk0 >> 4) * 64 + g * 32 + b) * 8;
  *(ushort4*)&xhi[offx] = h0v; *(ushort4*)&xhi[offx + 4] = h1v;
  *(ushort4*)&xlo[offx] = l0v; *(ushort4*)&xlo[offx + 4] = l1v;
}

// ---------------- k2a: e + softmax; bf16 encatt, 512 threads, 2-way a-split ----------------
__global__ __launch_bounds__(512) void k2a_soft(
    const float* __restrict__ dec_gate, const float* __restrict__ bdec,
    const float* __restrict__ watt, const float* __restrict__ batt,
    const ushort_t* __restrict__ encatt_bf, const int* __restrict__ clen,
    float* __restrict__ outa, float* __restrict__ al_ws, int t)
{
  int b = blockIdx.x, tid = threadIdx.x;
  __shared__ float dec_s[512], watt_s[512], part_s[2][256], red_s[256];
  dec_s[tid] = dec_gate[b * 2560 + tid] + bdec[tid];
  watt_s[tid] = watt[tid];
  __syncthreads();
  int p = tid & 255, half = tid >> 8;
  float acc = 0.f;
  if (p < NP) {
    const ushort_t* col = encatt_bf + (size_t)b * 512 * 196 + p;
    int a0 = half * 256;
#pragma unroll 8
    for (int a = a0; a < a0 + 256; ++a)
      acc += fmaxf(bf2f(col[(size_t)a * 196]) + dec_s[a], 0.f) * watt_s[a];
  }
  part_s[half][p] = acc;
  __syncthreads();
  float e = -1e30f;
  if (tid < NP) e = part_s[0][tid] + part_s[1][tid] + batt[0];
  if (tid < 256) red_s[tid] = e;
  __syncthreads();
  for (int wd = 128; wd > 0; wd >>= 1) {
    if (tid < wd) red_s[tid] = fmaxf(red_s[tid], red_s[tid + wd]);
    __syncthreads();
  }
  float m = red_s[0];
  __syncthreads();
  float ex = (tid < NP) ? expf(e - m) : 0.f;
  if (tid < 256) red_s[tid] = ex;
  __syncthreads();
  for (int wd = 128; wd > 0; wd >>= 1) {
    if (tid < wd) red_s[tid] += red_s[tid + wd];
    __syncthreads();
  }
  float inv = 1.f / red_s[0];
  if (tid < NP) {
    float al = ex * inv;
    al_ws[b * NP + tid] = al;
    bool act = clen[b] - 1 > t;
    outa[(size_t)(b * TS + t) * NP + tid] = act ? al : 0.f;
  }
}

// ---------------- k2b: awe + gate -> x frag cols 0..2047 (bf16 enc, grid 32 x 8) ----------------
__global__ __launch_bounds__(256) void k2b_awe(
    const float* __restrict__ al_ws, const float* __restrict__ dec_gate,
    const float* __restrict__ bfb, const ushort_t* __restrict__ enc_bf,
    ushort_t* __restrict__ xhi, ushort_t* __restrict__ xlo)
{
  int b = blockIdx.x, ds = blockIdx.y, tid = threadIdx.x;
  __shared__ float al_s[196];
  __shared__ float part[4][64][4];
  if (tid < NP) al_s[tid] = al_ws[b * NP + tid];
  __syncthreads();
  int q = tid & 63, sp = tid >> 6;
  int d = ds * 256 + q * 4;
  float ax = 0.f, ay = 0.f, az = 0.f, aw = 0.f;
  int p0 = sp * 49;
#pragma unroll 7
  for (int p = p0; p < p0 + 49; ++p) {
    float al = al_s[p];
    ushort4 ev = *(const ushort4*)&enc_bf[(size_t)(b * NP + p) * ENC + d];
    ax += al * bf2f(ev.x); ay += al * bf2f(ev.y);
    az += al * bf2f(ev.z); aw += al * bf2f(ev.w);
  }
  part[sp][q][0] = ax; part[sp][q][1] = ay; part[sp][q][2] = az; part[sp][q][3] = aw;
  __syncthreads();
  if (sp == 0) {
    ax = part[0][q][0] + part[1][q][0] + part[2][q][0] + part[3][q][0];
    ay = part[0][q][1] + part[1][q][1] + part[2][q][1] + part[3][q][1];
    az = part[0][q][2] + part[1][q][2] + part[2][q][2] + part[3][q][2];
    aw = part[0][q][3] + part[1][q][3] + part[2][q][3] + part[3][q][3];
    float4 gg = *(const float4*)&dec_gate[b * 2560 + 512 + d];
    float4 bb = *(const float4*)&bfb[d];
    float v0 = sigm(gg.x + bb.x) * ax;
    float v1 = sigm(gg.y + bb.y) * ay;
    float v2 = sigm(gg.z + bb.z) * az;
    float v3 = sigm(gg.w + bb.w) * aw;
    ushort4 hi, lo;
    hi.x = f2bf(v0); lo.x = f2bf(v0 - bf2f(hi.x));
    hi.y = f2bf(v1); lo.y = f2bf(v1 - bf2f(hi.y));
    hi.z = f2bf(v2); lo.z = f2bf(v2 - bf2f(hi.z));
    hi.w = f2bf(v3); lo.w = f2bf(v3 - bf2f(hi.w));
    size_t off = ((size_t)(d >> 4) * 64 + ((d >> 3) & 1) * 32 + b) * 8 + (d & 7);
    *(ushort4*)&xhi[off] = hi;
    *(ushort4*)&xlo[off] = lo;
  }
}

// ---------------- k4: LSTM pointwise + state update + h history (hi only) ----------------
__global__ __launch_bounds__(64) void k4_lstm_frag(
    const float* __restrict__ P2, const float* __restrict__ embproj,
    const int* __restrict__ clen, float* __restrict__ c,
    ushort_t* __restrict__ hhi, ushort_t* __restrict__ hlo,
    ushort_t* __restrict__ xhi, ushort_t* __restrict__ xlo,
    ushort_t* __restrict__ hhist_hi, int t)
{
  int idx = blockIdx.x * 64 + threadIdx.x;   // 2048: b*64 + dq
  int b = idx >> 6, dq = idx & 63, d0 = dq << 3;
  bool act = clen[b] - 1 > t;
  const float* ep = embproj + (size_t)(t * 32 + b) * 2048;
  f4v i0 = *(const f4v*)&ep[d0],        i1 = *(const f4v*)&ep[d0 + 4];
  f4v f0 = *(const f4v*)&ep[512 + d0],  f1 = *(const f4v*)&ep[512 + d0 + 4];
  f4v g0 = *(const f4v*)&ep[1024 + d0], g1 = *(const f4v*)&ep[1024 + d0 + 4];
  f4v o0 = *(const f4v*)&ep[1536 + d0], o1 = *(const f4v*)&ep[1536 + d0 + 4];
#pragma unroll
  for (int s = 0; s < 8; ++s) {
    const float* p2 = P2 + (size_t)s * 65536 + b * 2048;
    i0 += *(const f4v*)&p2[d0];        i1 += *(const f4v*)&p2[d0 + 4];
    f0 += *(const f4v*)&p2[512 + d0];  f1 += *(const f4v*)&p2[512 + d0 + 4];
    g0 += *(const f4v*)&p2[1024 + d0]; g1 += *(const f4v*)&p2[1024 + d0 + 4];
    o0 += *(const f4v*)&p2[1536 + d0]; o1 += *(const f4v*)&p2[1536 + d0 + 4];
  }
  f4v c0 = *(const f4v*)&c[b * 512 + d0], c1 = *(const f4v*)&c[b * 512 + d0 + 4];
  ushort_t hh[8], hl[8];
  f4v cn0, cn1;
#pragma unroll
  for (int j = 0; j < 8; ++j) {
    float iv = j < 4 ? i0[j] : i1[j - 4];
    float fv = j < 4 ? f0[j] : f1[j - 4];
    float gv = j < 4 ? g0[j] : g1[j - 4];
    float ov = j < 4 ? o0[j] : o1[j - 4];
    float cv = j < 4 ? c0[j] : c1[j - 4];
    float cn = sigm(fv) * cv + sigm(iv) * tanhf(gv);
    float hn = sigm(ov) * tanhf(cn);
    if (j < 4) cn0[j] = cn; else cn1[j - 4] = cn;
    hh[j] = f2bf(hn); hl[j] = f2bf(hn - bf2f(hh[j]));
  }
  ushort4 h0v = make_ushort4(hh[0], hh[1], hh[2], hh[3]);
  ushort4 h1v = make_ushort4(hh[4], hh[5], hh[6], hh[7]);
  ushort4 l0v = make_ushort4(hl[0], hl[1], hl[2], hl[3]);
  ushort4 l1v = make_ushort4(hl[4], hl[5], hl[6], hl[7]);
  int kc = d0 >> 4, g = (d0 >> 3) & 1;
  // h history (h_new pre-mask): always write
  size_t offh = ((size_t)(t * 32 + kc)) * 512 + ((size_t)g * 32 + b) * 8;
  *(ushort4*)&hhist_hi[offh] = h0v; *(ushort4*)&hhist_hi[offh + 4] = h1v;
  if (!act) return;                   // inactive rows: state frozen
  *(f4v*)&c[b * 512 + d0] = cn0; *(f4v*)&c[b * 512 + d0 + 4] = cn1;
  size_t off = ((size_t)kc * 64 + g * 32 + b) * 8;
  *(ushort4*)&hhi[off] = h0v; *(ushort4*)&hhi[off + 4] = h1v;
  *(ushort4*)&hlo[off] = l0v; *(ushort4*)&hlo[off + 4] = l1v;
  int xk0 = 2048 + d0;
  size_t offx = ((size_t)(xk0 >> 4) * 64 + g * 32 + b) * 8;
  *(ushort4*)&xhi[offx] = h0v; *(ushort4*)&xhi[offx + 4] = h1v;
  *(ushort4*)&xlo[offx] = l0v; *(ushort4*)&xlo[offx + 4] = l1v;
}

// =====================================================================
extern "C" void kernel_launch(void* const* d_in, const int* in_sizes, int n_in,
                              void* d_out, int out_size, void* d_ws, size_t ws_size,
                              hipStream_t stream)
{
  (void)in_sizes; (void)n_in; (void)out_size; (void)ws_size;
  const float* enc   = (const float*)d_in[0];
  const int*   caps  = (const int*)d_in[1];
  const int*   clen  = (const int*)d_in[2];
  const float* emb   = (const float*)d_in[3];
  const float* W_enc = (const float*)d_in[4];
  const float* b_enc = (const float*)d_in[5];
  const float* W_dec = (const float*)d_in[6];
  const float* b_dec = (const float*)d_in[7];
  const float* w_att = (const float*)d_in[8];
  const float* b_att = (const float*)d_in[9];
  const float* W_ih  = (const float*)d_in[10];
  const float* b_ih  = (const float*)d_in[11];
  const float* W_hh  = (const float*)d_in[12];
  const float* b_hh  = (const float*)d_in[13];
  const float* W_h   = (const float*)d_in[14];
  const float* b_h   = (const float*)d_in[15];
  const float* W_c   = (const float*)d_in[16];
  const float* b_c   = (const float*)d_in[17];
  const float* W_fb  = (const float*)d_in[18];
  const float* b_fb  = (const float*)d_in[19];
  const float* W_fc  = (const float*)d_in[20];
  const float* b_fc  = (const float*)d_in[21];

  float* out_preds = (float*)d_out;
  float* out_alpha = out_preds + (size_t)NB * TS * VOC;

  // ---------- workspace layout (within proven 173,539,328-byte footprint) ----------
  char* p = (char*)d_ws;
  ushort_t* encatt_bf = (ushort_t*)p;     p += 12845056;
  float* embproj  = (float*)p;            p += 10223616;
  float* P2buf    = (float*)p;            p += 2097152;
  float* dec_gate = (float*)p;            p += 327680;
  ushort_t* x_lo  = (ushort_t*)p;         p += 262144;
  float* h0f      = (float*)p;            p += 65536;
  float* cbuf     = (float*)p;            p += 65536;
  float* al_ws    = (float*)p;            p += 25088;
  ushort_t* h_hi  = (ushort_t*)p;         p += 32768;
  ushort_t* h_lo  = (ushort_t*)p;         p += 32768;
  ushort_t* x_hi  = (ushort_t*)p;         p += 163840;
  p += 262144 - 25088 - 32768 - 32768 - 163840;
  ushort_t* e_hi  = (ushort_t*)p;         p += 25690112;
  ushort_t* enc_bf = (ushort_t*)p;        p += 25690112;   // plain [6272][2048] bf16
  ushort_t* We_hi = (ushort_t*)p;         p += 2097152;
  ushort_t* We_lo = (ushort_t*)p;         p += 2097152;
  ushort_t* W1_hi = (ushort_t*)p;         p += 2621440;
  ushort_t* W1_lo = (ushort_t*)p;         p += 2621440;
  ushort_t* W3_hi = (ushort_t*)p;         p += 10485760;
  ushort_t* W3_lo = (ushort_t*)p;         p += 10485760;
  ushort_t* Wf_hi = (ushort_t*)p;         p += 32768000;
  ushort_t* WiE_hi = (ushort_t*)p;        p += 2097152;
  ushort_t* WiE_lo = (ushort_t*)p;        p += 2097152;
  ushort_t* eF_hi  = (ushort_t*)p;        p += 1277952;
  ushort_t* eF_lo  = (ushort_t*)p;        p += 1277952;
  ushort_t* hh_hi  = (ushort_t*)p;        p += 1277952;

  // prologue-only aliases (regions rewritten later, stream-ordered):
  ushort_t* avg_hi = (ushort_t*)embproj;
  ushort_t* avg_lo = avg_hi + 65536;
  ushort_t* Whc_hi = Wf_hi;
  ushort_t* Whc_lo = Wf_hi + 2097152;

  // ---------------- prologue ----------------
  mavg_frag<<<dim3(32, 8), 256, 0, stream>>>(enc, avg_hi, avg_lo);
  convT_frag<<<dim3(16, 32), 256, 0, stream>>>(W_h, 512, Whc_hi, Whc_lo, 128, 0);
  convT_frag<<<dim3(16, 32), 256, 0, stream>>>(W_c, 512,
      Whc_hi + (size_t)16 * 128 * 512, Whc_lo + (size_t)16 * 128 * 512, 128, 0);
  mh0c0<<<dim3(8), 256, 0, stream>>>(avg_hi, avg_lo, Whc_hi, Whc_lo, b_h, b_c, h0f, cbuf);
  convA_fragH<<<dim3(196, 32), 256, 0, stream>>>(enc, e_hi);
  conv_enc_bf<<<dim3(6272), 256, 0, stream>>>(enc, enc_bf);
  convT_frag<<<dim3(16, 32), 256, 0, stream>>>(W_enc, 512, We_hi, We_lo, 128, 0);
  convT_frag<<<dim3(16, 8), 256, 0, stream>>>(W_dec, 512, W1_hi, W1_lo, 32, 0);
  convT_frag<<<dim3(64, 8), 256, 0, stream>>>(W_fb, 2048,
      W1_hi + (size_t)16 * 32 * 512, W1_lo + (size_t)16 * 32 * 512, 32, 0);
  convT_frag<<<dim3(64, 32), 256, 0, stream>>>(W_ih + (size_t)512 * 2048, 2048,
      W3_hi, W3_lo, 160, 0);
  convT_frag<<<dim3(64, 8), 256, 0, stream>>>(W_hh, 2048, W3_hi, W3_lo, 160, 128);
  convT_fragH<<<dim3(1000, 8), 256, 0, stream>>>(W_fc, VOC, Wf_hi, 32, 0);  // after mh0c0
  convA_emb_frag<<<dim3(39, 8), 256, 0, stream>>>(emb, caps, eF_hi, eF_lo);
  convT_frag<<<dim3(64, 8), 256, 0, stream>>>(W_ih, 2048, WiE_hi, WiE_lo, 32, 0);

  menc_att<<<dim3(4, 196), 256, 0, stream>>>(e_hi, We_hi, We_lo, b_enc, encatt_bf);
  m_emb<<<dim3(16, 39), 256, 0, stream>>>(eF_hi, eF_lo, WiE_hi, WiE_lo, b_ih, b_hh, embproj);
  hsplit_frag<<<dim3(8), 256, 0, stream>>>(h0f, h_hi, h_lo, x_hi, x_lo);
  mk1<<<dim3(20), 256, 0, stream>>>(h_hi, h_lo, W1_hi, W1_lo, dec_gate);

  // ---------------- decode loop (preds deferred) ----------------
  for (int t = 0; t < TS; ++t) {
    k2a_soft<<<dim3(32), 512, 0, stream>>>(dec_gate, b_dec, w_att, b_att,
                                           encatt_bf, clen, out_alpha, al_ws, t);
    k2b_awe<<<dim3(32, 8), 256, 0, stream>>>(al_ws, dec_gate, b_fb, enc_bf, x_hi, x_lo);
    mk3<<<dim3(16, 8), 256, 0, stream>>>(x_hi, x_lo, W3_hi, W3_lo, P2buf);
    k4_lstm_frag<<<dim3(32), 64, 0, stream>>>(P2buf, embproj, clen, cbuf,
                                              h_hi, h_lo, x_hi, x_lo, hh_hi, t);
    if (t < TS - 1)
      mk1<<<dim3(20), 256, 0, stream>>>(h_hi, h_lo, W1_hi, W1_lo, dec_gate);
  }

  // ---------------- deferred vocab projection (XCD-swizzled, hi-only) ----------------
  mpreds<<<dim3(9750), 256, 0, stream>>>(hh_hi, Wf_hi, b_fc, clen, out_preds);
}